// Round 1
// baseline (2482.296 us; speedup 1.0000x reference)
//
#include <hip/hip_runtime.h>
#include <math.h>

#define WN 4096
#define NP 8192
#define KK 32
#define EPSB 1e-5f

__device__ __forceinline__ float lrelu(float x){ return fmaxf(x, 0.01f*x); }
__device__ __forceinline__ float rlane(float v, int c){
  return __int_as_float(__builtin_amdgcn_readlane(__float_as_int(v), c));
}

// ---------------- prep: build pts (b,p,3), xe0 (b,p,3) and squared norms ----------------
__global__ void k_prep(const float* __restrict__ x, float* __restrict__ pts, float* __restrict__ xe0,
                       float* __restrict__ sqp, float* __restrict__ sqe){
  int i = blockIdx.x*256 + threadIdx.x;
  if(i >= NP) return;
  int b = i>>12, p = i&4095;
  const float* xb = x + b*12288;
  float a0 = xb[p], a1 = xb[4096+p], a2 = xb[8192+p];
  pts[i*3+0]=a0; pts[i*3+1]=a1; pts[i*3+2]=a2;
  sqp[i] = (a0*a0 + a1*a1) + a2*a2;
  float e0 = xb[p*3+0], e1 = xb[p*3+1], e2 = xb[p*3+2];
  xe0[i*3+0]=e0; xe0[i*3+1]=e1; xe0[i*3+2]=e2;
  sqe[i] = (e0*e0 + e1*e1) + e2*e2;
}

// ---------------- top-32 selection over a wave-private LDS column set ----------------
// dw[m] is only ever touched by lane m&63 (stride-64 ownership -> 2-way bank alias, free).
__device__ __forceinline__ void select32(float* dw, float gv[8], int gi[8], int l, int* __restrict__ out){
  for(int r=0;r<KK;r++){
    float v = gv[0]; int mi = gi[0];
    #pragma unroll
    for(int g=1; g<8; g++){ if(gv[g] < v || (gv[g]==v && gi[g]<mi)){ v=gv[g]; mi=gi[g]; } }
    #pragma unroll
    for(int off=32; off; off>>=1){
      float ov = __shfl_xor(v, off);
      int om = __shfl_xor(mi, off);
      if(ov < v || (ov==v && om<mi)){ v=ov; mi=om; }
    }
    if(l==0) out[r]=mi;
    if((mi&63)==l){
      dw[mi] = 3.4e38f;
      int gsel = mi>>9;
      #pragma unroll
      for(int g=0; g<8; g++){
        if(g == gsel){
          float bv = 3.4e38f; int bi = l;
          #pragma unroll
          for(int jj=0;jj<8;jj++){
            int m2 = l + (((g<<3)+jj)<<6);
            float dv = dw[m2];
            if(dv < bv){ bv=dv; bi=m2; }
          }
          gv[g]=bv; gi[g]=bi;
        }
      }
    }
  }
}

// ---------------- KNN for 3-channel points (fused distance + select) ----------------
__global__ __launch_bounds__(128) void k_knn3(const float* __restrict__ pnt, const float* __restrict__ sq,
                                              int* __restrict__ idx){
  __shared__ float dist[2][4096];
  int w = threadIdx.x>>6, l = threadIdx.x&63;
  int q = blockIdx.x*2 + w;
  int b = q>>12, qr = q&4095;
  const float* pb = pnt + (size_t)b*WN*3;
  const float* sb = sq + b*WN;
  float q0=pb[qr*3], q1=pb[qr*3+1], q2=pb[qr*3+2];
  float sqq = sb[qr];
  float* dw = dist[w];
  float gv[8]; int gi[8];
  #pragma unroll
  for(int g=0;g<8;g++){ gv[g]=3.4e38f; gi[g]=0; }
  #pragma unroll
  for(int j=0;j<64;j++){
    int m = l + (j<<6);
    float d0=pb[m*3], d1=pb[m*3+1], d2=pb[m*3+2];
    float dot = q0*d0 + q1*d1 + q2*d2;
    float d = (sqq - 2.0f*dot) + sb[m];
    dw[m] = d;
    if(d < gv[j>>3]){ gv[j>>3]=d; gi[j>>3]=m; }
  }
  select32(dw, gv, gi, l, idx + (size_t)q*KK);
}

// ---------------- KNN selection from precomputed D ----------------
__global__ __launch_bounds__(128) void k_knn_sel(const float* __restrict__ D, int* __restrict__ idx){
  __shared__ float dist[2][4096];
  int w = threadIdx.x>>6, l = threadIdx.x&63;
  int q = blockIdx.x*2 + w;
  int b = q>>12, qr = q&4095;
  const float* row = D + ((size_t)b<<24) + ((size_t)qr<<12);
  float* dw = dist[w];
  float gv[8]; int gi[8];
  #pragma unroll
  for(int g=0;g<8;g++){ gv[g]=3.4e38f; gi[g]=0; }
  #pragma unroll
  for(int j=0;j<64;j++){
    int m = l + (j<<6);
    float d = row[m];
    dw[m] = d;
    if(d < gv[j>>3]){ gv[j>>3]=d; gi[j>>3]=m; }
  }
  select32(dw, gv, gi, l, idx + (size_t)q*KK);
}

// ---------------- gaussian kernel conv: block per point, thread per center ----------------
__global__ __launch_bounds__(128) void k_gauss(const float* __restrict__ pts, const float* __restrict__ sqp,
                                               const int* __restrict__ idxP, const float* __restrict__ cen,
                                               float* __restrict__ kout){
  __shared__ float nbx[KK], nby[KK], nbz[KK], nsq[KK];
  int p = blockIdx.x; int b = p>>12; int t = threadIdx.x;
  if(t < KK){
    int id = idxP[(size_t)p*KK + t] + (b<<12);
    nbx[t]=pts[id*3]; nby[t]=pts[id*3+1]; nbz[t]=pts[id*3+2];
    nsq[t]=sqp[id];
  }
  __syncthreads();
  float c0=cen[t*3], c1=cen[t*3+1], c2=cen[t*3+2];
  float sqc=(c0*c0+c1*c1)+c2*c2;
  float acc=0.f;
  #pragma unroll
  for(int k=0;k<KK;k++){
    float dot = nbx[k]*c0 + nby[k]*c1 + nbz[k]*c2;
    float d = (nsq[k] - 2.0f*dot) + sqc;
    acc += expf(-0.5f*d);
  }
  kout[(size_t)((b<<7)+t)*4096 + (p&4095)] = acc;
}

// ---------------- finalize BN stats from per-wave partials ----------------
__global__ void k_fin(const float* __restrict__ psum, const float* __restrict__ psq, int NW, int C, float Nn,
                      const float* __restrict__ g, const float* __restrict__ be,
                      float* __restrict__ sc, float* __restrict__ sh){
  int o = blockIdx.x, t = threadIdx.x;
  float s=0.f, q=0.f;
  for(int w=t; w<NW; w+=256){ s += psum[(size_t)w*C+o]; q += psq[(size_t)w*C+o]; }
  __shared__ float ls[256], lq[256];
  ls[t]=s; lq[t]=q; __syncthreads();
  for(int st=128; st; st>>=1){ if(t<st){ ls[t]+=ls[t+st]; lq[t]+=lq[t+st]; } __syncthreads(); }
  if(t==0){
    float mu = ls[0]/Nn;
    float var = lq[0]/Nn - mu*mu; if(var<0.f) var=0.f;
    float s1 = g[o]*rsqrtf(var + EPSB);
    sc[o]=s1; sh[o]=be[o]-mu*s1;
  }
}

// ---------------- edge-conv 1 (Cin=3 -> 64) ----------------
__global__ __launch_bounds__(256) void k_ec1_h1(const float* __restrict__ xe0, const int* __restrict__ idx1,
                                                const float* __restrict__ w1, float* __restrict__ hbuf,
                                                float* __restrict__ psum, float* __restrict__ psq){
  int wid = (blockIdx.x*256 + threadIdx.x)>>6;   // < 1024
  int l = threadIdx.x&63;
  float wr[6];
  #pragma unroll
  for(int c=0;c<6;c++) wr[c] = w1[l*6+c];
  float s=0.f, ss=0.f;
  for(int p=wid; p<NP; p+=1024){
    int bb = (p>>12)<<12;
    float x0=xe0[p*3], x1=xe0[p*3+1], x2=xe0[p*3+2];
    const int* ip = idx1 + (size_t)p*KK;
    for(int k=0;k<KK;k++){
      int id = ip[k];
      const float* nb = xe0 + (size_t)(bb+id)*3;
      float h = wr[0]*(nb[0]-x0) + wr[1]*(nb[1]-x1) + wr[2]*(nb[2]-x2)
              + wr[3]*x0 + wr[4]*x1 + wr[5]*x2;
      hbuf[(size_t)(p*KK+k)*64 + l] = h;
      s += h; ss += h*h;
    }
  }
  psum[(size_t)wid*64+l]=s; psq[(size_t)wid*64+l]=ss;
}

__global__ __launch_bounds__(256) void k_ec1_h2(float* __restrict__ hbuf, const float* __restrict__ w2,
                                                const float* __restrict__ sc, const float* __restrict__ sh,
                                                float* __restrict__ psum, float* __restrict__ psq){
  int wid = (blockIdx.x*256 + threadIdx.x)>>6;   // < 1024
  int l = threadIdx.x&63;
  float wr[64];
  #pragma unroll
  for(int c=0;c<64;c+=4){ float4 v = *(const float4*)&w2[l*64+c]; wr[c]=v.x; wr[c+1]=v.y; wr[c+2]=v.z; wr[c+3]=v.w; }
  float s1=sc[l], t1=sh[l];
  float s=0.f, ss=0.f;
  for(int smp=wid; smp<NP*KK; smp+=1024){
    float y = lrelu(fmaf(hbuf[(size_t)smp*64+l], s1, t1));
    float a0=0.f, a1=0.f;
    #pragma unroll
    for(int c=0;c<64;c+=2){
      a0 = fmaf(rlane(y,c),   wr[c],   a0);
      a1 = fmaf(rlane(y,c+1), wr[c+1], a1);
    }
    float h2 = a0+a1;
    hbuf[(size_t)smp*64+l] = h2;   // in-place: own element read before any write (wave-private sample)
    s+=h2; ss+=h2*h2;
  }
  psum[(size_t)wid*64+l]=s; psq[(size_t)wid*64+l]=ss;
}

__global__ __launch_bounds__(256) void k_ec1_max(const float* __restrict__ hbuf, const float* __restrict__ sc,
                                                 const float* __restrict__ sh, float* __restrict__ xe1,
                                                 float* __restrict__ xe1T, float* __restrict__ sqx){
  int p = (blockIdx.x*256 + threadIdx.x)>>6;     // < 8192
  int l = threadIdx.x&63;
  float s1=sc[l], t1=sh[l];
  float mx = -3.4e38f;
  for(int k=0;k<KK;k++){
    float h = hbuf[(size_t)(p*KK+k)*64 + l];
    mx = fmaxf(mx, lrelu(fmaf(h,s1,t1)));
  }
  xe1[(size_t)p*64+l]=mx;
  int b=p>>12, pr=p&4095;
  xe1T[(size_t)(b*64+l)*4096 + pr]=mx;
  float sq = mx*mx;
  #pragma unroll
  for(int off=32; off; off>>=1) sq += __shfl_xor(sq, off);
  if(l==0) sqx[p]=sq;
}

// ---------------- D = sq_n - 2 X X^T + sq_m  (per batch, 128x128 tiles, 8x8/thread) ----------------
__global__ __launch_bounds__(256) void k_dgemm(const float* __restrict__ xT, const float* __restrict__ sqx,
                                               float* __restrict__ D){
  __shared__ float As[32*128], Bs2[32*128];
  int b = blockIdx.z;
  int m0 = blockIdx.y*128, n0 = blockIdx.x*128;
  int t = threadIdx.x;
  int tx = t&15, ty = t>>4;
  const float* xb = xT + (size_t)b*64*4096;
  float acc[8][8];
  #pragma unroll
  for(int i=0;i<8;i++){
    #pragma unroll
    for(int j=0;j<8;j++) acc[i][j]=0.f;
  }
  for(int kc=0;kc<2;kc++){
    __syncthreads();
    #pragma unroll
    for(int i=0;i<16;i++){
      int e = t + (i<<8);
      int k = e>>7, mm = e&127;
      As[k*128+mm]  = xb[(size_t)(kc*32+k)*4096 + m0+mm];
      Bs2[k*128+mm] = xb[(size_t)(kc*32+k)*4096 + n0+mm];
    }
    __syncthreads();
    #pragma unroll 4
    for(int k=0;k<32;k++){
      float av[8], bv[8];
      float4 A0 = *(float4*)&As[k*128 + ty*8];
      float4 A1 = *(float4*)&As[k*128 + ty*8+4];
      float4 B0 = *(float4*)&Bs2[k*128 + tx*8];
      float4 B1 = *(float4*)&Bs2[k*128 + tx*8+4];
      av[0]=A0.x; av[1]=A0.y; av[2]=A0.z; av[3]=A0.w; av[4]=A1.x; av[5]=A1.y; av[6]=A1.z; av[7]=A1.w;
      bv[0]=B0.x; bv[1]=B0.y; bv[2]=B0.z; bv[3]=B0.w; bv[4]=B1.x; bv[5]=B1.y; bv[6]=B1.z; bv[7]=B1.w;
      #pragma unroll
      for(int i=0;i<8;i++){
        #pragma unroll
        for(int j=0;j<8;j++) acc[i][j] = fmaf(av[i], bv[j], acc[i][j]);
      }
    }
  }
  const float* sb = sqx + (b<<12);
  float* Db = D + ((size_t)b<<24);
  #pragma unroll
  for(int i=0;i<8;i++){
    int r = m0 + ty*8 + i;
    float sqa = sb[r];
    float o[8];
    #pragma unroll
    for(int j=0;j<8;j++) o[j] = (sqa - 2.0f*acc[i][j]) + sb[n0+tx*8+j];
    *(float4*)&Db[(size_t)r*4096 + n0+tx*8]   = make_float4(o[0],o[1],o[2],o[3]);
    *(float4*)&Db[(size_t)r*4096 + n0+tx*8+4] = make_float4(o[4],o[5],o[6],o[7]);
  }
}

// ---------------- edge-conv 2 (Cin=64 -> 128); wave handles (point, o-half) ----------------
__global__ __launch_bounds__(256) void k_ec2_h1(const float* __restrict__ xe1, const int* __restrict__ idx2,
                                                const float* __restrict__ w1, float* __restrict__ hbuf,
                                                float* __restrict__ psum, float* __restrict__ psq){
  int gw = (blockIdx.x*256 + threadIdx.x)>>6;    // < 2048
  int l = threadIdx.x&63;
  int half = gw&1;
  int o = (half<<6)+l;
  float wr[128];
  #pragma unroll
  for(int c=0;c<128;c+=4){ float4 v = *(const float4*)&w1[(size_t)o*128+c]; wr[c]=v.x; wr[c+1]=v.y; wr[c+2]=v.z; wr[c+3]=v.w; }
  float s=0.f, ss=0.f;
  for(int wp=gw; wp<NP*2; wp+=2048){
    int p = wp>>1;
    int bb = (p>>12)<<12;
    float xo = xe1[(size_t)p*64+l];
    float base0=0.f, base1=0.f;
    #pragma unroll
    for(int c=0;c<64;c+=2){
      base0 = fmaf(rlane(xo,c),   wr[64+c],   base0);
      base1 = fmaf(rlane(xo,c+1), wr[64+c+1], base1);
    }
    float base = base0+base1;
    const int* ip = idx2 + (size_t)p*KK;
    for(int k=0;k<KK;k++){
      int id = ip[k];
      float dn = xe1[(size_t)(bb+id)*64 + l] - xo;
      float a0=base, a1=0.f;
      #pragma unroll
      for(int c=0;c<64;c+=2){
        a0 = fmaf(rlane(dn,c),   wr[c],   a0);
        a1 = fmaf(rlane(dn,c+1), wr[c+1], a1);
      }
      float h = a0+a1;
      hbuf[(size_t)(p*KK+k)*128 + o] = h;
      s+=h; ss+=h*h;
    }
  }
  psum[(size_t)gw*128+o]=s; psq[(size_t)gw*128+o]=ss;
  psum[(size_t)gw*128+((1-half)<<6)+l]=0.f; psq[(size_t)gw*128+((1-half)<<6)+l]=0.f;
}

// MODE 0: stats of h2 (no store). MODE 1: y2 + max over k -> xe2.
template<int MODE>
__global__ __launch_bounds__(256) void k_ec2_h2(const float* __restrict__ hbuf, const float* __restrict__ w2,
                                                const float* __restrict__ s1v, const float* __restrict__ t1v,
                                                const float* __restrict__ s2v, const float* __restrict__ t2v,
                                                float* __restrict__ psum, float* __restrict__ psq,
                                                float* __restrict__ xe2){
  int gw = (blockIdx.x*256 + threadIdx.x)>>6;    // < 2048
  int l = threadIdx.x&63;
  int half = gw&1;
  int o = (half<<6)+l;
  float wr[128];
  #pragma unroll
  for(int c=0;c<128;c+=4){ float4 v = *(const float4*)&w2[(size_t)o*128+c]; wr[c]=v.x; wr[c+1]=v.y; wr[c+2]=v.z; wr[c+3]=v.w; }
  float sA=s1v[l], tA=t1v[l], sB=s1v[64+l], tB=t1v[64+l];
  float sc2=0.f, sh2=0.f;
  if(MODE==1){ sc2=s2v[o]; sh2=t2v[o]; }
  float s=0.f, ss=0.f;
  for(int wp=gw; wp<NP*2; wp+=2048){
    int p = wp>>1;
    const float* hs = hbuf + (size_t)p*KK*128;
    float mx = -3.4e38f;
    for(int k=0;k<KK;k++){
      float ya = lrelu(fmaf(hs[k*128 + l],     sA, tA));
      float yb = lrelu(fmaf(hs[k*128 + 64 + l], sB, tB));
      float a0=0.f, a1=0.f;
      #pragma unroll
      for(int c=0;c<64;c+=2){
        a0 = fmaf(rlane(ya,c),   wr[c],   a0);
        a1 = fmaf(rlane(ya,c+1), wr[c+1], a1);
      }
      #pragma unroll
      for(int c=0;c<64;c+=2){
        a0 = fmaf(rlane(yb,c),   wr[64+c],   a0);
        a1 = fmaf(rlane(yb,c+1), wr[64+c+1], a1);
      }
      float h = a0+a1;
      if(MODE==0){ s+=h; ss+=h*h; }
      else mx = fmaxf(mx, lrelu(fmaf(h,sc2,sh2)));
    }
    if(MODE==1) xe2[(size_t)p*128+o]=mx;
  }
  if(MODE==0){
    psum[(size_t)gw*128+o]=s; psq[(size_t)gw*128+o]=ss;
    psum[(size_t)gw*128+((1-half)<<6)+l]=0.f; psq[(size_t)gw*128+((1-half)<<6)+l]=0.f;
  }
}

// ---------------- hcat = [xe2 (flat-reinterpret) ; kernels_r] ----------------
__global__ void k_hcat(const float* __restrict__ xe2, const float* __restrict__ kr, float* __restrict__ hcat){
  size_t i = (size_t)blockIdx.x*256 + threadIdx.x;   // < 2*256*4096
  int b = (int)(i>>20);
  int r = (int)(i & 1048575);
  int ch = r>>12;
  float v;
  if(ch < 128) v = xe2[(size_t)b*524288 + r];
  else         v = kr [(size_t)(b*128 + (ch-128))*4096 + (r&4095)];
  hcat[i] = v;
}

// ---------------- generic small transpose (O,C)->(C,O) ----------------
__global__ void k_transpose(const float* __restrict__ w, float* __restrict__ wT, int O, int C){
  int i = blockIdx.x*256 + threadIdx.x;
  if(i >= O*C) return;
  int o = i / C, c = i % C;
  wT[(size_t)c*O + o] = w[i];
}

// ---------------- cbr GEMM: out[b][o][s] = sum_c act(in[b][c][s]) * w[o][c] ----------------
__global__ __launch_bounds__(256) void k_cbr(const float* __restrict__ in, const float* __restrict__ wT,
                                             const float* __restrict__ sc, const float* __restrict__ sh,
                                             float* __restrict__ out, int Cin, int Cout){
  int b = blockIdx.z;
  int tyu = __builtin_amdgcn_readfirstlane((int)(threadIdx.x>>6));
  int tx = threadIdx.x&63;
  int o0 = blockIdx.y*32 + tyu*8;
  int s = blockIdx.x*256 + tx*4;
  const float* ib = in + (size_t)b*Cin*4096;
  float acc[8][4];
  #pragma unroll
  for(int j=0;j<8;j++){ acc[j][0]=0.f; acc[j][1]=0.f; acc[j][2]=0.f; acc[j][3]=0.f; }
  for(int c=0;c<Cin;c++){
    float4 x = *(const float4*)&ib[(size_t)c*4096 + s];
    if(sc){
      float a = sc[c], h = sh[c];
      x.x = lrelu(fmaf(x.x,a,h)); x.y = lrelu(fmaf(x.y,a,h));
      x.z = lrelu(fmaf(x.z,a,h)); x.w = lrelu(fmaf(x.w,a,h));
    }
    const float* wp = wT + (size_t)c*Cout + o0;
    #pragma unroll
    for(int j=0;j<8;j++){
      float wv = wp[j];
      acc[j][0]=fmaf(x.x,wv,acc[j][0]);
      acc[j][1]=fmaf(x.y,wv,acc[j][1]);
      acc[j][2]=fmaf(x.z,wv,acc[j][2]);
      acc[j][3]=fmaf(x.w,wv,acc[j][3]);
    }
  }
  #pragma unroll
  for(int j=0;j<8;j++){
    *(float4*)&out[(size_t)(b*Cout + o0+j)*4096 + s] = make_float4(acc[j][0],acc[j][1],acc[j][2],acc[j][3]);
  }
}

// ---------------- per-channel stats over (b, s) for cbr layers ----------------
__global__ void k_cstats(const float* __restrict__ buf, int C, const float* __restrict__ g,
                         const float* __restrict__ be, float* __restrict__ sc, float* __restrict__ sh){
  int o = blockIdx.x, t = threadIdx.x;
  float s=0.f, q=0.f;
  for(int i=t;i<8192;i+=256){
    int b=i>>12, ss_=i&4095;
    float v = buf[(size_t)(b*C+o)*4096 + ss_];
    s+=v; q+=v*v;
  }
  __shared__ float ls[256], lq[256];
  ls[t]=s; lq[t]=q; __syncthreads();
  for(int st=128; st; st>>=1){ if(t<st){ ls[t]+=ls[t+st]; lq[t]+=lq[t+st]; } __syncthreads(); }
  if(t==0){
    float mu = ls[0]/8192.f;
    float var = lq[0]/8192.f - mu*mu; if(var<0.f) var=0.f;
    float s1 = g[o]*rsqrtf(var + EPSB);
    sc[o]=s1; sh[o]=be[o]-mu*s1;
  }
}

// ---------------- final layer: 9 outputs + partial spatial max ----------------
__global__ __launch_bounds__(256) void k_final4(const float* __restrict__ c3, const float* __restrict__ w4T,
                                                const float* __restrict__ sc, const float* __restrict__ sh,
                                                float* __restrict__ pmax){
  int b = blockIdx.y, st = blockIdx.x;
  int t = threadIdx.x; int s = st*256 + t;
  float acc[9];
  #pragma unroll
  for(int j=0;j<9;j++) acc[j]=0.f;
  const float* ib = c3 + (size_t)b*256*4096;
  for(int c=0;c<256;c++){
    float x = lrelu(fmaf(ib[(size_t)c*4096+s], sc[c], sh[c]));
    #pragma unroll
    for(int j=0;j<9;j++) acc[j]=fmaf(x, w4T[c*9+j], acc[j]);
  }
  __shared__ float red[256];
  for(int j=0;j<9;j++){
    red[t]=acc[j]; __syncthreads();
    for(int stp=128; stp; stp>>=1){ if(t<stp) red[t]=fmaxf(red[t],red[t+stp]); __syncthreads(); }
    if(t==0) pmax[(b*16+st)*9 + j]=red[0];
    __syncthreads();
  }
}

__global__ void k_out(const float* __restrict__ pmax, float* __restrict__ out){
  int i = threadIdx.x;
  if(i<18){
    int b=i/9, o=i%9;
    float m=-3.4e38f;
    for(int k=0;k<16;k++) m=fmaxf(m, pmax[(b*16+k)*9+o]);
    out[i] = m + ((o==0||o==4||o==8)?1.f:0.f);
  }
}

// ---------------- launch ----------------
extern "C" void kernel_launch(void* const* d_in, const int* in_sizes, int n_in,
                              void* d_out, int out_size, void* d_ws, size_t ws_size,
                              hipStream_t stream){
  const float* x    = (const float*)d_in[0];
  const float* kc   = (const float*)d_in[1];
  const float* e1w1 = (const float*)d_in[2];
  const float* e1g1 = (const float*)d_in[3];
  const float* e1b1 = (const float*)d_in[4];
  const float* e1w2 = (const float*)d_in[5];
  const float* e1g2 = (const float*)d_in[6];
  const float* e1b2 = (const float*)d_in[7];
  const float* e2w1 = (const float*)d_in[8];
  const float* e2g1 = (const float*)d_in[9];
  const float* e2b1 = (const float*)d_in[10];
  const float* e2w2 = (const float*)d_in[11];
  const float* e2g2 = (const float*)d_in[12];
  const float* e2b2 = (const float*)d_in[13];
  const float* w1   = (const float*)d_in[14];
  const float* g1   = (const float*)d_in[15];
  const float* b1   = (const float*)d_in[16];
  const float* w2   = (const float*)d_in[17];
  const float* g2   = (const float*)d_in[18];
  const float* b2   = (const float*)d_in[19];
  const float* w3   = (const float*)d_in[20];
  const float* g3   = (const float*)d_in[21];
  const float* b3   = (const float*)d_in[22];
  const float* w4   = (const float*)d_in[23];

  if(ws_size < 156061696ull) return;   // need ~149 MB scratch
  char* ws = (char*)d_ws;
  float* pts   = (float*)(ws + 0);
  float* xe0   = (float*)(ws + 98304);
  float* sqp   = (float*)(ws + 196608);
  float* sqe   = (float*)(ws + 229376);
  float* sqx1  = (float*)(ws + 262144);
  float* xe1   = (float*)(ws + 294912);
  float* xe1T  = (float*)(ws + 2392064);
  float* xe2   = (float*)(ws + 4489216);
  float* kr    = (float*)(ws + 8683520);
  int*   idxP  = (int*)  (ws + 12877824);
  int*   idx1  = (int*)  (ws + 13926400);
  int*   idx2  = (int*)  (ws + 14974976);
  float* psum  = (float*)(ws + 16023552);
  float* psq   = (float*)(ws + 17072128);
  float* par   = (float*)(ws + 18120704);
  float* pmax  = (float*)(ws + 18153472);
  float* wT1   = (float*)(ws + 18157568);
  float* wT2   = (float*)(ws + 19206144);
  float* wT3   = (float*)(ws + 21303296);
  float* wT4   = (float*)(ws + 21827584);
  float* hbuf  = (float*)(ws + 21843968);   // 134217728 B; also: D matrix; also cbr buffers

  // param sub-arrays (floats)
  float* e1s1 = par+0;    float* e1t1 = par+64;
  float* e1s2 = par+128;  float* e1t2 = par+192;
  float* e2s1 = par+256;  float* e2t1 = par+384;
  float* e2s2 = par+512;  float* e2t2 = par+640;
  float* c1s  = par+768;  float* c1t  = par+1792;
  float* c2s  = par+2816; float* c2t  = par+3328;
  float* c3s  = par+3840; float* c3t  = par+4096;

  float* hcat  = hbuf;                       // 2*256*4096
  float* c1out = hbuf + 2097152;             // 2*1024*4096
  float* c2out = hbuf + 10485760;            // 2*512*4096
  float* c3out = hbuf + 14680064;            // 2*256*4096

  hipLaunchKernelGGL(k_prep, dim3(32), dim3(256), 0, stream, x, pts, xe0, sqp, sqe);
  hipLaunchKernelGGL(k_knn3, dim3(4096), dim3(128), 0, stream, pts, sqp, idxP);
  hipLaunchKernelGGL(k_knn3, dim3(4096), dim3(128), 0, stream, xe0, sqe, idx1);
  hipLaunchKernelGGL(k_gauss, dim3(8192), dim3(128), 0, stream, pts, sqp, idxP, kc, kr);

  // edge-conv 1
  hipLaunchKernelGGL(k_ec1_h1, dim3(256), dim3(256), 0, stream, xe0, idx1, e1w1, hbuf, psum, psq);
  hipLaunchKernelGGL(k_fin, dim3(64), dim3(256), 0, stream, psum, psq, 1024, 64, 262144.f, e1g1, e1b1, e1s1, e1t1);
  hipLaunchKernelGGL(k_ec1_h2, dim3(256), dim3(256), 0, stream, hbuf, e1w2, e1s1, e1t1, psum, psq);
  hipLaunchKernelGGL(k_fin, dim3(64), dim3(256), 0, stream, psum, psq, 1024, 64, 262144.f, e1g2, e1b2, e1s2, e1t2);
  hipLaunchKernelGGL(k_ec1_max, dim3(2048), dim3(256), 0, stream, hbuf, e1s2, e1t2, xe1, xe1T, sqx1);

  // knn on 64-d features: D into hbuf, then select
  hipLaunchKernelGGL(k_dgemm, dim3(32,32,2), dim3(256), 0, stream, xe1T, sqx1, hbuf);
  hipLaunchKernelGGL(k_knn_sel, dim3(4096), dim3(128), 0, stream, hbuf, idx2);

  // edge-conv 2
  hipLaunchKernelGGL(k_ec2_h1, dim3(512), dim3(256), 0, stream, xe1, idx2, e2w1, hbuf, psum, psq);
  hipLaunchKernelGGL(k_fin, dim3(128), dim3(256), 0, stream, psum, psq, 2048, 128, 262144.f, e2g1, e2b1, e2s1, e2t1);
  hipLaunchKernelGGL(k_ec2_h2<0>, dim3(512), dim3(256), 0, stream, hbuf, e2w2, e2s1, e2t1, e2s2, e2t2, psum, psq, xe2);
  hipLaunchKernelGGL(k_fin, dim3(128), dim3(256), 0, stream, psum, psq, 2048, 128, 262144.f, e2g2, e2b2, e2s2, e2t2);
  hipLaunchKernelGGL(k_ec2_h2<1>, dim3(512), dim3(256), 0, stream, hbuf, e2w2, e2s1, e2t1, e2s2, e2t2, psum, psq, xe2);

  // concat + cbr chain (buffers live in hbuf region, which is free now)
  hipLaunchKernelGGL(k_hcat, dim3(8192), dim3(256), 0, stream, xe2, kr, hcat);
  hipLaunchKernelGGL(k_transpose, dim3((1024*256+255)/256), dim3(256), 0, stream, w1, wT1, 1024, 256);
  hipLaunchKernelGGL(k_transpose, dim3((512*1024+255)/256), dim3(256), 0, stream, w2, wT2, 512, 1024);
  hipLaunchKernelGGL(k_transpose, dim3((256*512+255)/256), dim3(256), 0, stream, w3, wT3, 256, 512);
  hipLaunchKernelGGL(k_transpose, dim3((9*256+255)/256), dim3(256), 0, stream, w4, wT4, 9, 256);

  hipLaunchKernelGGL(k_cbr, dim3(16,32,2), dim3(256), 0, stream, hcat, wT1, (const float*)nullptr, (const float*)nullptr, c1out, 256, 1024);
  hipLaunchKernelGGL(k_cstats, dim3(1024), dim3(256), 0, stream, c1out, 1024, g1, b1, c1s, c1t);
  hipLaunchKernelGGL(k_cbr, dim3(16,16,2), dim3(256), 0, stream, c1out, wT2, c1s, c1t, c2out, 1024, 512);
  hipLaunchKernelGGL(k_cstats, dim3(512), dim3(256), 0, stream, c2out, 512, g2, b2, c2s, c2t);
  hipLaunchKernelGGL(k_cbr, dim3(16,8,2), dim3(256), 0, stream, c2out, wT3, c2s, c2t, c3out, 512, 256);
  hipLaunchKernelGGL(k_cstats, dim3(256), dim3(256), 0, stream, c3out, 256, g3, b3, c3s, c3t);
  hipLaunchKernelGGL(k_final4, dim3(16,2), dim3(256), 0, stream, c3out, wT4, c3s, c3t, pmax);
  hipLaunchKernelGGL(k_out, dim3(1), dim3(32), 0, stream, pmax, (float*)d_out);
}

// Round 2
// 1981.256 us; speedup vs baseline: 1.2529x; 1.2529x over previous
//
#include <hip/hip_runtime.h>
#include <math.h>

#define WN 4096
#define NP 8192
#define KK 32
#define EPSB 1e-5f

__device__ __forceinline__ float lrelu(float x){ return fmaxf(x, 0.01f*x); }
__device__ __forceinline__ float rlane(float v, int c){
  return __int_as_float(__builtin_amdgcn_readlane(__float_as_int(v), c));
}

// ---------------- prep: build pts (b,p,3), xe0 (b,p,3) and squared norms ----------------
__global__ void k_prep(const float* __restrict__ x, float* __restrict__ pts, float* __restrict__ xe0,
                       float* __restrict__ sqp, float* __restrict__ sqe){
  int i = blockIdx.x*256 + threadIdx.x;
  if(i >= NP) return;
  int b = i>>12, p = i&4095;
  const float* xb = x + b*12288;
  float a0 = xb[p], a1 = xb[4096+p], a2 = xb[8192+p];
  pts[i*3+0]=a0; pts[i*3+1]=a1; pts[i*3+2]=a2;
  sqp[i] = (a0*a0 + a1*a1) + a2*a2;
  float e0 = xb[p*3+0], e1 = xb[p*3+1], e2 = xb[p*3+2];
  xe0[i*3+0]=e0; xe0[i*3+1]=e1; xe0[i*3+2]=e2;
  sqe[i] = (e0*e0 + e1*e1) + e2*e2;
}

// ---------------- top-32 selection over a wave-private LDS column set ----------------
__device__ __forceinline__ void select32(float* dw, float gv[8], int gi[8], int l, int* __restrict__ out){
  for(int r=0;r<KK;r++){
    float v = gv[0]; int mi = gi[0];
    #pragma unroll
    for(int g=1; g<8; g++){ if(gv[g] < v || (gv[g]==v && gi[g]<mi)){ v=gv[g]; mi=gi[g]; } }
    #pragma unroll
    for(int off=32; off; off>>=1){
      float ov = __shfl_xor(v, off);
      int om = __shfl_xor(mi, off);
      if(ov < v || (ov==v && om<mi)){ v=ov; mi=om; }
    }
    if(l==0) out[r]=mi;
    if((mi&63)==l){
      dw[mi] = 3.4e38f;
      int gsel = mi>>9;
      #pragma unroll
      for(int g=0; g<8; g++){
        if(g == gsel){
          float bv = 3.4e38f; int bi = l;
          #pragma unroll
          for(int jj=0;jj<8;jj++){
            int m2 = l + (((g<<3)+jj)<<6);
            float dv = dw[m2];
            if(dv < bv){ bv=dv; bi=m2; }
          }
          gv[g]=bv; gi[g]=bi;
        }
      }
    }
  }
}

// ---------------- KNN for 3-channel points (fused distance + select) ----------------
__global__ __launch_bounds__(128) void k_knn3(const float* __restrict__ pnt, const float* __restrict__ sq,
                                              int* __restrict__ idx){
  __shared__ float dist[2][4096];
  int w = threadIdx.x>>6, l = threadIdx.x&63;
  int q = blockIdx.x*2 + w;
  int b = q>>12, qr = q&4095;
  const float* pb = pnt + (size_t)b*WN*3;
  const float* sb = sq + b*WN;
  float q0=pb[qr*3], q1=pb[qr*3+1], q2=pb[qr*3+2];
  float sqq = sb[qr];
  float* dw = dist[w];
  float gv[8]; int gi[8];
  #pragma unroll
  for(int g=0;g<8;g++){ gv[g]=3.4e38f; gi[g]=0; }
  #pragma unroll
  for(int j=0;j<64;j++){
    int m = l + (j<<6);
    float d0=pb[m*3], d1=pb[m*3+1], d2=pb[m*3+2];
    float dot = q0*d0 + q1*d1 + q2*d2;
    float d = (sqq - 2.0f*dot) + sb[m];
    dw[m] = d;
    if(d < gv[j>>3]){ gv[j>>3]=d; gi[j>>3]=m; }
  }
  select32(dw, gv, gi, l, idx + (size_t)q*KK);
}

// ---------------- KNN selection from precomputed D ----------------
__global__ __launch_bounds__(128) void k_knn_sel(const float* __restrict__ D, int* __restrict__ idx){
  __shared__ float dist[2][4096];
  int w = threadIdx.x>>6, l = threadIdx.x&63;
  int q = blockIdx.x*2 + w;
  int b = q>>12, qr = q&4095;
  const float* row = D + ((size_t)b<<24) + ((size_t)qr<<12);
  float* dw = dist[w];
  float gv[8]; int gi[8];
  #pragma unroll
  for(int g=0;g<8;g++){ gv[g]=3.4e38f; gi[g]=0; }
  #pragma unroll
  for(int j=0;j<64;j++){
    int m = l + (j<<6);
    float d = row[m];
    dw[m] = d;
    if(d < gv[j>>3]){ gv[j>>3]=d; gi[j>>3]=m; }
  }
  select32(dw, gv, gi, l, idx + (size_t)q*KK);
}

// ---------------- gaussian kernel conv: block per point, thread per center ----------------
__global__ __launch_bounds__(128) void k_gauss(const float* __restrict__ pts, const float* __restrict__ sqp,
                                               const int* __restrict__ idxP, const float* __restrict__ cen,
                                               float* __restrict__ kout){
  __shared__ float nbx[KK], nby[KK], nbz[KK], nsq[KK];
  int p = blockIdx.x; int b = p>>12; int t = threadIdx.x;
  if(t < KK){
    int id = idxP[(size_t)p*KK + t] + (b<<12);
    nbx[t]=pts[id*3]; nby[t]=pts[id*3+1]; nbz[t]=pts[id*3+2];
    nsq[t]=sqp[id];
  }
  __syncthreads();
  float c0=cen[t*3], c1=cen[t*3+1], c2=cen[t*3+2];
  float sqc=(c0*c0+c1*c1)+c2*c2;
  float acc=0.f;
  #pragma unroll
  for(int k=0;k<KK;k++){
    float dot = nbx[k]*c0 + nby[k]*c1 + nbz[k]*c2;
    float d = (nsq[k] - 2.0f*dot) + sqc;
    acc += expf(-0.5f*d);
  }
  kout[(size_t)((b<<7)+t)*4096 + (p&4095)] = acc;
}

// ---------------- finalize BN stats from per-wave partials ----------------
__global__ void k_fin(const float* __restrict__ psum, const float* __restrict__ psq, int NW, int C, float Nn,
                      const float* __restrict__ g, const float* __restrict__ be,
                      float* __restrict__ sc, float* __restrict__ sh){
  int o = blockIdx.x, t = threadIdx.x;
  float s=0.f, q=0.f;
  for(int w=t; w<NW; w+=256){ s += psum[(size_t)w*C+o]; q += psq[(size_t)w*C+o]; }
  __shared__ float ls[256], lq[256];
  ls[t]=s; lq[t]=q; __syncthreads();
  for(int st=128; st; st>>=1){ if(t<st){ ls[t]+=ls[t+st]; lq[t]+=lq[t+st]; } __syncthreads(); }
  if(t==0){
    float mu = ls[0]/Nn;
    float var = lq[0]/Nn - mu*mu; if(var<0.f) var=0.f;
    float s1 = g[o]*rsqrtf(var + EPSB);
    sc[o]=s1; sh[o]=be[o]-mu*s1;
  }
}

// ---------------- edge-conv 1 (Cin=3 -> 64) ----------------
__global__ __launch_bounds__(256) void k_ec1_h1(const float* __restrict__ xe0, const int* __restrict__ idx1,
                                                const float* __restrict__ w1, float* __restrict__ hbuf,
                                                float* __restrict__ psum, float* __restrict__ psq){
  int wid = (blockIdx.x*256 + threadIdx.x)>>6;   // < 1024
  int l = threadIdx.x&63;
  float wr[6];
  #pragma unroll
  for(int c=0;c<6;c++) wr[c] = w1[l*6+c];
  float s=0.f, ss=0.f;
  for(int p=wid; p<NP; p+=1024){
    int bb = (p>>12)<<12;
    float x0=xe0[p*3], x1=xe0[p*3+1], x2=xe0[p*3+2];
    const int* ip = idx1 + (size_t)p*KK;
    for(int k=0;k<KK;k++){
      int id = ip[k];
      const float* nb = xe0 + (size_t)(bb+id)*3;
      float h = wr[0]*(nb[0]-x0) + wr[1]*(nb[1]-x1) + wr[2]*(nb[2]-x2)
              + wr[3]*x0 + wr[4]*x1 + wr[5]*x2;
      hbuf[(size_t)(p*KK+k)*64 + l] = h;
      s += h; ss += h*h;
    }
  }
  psum[(size_t)wid*64+l]=s; psq[(size_t)wid*64+l]=ss;
}

__global__ __launch_bounds__(256) void k_ec1_h2(float* __restrict__ hbuf, const float* __restrict__ w2,
                                                const float* __restrict__ sc, const float* __restrict__ sh,
                                                float* __restrict__ psum, float* __restrict__ psq){
  int wid = (blockIdx.x*256 + threadIdx.x)>>6;   // < 1024
  int l = threadIdx.x&63;
  float wr[64];
  #pragma unroll
  for(int c=0;c<64;c+=4){ float4 v = *(const float4*)&w2[l*64+c]; wr[c]=v.x; wr[c+1]=v.y; wr[c+2]=v.z; wr[c+3]=v.w; }
  float s1=sc[l], t1=sh[l];
  float s=0.f, ss=0.f;
  for(int smp=wid; smp<NP*KK; smp+=1024){
    float y = lrelu(fmaf(hbuf[(size_t)smp*64+l], s1, t1));
    float a0=0.f, a1=0.f;
    #pragma unroll
    for(int c=0;c<64;c+=2){
      a0 = fmaf(rlane(y,c),   wr[c],   a0);
      a1 = fmaf(rlane(y,c+1), wr[c+1], a1);
    }
    float h2 = a0+a1;
    hbuf[(size_t)smp*64+l] = h2;
    s+=h2; ss+=h2*h2;
  }
  psum[(size_t)wid*64+l]=s; psq[(size_t)wid*64+l]=ss;
}

__global__ __launch_bounds__(256) void k_ec1_max(const float* __restrict__ hbuf, const float* __restrict__ sc,
                                                 const float* __restrict__ sh, float* __restrict__ xe1,
                                                 float* __restrict__ xe1T, float* __restrict__ sqx){
  int p = (blockIdx.x*256 + threadIdx.x)>>6;     // < 8192
  int l = threadIdx.x&63;
  float s1=sc[l], t1=sh[l];
  float mx = -3.4e38f;
  for(int k=0;k<KK;k++){
    float h = hbuf[(size_t)(p*KK+k)*64 + l];
    mx = fmaxf(mx, lrelu(fmaf(h,s1,t1)));
  }
  xe1[(size_t)p*64+l]=mx;
  int b=p>>12, pr=p&4095;
  xe1T[(size_t)(b*64+l)*4096 + pr]=mx;
  float sq = mx*mx;
  #pragma unroll
  for(int off=32; off; off>>=1) sq += __shfl_xor(sq, off);
  if(l==0) sqx[p]=sq;
}

// ---------------- D = sq_n - 2 X X^T + sq_m  (per batch, 128x128 tiles, 8x8/thread) ----------------
__global__ __launch_bounds__(256) void k_dgemm(const float* __restrict__ xT, const float* __restrict__ sqx,
                                               float* __restrict__ D){
  __shared__ float As[32*128], Bs2[32*128];
  int b = blockIdx.z;
  int m0 = blockIdx.y*128, n0 = blockIdx.x*128;
  int t = threadIdx.x;
  int tx = t&15, ty = t>>4;
  const float* xb = xT + (size_t)b*64*4096;
  float acc[8][8];
  #pragma unroll
  for(int i=0;i<8;i++){
    #pragma unroll
    for(int j=0;j<8;j++) acc[i][j]=0.f;
  }
  for(int kc=0;kc<2;kc++){
    __syncthreads();
    #pragma unroll
    for(int i=0;i<16;i++){
      int e = t + (i<<8);
      int k = e>>7, mm = e&127;
      As[k*128+mm]  = xb[(size_t)(kc*32+k)*4096 + m0+mm];
      Bs2[k*128+mm] = xb[(size_t)(kc*32+k)*4096 + n0+mm];
    }
    __syncthreads();
    #pragma unroll 4
    for(int k=0;k<32;k++){
      float av[8], bv[8];
      float4 A0 = *(float4*)&As[k*128 + ty*8];
      float4 A1 = *(float4*)&As[k*128 + ty*8+4];
      float4 B0 = *(float4*)&Bs2[k*128 + tx*8];
      float4 B1 = *(float4*)&Bs2[k*128 + tx*8+4];
      av[0]=A0.x; av[1]=A0.y; av[2]=A0.z; av[3]=A0.w; av[4]=A1.x; av[5]=A1.y; av[6]=A1.z; av[7]=A1.w;
      bv[0]=B0.x; bv[1]=B0.y; bv[2]=B0.z; bv[3]=B0.w; bv[4]=B1.x; bv[5]=B1.y; bv[6]=B1.z; bv[7]=B1.w;
      #pragma unroll
      for(int i=0;i<8;i++){
        #pragma unroll
        for(int j=0;j<8;j++) acc[i][j] = fmaf(av[i], bv[j], acc[i][j]);
      }
    }
  }
  const float* sb = sqx + (b<<12);
  float* Db = D + ((size_t)b<<24);
  #pragma unroll
  for(int i=0;i<8;i++){
    int r = m0 + ty*8 + i;
    float sqa = sb[r];
    float o[8];
    #pragma unroll
    for(int j=0;j<8;j++) o[j] = (sqa - 2.0f*acc[i][j]) + sb[n0+tx*8+j];
    *(float4*)&Db[(size_t)r*4096 + n0+tx*8]   = make_float4(o[0],o[1],o[2],o[3]);
    *(float4*)&Db[(size_t)r*4096 + n0+tx*8+4] = make_float4(o[4],o[5],o[6],o[7]);
  }
}

// ---------------- edge-conv 2 (Cin=64 -> 128); wave handles (point, o-half) ----------------
__global__ __launch_bounds__(256) void k_ec2_h1(const float* __restrict__ xe1, const int* __restrict__ idx2,
                                                const float* __restrict__ w1, float* __restrict__ hbuf,
                                                float* __restrict__ psum, float* __restrict__ psq){
  int gw = (blockIdx.x*256 + threadIdx.x)>>6;    // < 2048
  int l = threadIdx.x&63;
  int half = gw&1;
  int o = (half<<6)+l;
  float wr[128];
  #pragma unroll
  for(int c=0;c<128;c+=4){ float4 v = *(const float4*)&w1[(size_t)o*128+c]; wr[c]=v.x; wr[c+1]=v.y; wr[c+2]=v.z; wr[c+3]=v.w; }
  float s=0.f, ss=0.f;
  for(int wp=gw; wp<NP*2; wp+=2048){
    int p = wp>>1;
    int bb = (p>>12)<<12;
    float xo = xe1[(size_t)p*64+l];
    float base0=0.f, base1=0.f;
    #pragma unroll
    for(int c=0;c<64;c+=2){
      base0 = fmaf(rlane(xo,c),   wr[64+c],   base0);
      base1 = fmaf(rlane(xo,c+1), wr[64+c+1], base1);
    }
    float base = base0+base1;
    const int* ip = idx2 + (size_t)p*KK;
    for(int k=0;k<KK;k++){
      int id = ip[k];
      float dn = xe1[(size_t)(bb+id)*64 + l] - xo;
      float a0=base, a1=0.f;
      #pragma unroll
      for(int c=0;c<64;c+=2){
        a0 = fmaf(rlane(dn,c),   wr[c],   a0);
        a1 = fmaf(rlane(dn,c+1), wr[c+1], a1);
      }
      float h = a0+a1;
      hbuf[(size_t)(p*KK+k)*128 + o] = h;
      s+=h; ss+=h*h;
    }
  }
  psum[(size_t)gw*128+o]=s; psq[(size_t)gw*128+o]=ss;
  psum[(size_t)gw*128+((1-half)<<6)+l]=0.f; psq[(size_t)gw*128+((1-half)<<6)+l]=0.f;
}

// MODE 0: stats of h2 (no store). MODE 1: y2 + max over k -> xe2.
template<int MODE>
__global__ __launch_bounds__(256) void k_ec2_h2(const float* __restrict__ hbuf, const float* __restrict__ w2,
                                                const float* __restrict__ s1v, const float* __restrict__ t1v,
                                                const float* __restrict__ s2v, const float* __restrict__ t2v,
                                                float* __restrict__ psum, float* __restrict__ psq,
                                                float* __restrict__ xe2){
  int gw = (blockIdx.x*256 + threadIdx.x)>>6;    // < 2048
  int l = threadIdx.x&63;
  int half = gw&1;
  int o = (half<<6)+l;
  float wr[128];
  #pragma unroll
  for(int c=0;c<128;c+=4){ float4 v = *(const float4*)&w2[(size_t)o*128+c]; wr[c]=v.x; wr[c+1]=v.y; wr[c+2]=v.z; wr[c+3]=v.w; }
  float sA=s1v[l], tA=t1v[l], sB=s1v[64+l], tB=t1v[64+l];
  float sc2=0.f, sh2=0.f;
  if(MODE==1){ sc2=s2v[o]; sh2=t2v[o]; }
  float s=0.f, ss=0.f;
  for(int wp=gw; wp<NP*2; wp+=2048){
    int p = wp>>1;
    const float* hs = hbuf + (size_t)p*KK*128;
    float mx = -3.4e38f;
    for(int k=0;k<KK;k++){
      float ya = lrelu(fmaf(hs[k*128 + l],     sA, tA));
      float yb = lrelu(fmaf(hs[k*128 + 64 + l], sB, tB));
      float a0=0.f, a1=0.f;
      #pragma unroll
      for(int c=0;c<64;c+=2){
        a0 = fmaf(rlane(ya,c),   wr[c],   a0);
        a1 = fmaf(rlane(ya,c+1), wr[c+1], a1);
      }
      #pragma unroll
      for(int c=0;c<64;c+=2){
        a0 = fmaf(rlane(yb,c),   wr[64+c],   a0);
        a1 = fmaf(rlane(yb,c+1), wr[64+c+1], a1);
      }
      float h = a0+a1;
      if(MODE==0){ s+=h; ss+=h*h; }
      else mx = fmaxf(mx, lrelu(fmaf(h,sc2,sh2)));
    }
    if(MODE==1) xe2[(size_t)p*128+o]=mx;
  }
  if(MODE==0){
    psum[(size_t)gw*128+o]=s; psq[(size_t)gw*128+o]=ss;
    psum[(size_t)gw*128+((1-half)<<6)+l]=0.f; psq[(size_t)gw*128+((1-half)<<6)+l]=0.f;
  }
}

// ---------------- hcat = [xe2 (flat-reinterpret) ; kernels_r] ----------------
__global__ void k_hcat(const float* __restrict__ xe2, const float* __restrict__ kr, float* __restrict__ hcat){
  size_t i = (size_t)blockIdx.x*256 + threadIdx.x;   // < 2*256*4096
  int b = (int)(i>>20);
  int r = (int)(i & 1048575);
  int ch = r>>12;
  float v;
  if(ch < 128) v = xe2[(size_t)b*524288 + r];
  else         v = kr [(size_t)(b*128 + (ch-128))*4096 + (r&4095)];
  hcat[i] = v;
}

// ---------------- generic small transpose (O,C)->(C,O) ----------------
__global__ void k_transpose(const float* __restrict__ w, float* __restrict__ wT, int O, int C){
  int i = blockIdx.x*256 + threadIdx.x;
  if(i >= O*C) return;
  int o = i / C, c = i % C;
  wT[(size_t)c*O + o] = w[i];
}

// ---------------- tiled cbr GEMM: out[b][o][s] = sum_c act(in[b][c][s]) * wT[c][o] ----------------
// BM x BN tile, BK=32, 256 threads, (BM/16)x(BN/16) acc per thread.
// Per-thread fragments are 4-consecutive-float chunks at (t&15)*4 / (t>>4)*4 (+g*64):
// LDS reads are <=2-way bank-aliased (free).
template<int BM, int BN>
__global__ __launch_bounds__(256) void k_cbr_t(const float* __restrict__ in, const float* __restrict__ wT,
                                               const float* __restrict__ sc, const float* __restrict__ sh,
                                               float* __restrict__ out, int Cin, int Cout){
  constexpr int BK = 32;
  constexpr int RT = BM/16, CT = BN/16;
  constexpr int GM = BM/64, GN = BN/64;
  constexpr int LA = BK*BM/256, LB = BK*BN/256;
  __shared__ float As[BK*BM], Bs[BK*BN];
  int t = threadIdx.x;
  int tx = t&15, ty = t>>4;
  int n0 = blockIdx.x*BN;            // global column in [0, 8192)
  int m0 = blockIdx.y*BM;            // output channel
  int b = n0>>12;
  int scol = n0 & 4095;
  const float* ib = in + (size_t)b*Cin*4096 + scol;
  bool doact = (sc != nullptr);
  float acc[RT][CT];
  #pragma unroll
  for(int i=0;i<RT;i++){
    #pragma unroll
    for(int j=0;j<CT;j++) acc[i][j]=0.f;
  }
  for(int kc=0; kc<Cin; kc+=BK){
    __syncthreads();
    #pragma unroll
    for(int i=0;i<LA;i++){
      int e = t + i*256;
      int k = e/BM, m = e - k*BM;
      As[e] = wT[(size_t)(kc+k)*Cout + m0 + m];
    }
    #pragma unroll
    for(int i=0;i<LB;i++){
      int e = t + i*256;
      int k = e/BN, n = e - k*BN;
      float v = ib[(size_t)(kc+k)*4096 + n];
      if(doact) v = lrelu(fmaf(v, sc[kc+k], sh[kc+k]));
      Bs[e] = v;
    }
    __syncthreads();
    #pragma unroll 4
    for(int k=0;k<BK;k++){
      float av[RT], bv[CT];
      #pragma unroll
      for(int g=0; g<GM; g++){
        float4 v = *(const float4*)&As[k*BM + g*64 + ty*4];
        av[g*4]=v.x; av[g*4+1]=v.y; av[g*4+2]=v.z; av[g*4+3]=v.w;
      }
      #pragma unroll
      for(int g=0; g<GN; g++){
        float4 v = *(const float4*)&Bs[k*BN + g*64 + tx*4];
        bv[g*4]=v.x; bv[g*4+1]=v.y; bv[g*4+2]=v.z; bv[g*4+3]=v.w;
      }
      #pragma unroll
      for(int i=0;i<RT;i++){
        #pragma unroll
        for(int j=0;j<CT;j++) acc[i][j] = fmaf(av[i], bv[j], acc[i][j]);
      }
    }
  }
  float* ob = out + (size_t)b*Cout*4096 + scol;
  #pragma unroll
  for(int i=0;i<RT;i++){
    int row = (i>>2)*64 + ty*4 + (i&3);
    #pragma unroll
    for(int g=0; g<GN; g++){
      *(float4*)&ob[(size_t)(m0+row)*4096 + g*64 + tx*4] =
        make_float4(acc[i][g*4], acc[i][g*4+1], acc[i][g*4+2], acc[i][g*4+3]);
    }
  }
}

// ---------------- per-channel stats over (b, s) for cbr layers ----------------
__global__ void k_cstats(const float* __restrict__ buf, int C, const float* __restrict__ g,
                         const float* __restrict__ be, float* __restrict__ sc, float* __restrict__ sh){
  int o = blockIdx.x, t = threadIdx.x;
  float s=0.f, q=0.f;
  for(int i=t;i<8192;i+=256){
    int b=i>>12, ss_=i&4095;
    float v = buf[(size_t)(b*C+o)*4096 + ss_];
    s+=v; q+=v*v;
  }
  __shared__ float ls[256], lq[256];
  ls[t]=s; lq[t]=q; __syncthreads();
  for(int st=128; st; st>>=1){ if(t<st){ ls[t]+=ls[t+st]; lq[t]+=lq[t+st]; } __syncthreads(); }
  if(t==0){
    float mu = ls[0]/8192.f;
    float var = lq[0]/8192.f - mu*mu; if(var<0.f) var=0.f;
    float s1 = g[o]*rsqrtf(var + EPSB);
    sc[o]=s1; sh[o]=be[o]-mu*s1;
  }
}

// ---------------- final layer: 9 outputs + partial spatial max ----------------
__global__ __launch_bounds__(256) void k_final4(const float* __restrict__ c3, const float* __restrict__ w4T,
                                                const float* __restrict__ sc, const float* __restrict__ sh,
                                                float* __restrict__ pmax){
  int b = blockIdx.y, st = blockIdx.x;
  int t = threadIdx.x; int s = st*256 + t;
  float acc[9];
  #pragma unroll
  for(int j=0;j<9;j++) acc[j]=0.f;
  const float* ib = c3 + (size_t)b*256*4096;
  for(int c=0;c<256;c++){
    float x = lrelu(fmaf(ib[(size_t)c*4096+s], sc[c], sh[c]));
    #pragma unroll
    for(int j=0;j<9;j++) acc[j]=fmaf(x, w4T[c*9+j], acc[j]);
  }
  __shared__ float red[256];
  for(int j=0;j<9;j++){
    red[t]=acc[j]; __syncthreads();
    for(int stp=128; stp; stp>>=1){ if(t<stp) red[t]=fmaxf(red[t],red[t+stp]); __syncthreads(); }
    if(t==0) pmax[(b*16+st)*9 + j]=red[0];
    __syncthreads();
  }
}

__global__ void k_out(const float* __restrict__ pmax, float* __restrict__ out){
  int i = threadIdx.x;
  if(i<18){
    int b=i/9, o=i%9;
    float m=-3.4e38f;
    for(int k=0;k<16;k++) m=fmaxf(m, pmax[(b*16+k)*9+o]);
    out[i] = m + ((o==0||o==4||o==8)?1.f:0.f);
  }
}

// ---------------- launch ----------------
extern "C" void kernel_launch(void* const* d_in, const int* in_sizes, int n_in,
                              void* d_out, int out_size, void* d_ws, size_t ws_size,
                              hipStream_t stream){
  const float* x    = (const float*)d_in[0];
  const float* kc   = (const float*)d_in[1];
  const float* e1w1 = (const float*)d_in[2];
  const float* e1g1 = (const float*)d_in[3];
  const float* e1b1 = (const float*)d_in[4];
  const float* e1w2 = (const float*)d_in[5];
  const float* e1g2 = (const float*)d_in[6];
  const float* e1b2 = (const float*)d_in[7];
  const float* e2w1 = (const float*)d_in[8];
  const float* e2g1 = (const float*)d_in[9];
  const float* e2b1 = (const float*)d_in[10];
  const float* e2w2 = (const float*)d_in[11];
  const float* e2g2 = (const float*)d_in[12];
  const float* e2b2 = (const float*)d_in[13];
  const float* w1   = (const float*)d_in[14];
  const float* g1   = (const float*)d_in[15];
  const float* b1   = (const float*)d_in[16];
  const float* w2   = (const float*)d_in[17];
  const float* g2   = (const float*)d_in[18];
  const float* b2   = (const float*)d_in[19];
  const float* w3   = (const float*)d_in[20];
  const float* g3   = (const float*)d_in[21];
  const float* b3   = (const float*)d_in[22];
  const float* w4   = (const float*)d_in[23];

  if(ws_size < 156061696ull) return;   // need ~149 MB scratch
  char* ws = (char*)d_ws;
  float* pts   = (float*)(ws + 0);
  float* xe0   = (float*)(ws + 98304);
  float* sqp   = (float*)(ws + 196608);
  float* sqe   = (float*)(ws + 229376);
  float* sqx1  = (float*)(ws + 262144);
  float* xe1   = (float*)(ws + 294912);
  float* xe1T  = (float*)(ws + 2392064);
  float* xe2   = (float*)(ws + 4489216);
  float* kr    = (float*)(ws + 8683520);
  int*   idxP  = (int*)  (ws + 12877824);
  int*   idx1  = (int*)  (ws + 13926400);
  int*   idx2  = (int*)  (ws + 14974976);
  float* psum  = (float*)(ws + 16023552);
  float* psq   = (float*)(ws + 17072128);
  float* par   = (float*)(ws + 18120704);
  float* pmax  = (float*)(ws + 18153472);
  float* wT1   = (float*)(ws + 18157568);
  float* wT2   = (float*)(ws + 19206144);
  float* wT3   = (float*)(ws + 21303296);
  float* wT4   = (float*)(ws + 21827584);
  float* hbuf  = (float*)(ws + 21843968);   // 134217728 B; also: D matrix; also cbr buffers

  float* e1s1 = par+0;    float* e1t1 = par+64;
  float* e1s2 = par+128;  float* e1t2 = par+192;
  float* e2s1 = par+256;  float* e2t1 = par+384;
  float* e2s2 = par+512;  float* e2t2 = par+640;
  float* c1s  = par+768;  float* c1t  = par+1792;
  float* c2s  = par+2816; float* c2t  = par+3328;
  float* c3s  = par+3840; float* c3t  = par+4096;

  float* hcat  = hbuf;                       // 2*256*4096
  float* c1out = hbuf + 2097152;             // 2*1024*4096
  float* c2out = hbuf + 10485760;            // 2*512*4096
  float* c3out = hbuf + 14680064;            // 2*256*4096

  hipLaunchKernelGGL(k_prep, dim3(32), dim3(256), 0, stream, x, pts, xe0, sqp, sqe);
  hipLaunchKernelGGL(k_knn3, dim3(4096), dim3(128), 0, stream, pts, sqp, idxP);
  hipLaunchKernelGGL(k_knn3, dim3(4096), dim3(128), 0, stream, xe0, sqe, idx1);
  hipLaunchKernelGGL(k_gauss, dim3(8192), dim3(128), 0, stream, pts, sqp, idxP, kc, kr);

  // edge-conv 1
  hipLaunchKernelGGL(k_ec1_h1, dim3(256), dim3(256), 0, stream, xe0, idx1, e1w1, hbuf, psum, psq);
  hipLaunchKernelGGL(k_fin, dim3(64), dim3(256), 0, stream, psum, psq, 1024, 64, 262144.f, e1g1, e1b1, e1s1, e1t1);
  hipLaunchKernelGGL(k_ec1_h2, dim3(256), dim3(256), 0, stream, hbuf, e1w2, e1s1, e1t1, psum, psq);
  hipLaunchKernelGGL(k_fin, dim3(64), dim3(256), 0, stream, psum, psq, 1024, 64, 262144.f, e1g2, e1b2, e1s2, e1t2);
  hipLaunchKernelGGL(k_ec1_max, dim3(2048), dim3(256), 0, stream, hbuf, e1s2, e1t2, xe1, xe1T, sqx1);

  // knn on 64-d features
  hipLaunchKernelGGL(k_dgemm, dim3(32,32,2), dim3(256), 0, stream, xe1T, sqx1, hbuf);
  hipLaunchKernelGGL(k_knn_sel, dim3(4096), dim3(128), 0, stream, hbuf, idx2);

  // edge-conv 2
  hipLaunchKernelGGL(k_ec2_h1, dim3(512), dim3(256), 0, stream, xe1, idx2, e2w1, hbuf, psum, psq);
  hipLaunchKernelGGL(k_fin, dim3(128), dim3(256), 0, stream, psum, psq, 2048, 128, 262144.f, e2g1, e2b1, e2s1, e2t1);
  hipLaunchKernelGGL(k_ec2_h2<0>, dim3(512), dim3(256), 0, stream, hbuf, e2w2, e2s1, e2t1, e2s2, e2t2, psum, psq, xe2);
  hipLaunchKernelGGL(k_fin, dim3(128), dim3(256), 0, stream, psum, psq, 2048, 128, 262144.f, e2g2, e2b2, e2s2, e2t2);
  hipLaunchKernelGGL(k_ec2_h2<1>, dim3(512), dim3(256), 0, stream, hbuf, e2w2, e2s1, e2t1, e2s2, e2t2, psum, psq, xe2);

  // concat + cbr chain
  hipLaunchKernelGGL(k_hcat, dim3(8192), dim3(256), 0, stream, xe2, kr, hcat);
  hipLaunchKernelGGL(k_transpose, dim3((1024*256+255)/256), dim3(256), 0, stream, w1, wT1, 1024, 256);
  hipLaunchKernelGGL(k_transpose, dim3((512*1024+255)/256), dim3(256), 0, stream, w2, wT2, 512, 1024);
  hipLaunchKernelGGL(k_transpose, dim3((256*512+255)/256), dim3(256), 0, stream, w3, wT3, 256, 512);
  hipLaunchKernelGGL(k_transpose, dim3((9*256+255)/256), dim3(256), 0, stream, w4, wT4, 9, 256);

  hipLaunchKernelGGL((k_cbr_t<128,128>), dim3(64,8), dim3(256), 0, stream, hcat, wT1, (const float*)nullptr, (const float*)nullptr, c1out, 256, 1024);
  hipLaunchKernelGGL(k_cstats, dim3(1024), dim3(256), 0, stream, c1out, 1024, g1, b1, c1s, c1t);
  hipLaunchKernelGGL((k_cbr_t<64,128>), dim3(64,8), dim3(256), 0, stream, c1out, wT2, c1s, c1t, c2out, 1024, 512);
  hipLaunchKernelGGL(k_cstats, dim3(512), dim3(256), 0, stream, c2out, 512, g2, b2, c2s, c2t);
  hipLaunchKernelGGL((k_cbr_t<64,64>), dim3(128,4), dim3(256), 0, stream, c2out, wT3, c2s, c2t, c3out, 512, 256);
  hipLaunchKernelGGL(k_cstats, dim3(256), dim3(256), 0, stream, c3out, 256, g3, b3, c3s, c3t);
  hipLaunchKernelGGL(k_final4, dim3(16,2), dim3(256), 0, stream, c3out, wT4, c3s, c3t, pmax);
  hipLaunchKernelGGL(k_out, dim3(1), dim3(32), 0, stream, pmax, (float*)d_out);
}

// Round 4
// 1527.717 us; speedup vs baseline: 1.6248x; 1.2969x over previous
//
#include <hip/hip_runtime.h>
#include <math.h>

#define WN 4096
#define NP 8192
#define KK 32
#define EPSB 1e-5f

__device__ __forceinline__ float lrelu(float x){ return fmaxf(x, 0.01f*x); }
__device__ __forceinline__ float rlane(float v, int c){
  return __int_as_float(__builtin_amdgcn_readlane(__float_as_int(v), c));
}

// ---------------- prep: build pts (b,p,3), xe0 (b,p,3) and squared norms ----------------
__global__ void k_prep(const float* __restrict__ x, float* __restrict__ pts, float* __restrict__ xe0,
                       float* __restrict__ sqp, float* __restrict__ sqe){
  int i = blockIdx.x*256 + threadIdx.x;
  if(i >= NP) return;
  int b = i>>12, p = i&4095;
  const float* xb = x + b*12288;
  float a0 = xb[p], a1 = xb[4096+p], a2 = xb[8192+p];
  pts[i*3+0]=a0; pts[i*3+1]=a1; pts[i*3+2]=a2;
  sqp[i] = (a0*a0 + a1*a1) + a2*a2;
  float e0 = xb[p*3+0], e1 = xb[p*3+1], e2 = xb[p*3+2];
  xe0[i*3+0]=e0; xe0[i*3+1]=e1; xe0[i*3+2]=e2;
  sqe[i] = (e0*e0 + e1*e1) + e2*e2;
}

// ---------------- top-32 selection over a wave-private LDS column set ----------------
__device__ __forceinline__ void select32(float* dw, float gv[8], int gi[8], int l, int* __restrict__ out){
  for(int r=0;r<KK;r++){
    float v = gv[0]; int mi = gi[0];
    #pragma unroll
    for(int g=1; g<8; g++){ if(gv[g] < v || (gv[g]==v && gi[g]<mi)){ v=gv[g]; mi=gi[g]; } }
    #pragma unroll
    for(int off=32; off; off>>=1){
      float ov = __shfl_xor(v, off);
      int om = __shfl_xor(mi, off);
      if(ov < v || (ov==v && om<mi)){ v=ov; mi=om; }
    }
    if(l==0) out[r]=mi;
    if((mi&63)==l){
      dw[mi] = 3.4e38f;
      int gsel = mi>>9;
      #pragma unroll
      for(int g=0; g<8; g++){
        if(g == gsel){
          float bv = 3.4e38f; int bi = l;
          #pragma unroll
          for(int jj=0;jj<8;jj++){
            int m2 = l + (((g<<3)+jj)<<6);
            float dv = dw[m2];
            if(dv < bv){ bv=dv; bi=m2; }
          }
          gv[g]=bv; gi[g]=bi;
        }
      }
    }
  }
}

// ---------------- KNN for 3-channel points (fused distance + select) ----------------
__global__ __launch_bounds__(128) void k_knn3(const float* __restrict__ pnt, const float* __restrict__ sq,
                                              int* __restrict__ idx){
  __shared__ float dist[2][4096];
  int w = threadIdx.x>>6, l = threadIdx.x&63;
  int q = blockIdx.x*2 + w;
  int b = q>>12, qr = q&4095;
  const float* pb = pnt + (size_t)b*WN*3;
  const float* sb = sq + b*WN;
  float q0=pb[qr*3], q1=pb[qr*3+1], q2=pb[qr*3+2];
  float sqq = sb[qr];
  float* dw = dist[w];
  float gv[8]; int gi[8];
  #pragma unroll
  for(int g=0;g<8;g++){ gv[g]=3.4e38f; gi[g]=0; }
  #pragma unroll
  for(int j=0;j<64;j++){
    int m = l + (j<<6);
    float d0=pb[m*3], d1=pb[m*3+1], d2=pb[m*3+2];
    float dot = q0*d0 + q1*d1 + q2*d2;
    float d = (sqq - 2.0f*dot) + sb[m];
    dw[m] = d;
    if(d < gv[j>>3]){ gv[j>>3]=d; gi[j>>3]=m; }
  }
  select32(dw, gv, gi, l, idx + (size_t)q*KK);
}

// ---------------- KNN selection from precomputed D ----------------
__global__ __launch_bounds__(128) void k_knn_sel(const float* __restrict__ D, int* __restrict__ idx){
  __shared__ float dist[2][4096];
  int w = threadIdx.x>>6, l = threadIdx.x&63;
  int q = blockIdx.x*2 + w;
  int b = q>>12, qr = q&4095;
  const float* row = D + ((size_t)b<<24) + ((size_t)qr<<12);
  float* dw = dist[w];
  float gv[8]; int gi[8];
  #pragma unroll
  for(int g=0;g<8;g++){ gv[g]=3.4e38f; gi[g]=0; }
  #pragma unroll
  for(int j=0;j<64;j++){
    int m = l + (j<<6);
    float d = row[m];
    dw[m] = d;
    if(d < gv[j>>3]){ gv[j>>3]=d; gi[j>>3]=m; }
  }
  select32(dw, gv, gi, l, idx + (size_t)q*KK);
}

// ---------------- gaussian kernel conv: block per point, thread per center ----------------
__global__ __launch_bounds__(128) void k_gauss(const float* __restrict__ pts, const float* __restrict__ sqp,
                                               const int* __restrict__ idxP, const float* __restrict__ cen,
                                               float* __restrict__ kout){
  __shared__ float nbx[KK], nby[KK], nbz[KK], nsq[KK];
  int p = blockIdx.x; int b = p>>12; int t = threadIdx.x;
  if(t < KK){
    int id = idxP[(size_t)p*KK + t] + (b<<12);
    nbx[t]=pts[id*3]; nby[t]=pts[id*3+1]; nbz[t]=pts[id*3+2];
    nsq[t]=sqp[id];
  }
  __syncthreads();
  float c0=cen[t*3], c1=cen[t*3+1], c2=cen[t*3+2];
  float sqc=(c0*c0+c1*c1)+c2*c2;
  float acc=0.f;
  #pragma unroll
  for(int k=0;k<KK;k++){
    float dot = nbx[k]*c0 + nby[k]*c1 + nbz[k]*c2;
    float d = (nsq[k] - 2.0f*dot) + sqc;
    acc += expf(-0.5f*d);
  }
  kout[(size_t)((b<<7)+t)*4096 + (p&4095)] = acc;
}

// ---------------- finalize BN stats from per-wave partials ----------------
__global__ void k_fin(const float* __restrict__ psum, const float* __restrict__ psq, int NW, int C, float Nn,
                      const float* __restrict__ g, const float* __restrict__ be,
                      float* __restrict__ sc, float* __restrict__ sh){
  int o = blockIdx.x, t = threadIdx.x;
  float s=0.f, q=0.f;
  for(int w=t; w<NW; w+=256){ s += psum[(size_t)w*C+o]; q += psq[(size_t)w*C+o]; }
  __shared__ float ls[256], lq[256];
  ls[t]=s; lq[t]=q; __syncthreads();
  for(int st=128; st; st>>=1){ if(t<st){ ls[t]+=ls[t+st]; lq[t]+=lq[t+st]; } __syncthreads(); }
  if(t==0){
    float mu = ls[0]/Nn;
    float var = lq[0]/Nn - mu*mu; if(var<0.f) var=0.f;
    float s1 = g[o]*rsqrtf(var + EPSB);
    sc[o]=s1; sh[o]=be[o]-mu*s1;
  }
}

// ---------------- edge-conv 1 (Cin=3 -> 64) ----------------
__global__ __launch_bounds__(256) void k_ec1_h1(const float* __restrict__ xe0, const int* __restrict__ idx1,
                                                const float* __restrict__ w1, float* __restrict__ hbuf,
                                                float* __restrict__ psum, float* __restrict__ psq){
  int wid = (blockIdx.x*256 + threadIdx.x)>>6;   // < 1024
  int l = threadIdx.x&63;
  float wr[6];
  #pragma unroll
  for(int c=0;c<6;c++) wr[c] = w1[l*6+c];
  float s=0.f, ss=0.f;
  for(int p=wid; p<NP; p+=1024){
    int bb = (p>>12)<<12;
    float x0=xe0[p*3], x1=xe0[p*3+1], x2=xe0[p*3+2];
    const int* ip = idx1 + (size_t)p*KK;
    for(int k=0;k<KK;k++){
      int id = ip[k];
      const float* nb = xe0 + (size_t)(bb+id)*3;
      float h = wr[0]*(nb[0]-x0) + wr[1]*(nb[1]-x1) + wr[2]*(nb[2]-x2)
              + wr[3]*x0 + wr[4]*x1 + wr[5]*x2;
      hbuf[(size_t)(p*KK+k)*64 + l] = h;
      s += h; ss += h*h;
    }
  }
  psum[(size_t)wid*64+l]=s; psq[(size_t)wid*64+l]=ss;
}

__global__ __launch_bounds__(256) void k_ec1_h2(float* __restrict__ hbuf, const float* __restrict__ w2,
                                                const float* __restrict__ sc, const float* __restrict__ sh,
                                                float* __restrict__ psum, float* __restrict__ psq){
  int wid = (blockIdx.x*256 + threadIdx.x)>>6;   // < 1024
  int l = threadIdx.x&63;
  float wr[64];
  #pragma unroll
  for(int c=0;c<64;c+=4){ float4 v = *(const float4*)&w2[l*64+c]; wr[c]=v.x; wr[c+1]=v.y; wr[c+2]=v.z; wr[c+3]=v.w; }
  float s1=sc[l], t1=sh[l];
  float s=0.f, ss=0.f;
  for(int smp=wid; smp<NP*KK; smp+=1024){
    float y = lrelu(fmaf(hbuf[(size_t)smp*64+l], s1, t1));
    float a0=0.f, a1=0.f;
    #pragma unroll
    for(int c=0;c<64;c+=2){
      a0 = fmaf(rlane(y,c),   wr[c],   a0);
      a1 = fmaf(rlane(y,c+1), wr[c+1], a1);
    }
    float h2 = a0+a1;
    hbuf[(size_t)smp*64+l] = h2;
    s+=h2; ss+=h2*h2;
  }
  psum[(size_t)wid*64+l]=s; psq[(size_t)wid*64+l]=ss;
}

__global__ __launch_bounds__(256) void k_ec1_max(const float* __restrict__ hbuf, const float* __restrict__ sc,
                                                 const float* __restrict__ sh, float* __restrict__ xe1,
                                                 float* __restrict__ xe1T, float* __restrict__ sqx){
  int p = (blockIdx.x*256 + threadIdx.x)>>6;     // < 8192
  int l = threadIdx.x&63;
  float s1=sc[l], t1=sh[l];
  float mx = -3.4e38f;
  for(int k=0;k<KK;k++){
    float h = hbuf[(size_t)(p*KK+k)*64 + l];
    mx = fmaxf(mx, lrelu(fmaf(h,s1,t1)));
  }
  xe1[(size_t)p*64+l]=mx;
  int b=p>>12, pr=p&4095;
  xe1T[(size_t)(b*64+l)*4096 + pr]=mx;
  float sq = mx*mx;
  #pragma unroll
  for(int off=32; off; off>>=1) sq += __shfl_xor(sq, off);
  if(l==0) sqx[p]=sq;
}

// ---------------- D = sq_n - 2 X X^T + sq_m  (per batch, 128x128 tiles, 8x8/thread) ----------------
__global__ __launch_bounds__(256) void k_dgemm(const float* __restrict__ xT, const float* __restrict__ sqx,
                                               float* __restrict__ D){
  __shared__ float As[32*128], Bs2[32*128];
  int b = blockIdx.z;
  int m0 = blockIdx.y*128, n0 = blockIdx.x*128;
  int t = threadIdx.x;
  int tx = t&15, ty = t>>4;
  const float* xb = xT + (size_t)b*64*4096;
  float acc[8][8];
  #pragma unroll
  for(int i=0;i<8;i++){
    #pragma unroll
    for(int j=0;j<8;j++) acc[i][j]=0.f;
  }
  for(int kc=0;kc<2;kc++){
    __syncthreads();
    #pragma unroll
    for(int i=0;i<16;i++){
      int e = t + (i<<8);
      int k = e>>7, mm = e&127;
      As[k*128+mm]  = xb[(size_t)(kc*32+k)*4096 + m0+mm];
      Bs2[k*128+mm] = xb[(size_t)(kc*32+k)*4096 + n0+mm];
    }
    __syncthreads();
    #pragma unroll 4
    for(int k=0;k<32;k++){
      float av[8], bv[8];
      float4 A0 = *(float4*)&As[k*128 + ty*8];
      float4 A1 = *(float4*)&As[k*128 + ty*8+4];
      float4 B0 = *(float4*)&Bs2[k*128 + tx*8];
      float4 B1 = *(float4*)&Bs2[k*128 + tx*8+4];
      av[0]=A0.x; av[1]=A0.y; av[2]=A0.z; av[3]=A0.w; av[4]=A1.x; av[5]=A1.y; av[6]=A1.z; av[7]=A1.w;
      bv[0]=B0.x; bv[1]=B0.y; bv[2]=B0.z; bv[3]=B0.w; bv[4]=B1.x; bv[5]=B1.y; bv[6]=B1.z; bv[7]=B1.w;
      #pragma unroll
      for(int i=0;i<8;i++){
        #pragma unroll
        for(int j=0;j<8;j++) acc[i][j] = fmaf(av[i], bv[j], acc[i][j]);
      }
    }
  }
  const float* sb = sqx + (b<<12);
  float* Db = D + ((size_t)b<<24);
  #pragma unroll
  for(int i=0;i<8;i++){
    int r = m0 + ty*8 + i;
    float sqa = sb[r];
    float o[8];
    #pragma unroll
    for(int j=0;j<8;j++) o[j] = (sqa - 2.0f*acc[i][j]) + sb[n0+tx*8+j];
    *(float4*)&Db[(size_t)r*4096 + n0+tx*8]   = make_float4(o[0],o[1],o[2],o[3]);
    *(float4*)&Db[(size_t)r*4096 + n0+tx*8+4] = make_float4(o[4],o[5],o[6],o[7]);
  }
}

// ---------------- edge-conv 2 pass 1: gather-GEMM h1 = W1*[nbr-x ; x], write h1T[c][s], stats ----------------
// grid 2048, 256 thr. Block: 128 samples (4 points), all 128 out-ch, K=128.
__global__ __launch_bounds__(256) void k_ec2g1(const float* __restrict__ xe1, const int* __restrict__ idx2,
                                               const float* __restrict__ w1T, float* __restrict__ h1T,
                                               float* __restrict__ psum, float* __restrict__ psq){
  __shared__ float As[32*128];
  __shared__ float Bs[32*132];
  __shared__ float cts[256];
  __shared__ int nid[128];
  int t = threadIdx.x;
  int blk = blockIdx.x;
  int s0 = blk*128;
  int pbase = s0>>5;
  int bb = (s0>>17)<<12;
  if(t<128) nid[t] = (idx2[s0 + t] + bb)<<6;      // pre-scaled float row offset
  cts[t] = xe1[(size_t)(pbase + (t>>6))*64 + (t&63)];
  int tx = t&15, ty = t>>4;
  float acc[8][8];
  #pragma unroll
  for(int i=0;i<8;i++){
    #pragma unroll
    for(int j=0;j<8;j++) acc[i][j]=0.f;
  }
  for(int kc=0;kc<128;kc+=32){
    __syncthreads();
    #pragma unroll
    for(int i=0;i<16;i++){
      int e = t + (i<<8);
      int k = e>>7, m = e&127;
      As[e] = w1T[(kc+k)*128 + m];
    }
    #pragma unroll
    for(int i=0;i<4;i++){
      int e = t + (i<<8);
      int kg = e&7, n = e>>3;
      int c0 = (kc&63) + (kg<<2);
      float4 v;
      if(kc < 64){
        float4 a = *(const float4*)&xe1[nid[n] + c0];
        float4 c = *(const float4*)&cts[((n>>5)<<6) + c0];
        v = make_float4(a.x-c.x, a.y-c.y, a.z-c.z, a.w-c.w);
      } else {
        v = *(const float4*)&cts[((n>>5)<<6) + c0];
      }
      int base = (kg<<2)*132 + n;
      Bs[base]=v.x; Bs[base+132]=v.y; Bs[base+264]=v.z; Bs[base+396]=v.w;
    }
    __syncthreads();
    #pragma unroll 4
    for(int k=0;k<32;k++){
      float av[8], bv[8];
      float4 A0 = *(const float4*)&As[k*128 + ty*4];
      float4 A1 = *(const float4*)&As[k*128 + 64 + ty*4];
      float4 B0 = *(const float4*)&Bs[k*132 + tx*4];
      float4 B1 = *(const float4*)&Bs[k*132 + 64 + tx*4];
      av[0]=A0.x; av[1]=A0.y; av[2]=A0.z; av[3]=A0.w; av[4]=A1.x; av[5]=A1.y; av[6]=A1.z; av[7]=A1.w;
      bv[0]=B0.x; bv[1]=B0.y; bv[2]=B0.z; bv[3]=B0.w; bv[4]=B1.x; bv[5]=B1.y; bv[6]=B1.z; bv[7]=B1.w;
      #pragma unroll
      for(int i=0;i<8;i++){
        #pragma unroll
        for(int j=0;j<8;j++) acc[i][j] = fmaf(av[i], bv[j], acc[i][j]);
      }
    }
  }
  float* ob = h1T + s0;
  #pragma unroll
  for(int i=0;i<8;i++){
    int row = ((i>>2)<<6) + ty*4 + (i&3);
    *(float4*)&ob[(size_t)row*262144 + tx*4]      = make_float4(acc[i][0],acc[i][1],acc[i][2],acc[i][3]);
    *(float4*)&ob[(size_t)row*262144 + 64 + tx*4] = make_float4(acc[i][4],acc[i][5],acc[i][6],acc[i][7]);
    float sr = ((acc[i][0]+acc[i][1])+(acc[i][2]+acc[i][3])) + ((acc[i][4]+acc[i][5])+(acc[i][6]+acc[i][7]));
    float sq = ((acc[i][0]*acc[i][0]+acc[i][1]*acc[i][1])+(acc[i][2]*acc[i][2]+acc[i][3]*acc[i][3]))
             + ((acc[i][4]*acc[i][4]+acc[i][5]*acc[i][5])+(acc[i][6]*acc[i][6]+acc[i][7]*acc[i][7]));
    #pragma unroll
    for(int off=1; off<16; off<<=1){ sr += __shfl_xor(sr, off); sq += __shfl_xor(sq, off); }
    if(tx==0){ psum[(size_t)blk*128+row]=sr; psq[(size_t)blk*128+row]=sq; }
  }
}

// ---------------- edge-conv 2 pass 2: h2 = W2*lrelu(BN(h1)), stats + per-point max ----------------
__global__ __launch_bounds__(256) void k_ec2g2(const float* __restrict__ h1T, const float* __restrict__ w2T,
                                               const float* __restrict__ s1, const float* __restrict__ t1,
                                               float* __restrict__ h2max, float* __restrict__ psum,
                                               float* __restrict__ psq){
  __shared__ float As[32*128];
  __shared__ float Bs[32*132];
  int t = threadIdx.x;
  int blk = blockIdx.x;
  int s0 = blk*128;
  int pbase = s0>>5;
  int tx = t&15, ty = t>>4;
  float acc[8][8];
  #pragma unroll
  for(int i=0;i<8;i++){
    #pragma unroll
    for(int j=0;j<8;j++) acc[i][j]=0.f;
  }
  for(int kc=0;kc<128;kc+=32){
    __syncthreads();
    #pragma unroll
    for(int i=0;i<16;i++){
      int e = t + (i<<8);
      int k = e>>7, m = e&127;
      As[e] = w2T[(kc+k)*128 + m];
    }
    #pragma unroll
    for(int i=0;i<4;i++){
      int e = t + (i<<8);
      int k = e>>5, n4 = (e&31)<<2;
      float4 v = *(const float4*)&h1T[(size_t)(kc+k)*262144 + s0 + n4];
      float a = s1[kc+k], h = t1[kc+k];
      v.x = lrelu(fmaf(v.x,a,h)); v.y = lrelu(fmaf(v.y,a,h));
      v.z = lrelu(fmaf(v.z,a,h)); v.w = lrelu(fmaf(v.w,a,h));
      *(float4*)&Bs[k*132 + n4] = v;
    }
    __syncthreads();
    #pragma unroll 4
    for(int k=0;k<32;k++){
      float av[8], bv[8];
      float4 A0 = *(const float4*)&As[k*128 + ty*4];
      float4 A1 = *(const float4*)&As[k*128 + 64 + ty*4];
      float4 B0 = *(const float4*)&Bs[k*132 + tx*4];
      float4 B1 = *(const float4*)&Bs[k*132 + 64 + tx*4];
      av[0]=A0.x; av[1]=A0.y; av[2]=A0.z; av[3]=A0.w; av[4]=A1.x; av[5]=A1.y; av[6]=A1.z; av[7]=A1.w;
      bv[0]=B0.x; bv[1]=B0.y; bv[2]=B0.z; bv[3]=B0.w; bv[4]=B1.x; bv[5]=B1.y; bv[6]=B1.z; bv[7]=B1.w;
      #pragma unroll
      for(int i=0;i<8;i++){
        #pragma unroll
        for(int j=0;j<8;j++) acc[i][j] = fmaf(av[i], bv[j], acc[i][j]);
      }
    }
  }
  #pragma unroll
  for(int i=0;i<8;i++){
    int row = ((i>>2)<<6) + ty*4 + (i&3);
    float sr = ((acc[i][0]+acc[i][1])+(acc[i][2]+acc[i][3])) + ((acc[i][4]+acc[i][5])+(acc[i][6]+acc[i][7]));
    float sq = ((acc[i][0]*acc[i][0]+acc[i][1]*acc[i][1])+(acc[i][2]*acc[i][2]+acc[i][3]*acc[i][3]))
             + ((acc[i][4]*acc[i][4]+acc[i][5]*acc[i][5])+(acc[i][6]*acc[i][6]+acc[i][7]*acc[i][7]));
    #pragma unroll
    for(int off=1; off<16; off<<=1){ sr += __shfl_xor(sr, off); sq += __shfl_xor(sq, off); }
    if(tx==0){ psum[(size_t)blk*128+row]=sr; psq[(size_t)blk*128+row]=sq; }
    // per-point max: cols tx*4.. within point pbase+(tx>>3) (g=0), pbase+2+(tx>>3) (g=1)
    float m0 = fmaxf(fmaxf(acc[i][0],acc[i][1]), fmaxf(acc[i][2],acc[i][3]));
    float m1 = fmaxf(fmaxf(acc[i][4],acc[i][5]), fmaxf(acc[i][6],acc[i][7]));
    #pragma unroll
    for(int off=1; off<8; off<<=1){ m0 = fmaxf(m0, __shfl_xor(m0, off)); m1 = fmaxf(m1, __shfl_xor(m1, off)); }
    if((tx&7)==0){
      int pl = pbase + (tx>>3);
      h2max[(size_t)pl*128 + row]     = m0;
      h2max[(size_t)(pl+2)*128 + row] = m1;
    }
  }
}

// ---------------- xe2 = lrelu(BN(h2max)) in-place ----------------
__global__ void k_xe2fin(float* __restrict__ xe2, const float* __restrict__ s2, const float* __restrict__ t2){
  int i = blockIdx.x*256 + threadIdx.x;   // < NP*128 = 1048576
  if(i >= NP*128) return;
  int o = i&127;
  xe2[i] = lrelu(fmaf(xe2[i], s2[o], t2[o]));
}

// ---------------- hcat = [xe2 (flat-reinterpret) ; kernels_r] ----------------
__global__ void k_hcat(const float* __restrict__ xe2, const float* __restrict__ kr, float* __restrict__ hcat){
  size_t i = (size_t)blockIdx.x*256 + threadIdx.x;   // < 2*256*4096
  int b = (int)(i>>20);
  int r = (int)(i & 1048575);
  int ch = r>>12;
  float v;
  if(ch < 128) v = xe2[(size_t)b*524288 + r];
  else         v = kr [(size_t)(b*128 + (ch-128))*4096 + (r&4095)];
  hcat[i] = v;
}

// ---------------- generic small transpose (O,C)->(C,O) ----------------
__global__ void k_transpose(const float* __restrict__ w, float* __restrict__ wT, int O, int C){
  int i = blockIdx.x*256 + threadIdx.x;
  if(i >= O*C) return;
  int o = i / C, c = i % C;
  wT[(size_t)c*O + o] = w[i];
}

// ---------------- tiled cbr GEMM ----------------
template<int BM, int BN>
__global__ __launch_bounds__(256) void k_cbr_t(const float* __restrict__ in, const float* __restrict__ wT,
                                               const float* __restrict__ sc, const float* __restrict__ sh,
                                               float* __restrict__ out, int Cin, int Cout){
  constexpr int BK = 32;
  constexpr int RT = BM/16, CT = BN/16;
  constexpr int GM = BM/64, GN = BN/64;
  constexpr int LA = BK*BM/256, LB = BK*BN/256;
  __shared__ float As[BK*BM], Bs[BK*BN];
  int t = threadIdx.x;
  int tx = t&15, ty = t>>4;
  int n0 = blockIdx.x*BN;
  int m0 = blockIdx.y*BM;
  int b = n0>>12;
  int scol = n0 & 4095;
  const float* ib = in + (size_t)b*Cin*4096 + scol;
  bool doact = (sc != nullptr);
  float acc[RT][CT];
  #pragma unroll
  for(int i=0;i<RT;i++){
    #pragma unroll
    for(int j=0;j<CT;j++) acc[i][j]=0.f;
  }
  for(int kc=0; kc<Cin; kc+=BK){
    __syncthreads();
    #pragma unroll
    for(int i=0;i<LA;i++){
      int e = t + i*256;
      int k = e/BM, m = e - k*BM;
      As[e] = wT[(size_t)(kc+k)*Cout + m0 + m];
    }
    #pragma unroll
    for(int i=0;i<LB;i++){
      int e = t + i*256;
      int k = e/BN, n = e - k*BN;
      float v = ib[(size_t)(kc+k)*4096 + n];
      if(doact) v = lrelu(fmaf(v, sc[kc+k], sh[kc+k]));
      Bs[e] = v;
    }
    __syncthreads();
    #pragma unroll 4
    for(int k=0;k<BK;k++){
      float av[RT], bv[CT];
      #pragma unroll
      for(int g=0; g<GM; g++){
        float4 v = *(const float4*)&As[k*BM + g*64 + ty*4];
        av[g*4]=v.x; av[g*4+1]=v.y; av[g*4+2]=v.z; av[g*4+3]=v.w;
      }
      #pragma unroll
      for(int g=0; g<GN; g++){
        float4 v = *(const float4*)&Bs[k*BN + g*64 + tx*4];
        bv[g*4]=v.x; bv[g*4+1]=v.y; bv[g*4+2]=v.z; bv[g*4+3]=v.w;
      }
      #pragma unroll
      for(int i=0;i<RT;i++){
        #pragma unroll
        for(int j=0;j<CT;j++) acc[i][j] = fmaf(av[i], bv[j], acc[i][j]);
      }
    }
  }
  float* ob = out + (size_t)b*Cout*4096 + scol;
  #pragma unroll
  for(int i=0;i<RT;i++){
    int row = (i>>2)*64 + ty*4 + (i&3);
    #pragma unroll
    for(int g=0; g<GN; g++){
      *(float4*)&ob[(size_t)(m0+row)*4096 + g*64 + tx*4] =
        make_float4(acc[i][g*4], acc[i][g*4+1], acc[i][g*4+2], acc[i][g*4+3]);
    }
  }
}

// ---------------- per-channel stats over (b, s) for cbr layers ----------------
__global__ void k_cstats(const float* __restrict__ buf, int C, const float* __restrict__ g,
                         const float* __restrict__ be, float* __restrict__ sc, float* __restrict__ sh){
  int o = blockIdx.x, t = threadIdx.x;
  float s=0.f, q=0.f;
  for(int i=t;i<8192;i+=256){
    int b=i>>12, ss_=i&4095;
    float v = buf[(size_t)(b*C+o)*4096 + ss_];
    s+=v; q+=v*v;
  }
  __shared__ float ls[256], lq[256];
  ls[t]=s; lq[t]=q; __syncthreads();
  for(int st=128; st; st>>=1){ if(t<st){ ls[t]+=ls[t+st]; lq[t]+=lq[t+st]; } __syncthreads(); }
  if(t==0){
    float mu = ls[0]/8192.f;
    float var = lq[0]/8192.f - mu*mu; if(var<0.f) var=0.f;
    float s1 = g[o]*rsqrtf(var + EPSB);
    sc[o]=s1; sh[o]=be[o]-mu*s1;
  }
}

// ---------------- final layer: 9 outputs + partial spatial max ----------------
__global__ __launch_bounds__(256) void k_final4(const float* __restrict__ c3, const float* __restrict__ w4T,
                                                const float* __restrict__ sc, const float* __restrict__ sh,
                                                float* __restrict__ pmax){
  int b = blockIdx.y, st = blockIdx.x;
  int t = threadIdx.x; int s = st*256 + t;
  float acc[9];
  #pragma unroll
  for(int j=0;j<9;j++) acc[j]=0.f;
  const float* ib = c3 + (size_t)b*256*4096;
  for(int c=0;c<256;c++){
    float x = lrelu(fmaf(ib[(size_t)c*4096+s], sc[c], sh[c]));
    #pragma unroll
    for(int j=0;j<9;j++) acc[j]=fmaf(x, w4T[c*9+j], acc[j]);
  }
  __shared__ float red[256];
  for(int j=0;j<9;j++){
    red[t]=acc[j]; __syncthreads();
    for(int stp=128; stp; stp>>=1){ if(t<stp) red[t]=fmaxf(red[t],red[t+stp]); __syncthreads(); }
    if(t==0) pmax[(b*16+st)*9 + j]=red[0];
    __syncthreads();
  }
}

__global__ void k_out(const float* __restrict__ pmax, float* __restrict__ out){
  int i = threadIdx.x;
  if(i<18){
    int b=i/9, o=i%9;
    float m=-3.4e38f;
    for(int k=0;k<16;k++) m=fmaxf(m, pmax[(b*16+k)*9+o]);
    out[i] = m + ((o==0||o==4||o==8)?1.f:0.f);
  }
}

// ---------------- launch ----------------
extern "C" void kernel_launch(void* const* d_in, const int* in_sizes, int n_in,
                              void* d_out, int out_size, void* d_ws, size_t ws_size,
                              hipStream_t stream){
  const float* x    = (const float*)d_in[0];
  const float* kc   = (const float*)d_in[1];
  const float* e1w1 = (const float*)d_in[2];
  const float* e1g1 = (const float*)d_in[3];
  const float* e1b1 = (const float*)d_in[4];
  const float* e1w2 = (const float*)d_in[5];
  const float* e1g2 = (const float*)d_in[6];
  const float* e1b2 = (const float*)d_in[7];
  const float* e2w1 = (const float*)d_in[8];
  const float* e2g1 = (const float*)d_in[9];
  const float* e2b1 = (const float*)d_in[10];
  const float* e2w2 = (const float*)d_in[11];
  const float* e2g2 = (const float*)d_in[12];
  const float* e2b2 = (const float*)d_in[13];
  const float* w1   = (const float*)d_in[14];
  const float* g1   = (const float*)d_in[15];
  const float* b1   = (const float*)d_in[16];
  const float* w2   = (const float*)d_in[17];
  const float* g2   = (const float*)d_in[18];
  const float* b2   = (const float*)d_in[19];
  const float* w3   = (const float*)d_in[20];
  const float* g3   = (const float*)d_in[21];
  const float* b3   = (const float*)d_in[22];
  const float* w4   = (const float*)d_in[23];

  if(ws_size < 156061696ull) return;
  char* ws = (char*)d_ws;
  float* pts   = (float*)(ws + 0);
  float* xe0   = (float*)(ws + 98304);
  float* sqp   = (float*)(ws + 196608);
  float* sqe   = (float*)(ws + 229376);
  float* sqx1  = (float*)(ws + 262144);
  float* xe1   = (float*)(ws + 294912);
  float* xe1T  = (float*)(ws + 2392064);
  float* xe2   = (float*)(ws + 4489216);
  float* kr    = (float*)(ws + 8683520);
  int*   idxP  = (int*)  (ws + 12877824);
  int*   idx1  = (int*)  (ws + 13926400);
  int*   idx2  = (int*)  (ws + 14974976);
  float* psum  = (float*)(ws + 16023552);
  float* psq   = (float*)(ws + 17072128);
  float* par   = (float*)(ws + 18120704);
  float* pmax  = (float*)(ws + 18153472);
  float* wT1   = (float*)(ws + 18157568);
  float* wT2   = (float*)(ws + 19206144);
  float* wT3   = (float*)(ws + 21303296);
  float* wT4   = (float*)(ws + 21827584);
  float* hbuf  = (float*)(ws + 21843968);
  // e2 weight transposes reuse the pts/xe0 region (dead by the time they're written)
  float* ew1T  = (float*)(ws + 0);
  float* ew2T  = (float*)(ws + 65536);

  float* e1s1 = par+0;    float* e1t1 = par+64;
  float* e1s2 = par+128;  float* e1t2 = par+192;
  float* e2s1 = par+256;  float* e2t1 = par+384;
  float* e2s2 = par+512;  float* e2t2 = par+640;
  float* c1s  = par+768;  float* c1t  = par+1792;
  float* c2s  = par+2816; float* c2t  = par+3328;
  float* c3s  = par+3840; float* c3t  = par+4096;

  float* hcat  = hbuf;
  float* c1out = hbuf + 2097152;
  float* c2out = hbuf + 10485760;
  float* c3out = hbuf + 14680064;

  hipLaunchKernelGGL(k_prep, dim3(32), dim3(256), 0, stream, x, pts, xe0, sqp, sqe);
  hipLaunchKernelGGL(k_knn3, dim3(4096), dim3(128), 0, stream, pts, sqp, idxP);
  hipLaunchKernelGGL(k_knn3, dim3(4096), dim3(128), 0, stream, xe0, sqe, idx1);
  hipLaunchKernelGGL(k_gauss, dim3(8192), dim3(128), 0, stream, pts, sqp, idxP, kc, kr);

  // edge-conv 1
  hipLaunchKernelGGL(k_ec1_h1, dim3(256), dim3(256), 0, stream, xe0, idx1, e1w1, hbuf, psum, psq);
  hipLaunchKernelGGL(k_fin, dim3(64), dim3(256), 0, stream, psum, psq, 1024, 64, 262144.f, e1g1, e1b1, e1s1, e1t1);
  hipLaunchKernelGGL(k_ec1_h2, dim3(256), dim3(256), 0, stream, hbuf, e1w2, e1s1, e1t1, psum, psq);
  hipLaunchKernelGGL(k_fin, dim3(64), dim3(256), 0, stream, psum, psq, 1024, 64, 262144.f, e1g2, e1b2, e1s2, e1t2);
  hipLaunchKernelGGL(k_ec1_max, dim3(2048), dim3(256), 0, stream, hbuf, e1s2, e1t2, xe1, xe1T, sqx1);

  // knn on 64-d features
  hipLaunchKernelGGL(k_dgemm, dim3(32,32,2), dim3(256), 0, stream, xe1T, sqx1, hbuf);
  hipLaunchKernelGGL(k_knn_sel, dim3(4096), dim3(128), 0, stream, hbuf, idx2);

  // edge-conv 2 (GEMM formulation, fused stats+max; second h2 pass eliminated)
  hipLaunchKernelGGL(k_transpose, dim3(64), dim3(256), 0, stream, e2w1, ew1T, 128, 128);
  hipLaunchKernelGGL(k_transpose, dim3(64), dim3(256), 0, stream, e2w2, ew2T, 128, 128);
  hipLaunchKernelGGL(k_ec2g1, dim3(2048), dim3(256), 0, stream, xe1, idx2, ew1T, hbuf, psum, psq);
  hipLaunchKernelGGL(k_fin, dim3(128), dim3(256), 0, stream, psum, psq, 2048, 128, 262144.f, e2g1, e2b1, e2s1, e2t1);
  hipLaunchKernelGGL(k_ec2g2, dim3(2048), dim3(256), 0, stream, hbuf, ew2T, e2s1, e2t1, xe2, psum, psq);
  hipLaunchKernelGGL(k_fin, dim3(128), dim3(256), 0, stream, psum, psq, 2048, 128, 262144.f, e2g2, e2b2, e2s2, e2t2);
  hipLaunchKernelGGL(k_xe2fin, dim3(4096), dim3(256), 0, stream, xe2, e2s2, e2t2);

  // concat + cbr chain
  hipLaunchKernelGGL(k_hcat, dim3(8192), dim3(256), 0, stream, xe2, kr, hcat);
  hipLaunchKernelGGL(k_transpose, dim3((1024*256+255)/256), dim3(256), 0, stream, w1, wT1, 1024, 256);
  hipLaunchKernelGGL(k_transpose, dim3((512*1024+255)/256), dim3(256), 0, stream, w2, wT2, 512, 1024);
  hipLaunchKernelGGL(k_transpose, dim3((256*512+255)/256), dim3(256), 0, stream, w3, wT3, 256, 512);
  hipLaunchKernelGGL(k_transpose, dim3((9*256+255)/256), dim3(256), 0, stream, w4, wT4, 9, 256);

  hipLaunchKernelGGL((k_cbr_t<128,128>), dim3(64,8), dim3(256), 0, stream, hcat, wT1, (const float*)nullptr, (const float*)nullptr, c1out, 256, 1024);
  hipLaunchKernelGGL(k_cstats, dim3(1024), dim3(256), 0, stream, c1out, 1024, g1, b1, c1s, c1t);
  hipLaunchKernelGGL((k_cbr_t<64,128>), dim3(64,8), dim3(256), 0, stream, c1out, wT2, c1s, c1t, c2out, 1024, 512);
  hipLaunchKernelGGL(k_cstats, dim3(512), dim3(256), 0, stream, c2out, 512, g2, b2, c2s, c2t);
  hipLaunchKernelGGL((k_cbr_t<64,64>), dim3(128,4), dim3(256), 0, stream, c2out, wT3, c2s, c2t, c3out, 512, 256);
  hipLaunchKernelGGL(k_cstats, dim3(256), dim3(256), 0, stream, c3out, 256, g3, b3, c3s, c3t);
  hipLaunchKernelGGL(k_final4, dim3(16,2), dim3(256), 0, stream, c3out, wT4, c3s, c3t, pmax);
  hipLaunchKernelGGL(k_out, dim3(1), dim3(32), 0, stream, pmax, (float*)d_out);
}

// Round 5
// 1245.438 us; speedup vs baseline: 1.9931x; 1.2267x over previous
//
#include <hip/hip_runtime.h>
#include <math.h>

#define WN 4096
#define NP 8192
#define KK 32
#define EPSB 1e-5f

typedef __attribute__((ext_vector_type(8))) short s8v;
typedef __attribute__((ext_vector_type(4))) float f4v;

__device__ __forceinline__ float lrelu(float x){ return fmaxf(x, 0.01f*x); }
__device__ __forceinline__ float rlane(float v, int c){
  return __int_as_float(__builtin_amdgcn_readlane(__float_as_int(v), c));
}
__device__ __forceinline__ short f2bf(float f){
  unsigned u = __float_as_uint(f);
  u = (u + 0x7fffu + ((u>>16)&1u)) >> 16;
  return (short)u;
}

// ---------------- prep: build pts (b,p,3), xe0 (b,p,3) and squared norms ----------------
__global__ void k_prep(const float* __restrict__ x, float* __restrict__ pts, float* __restrict__ xe0,
                       float* __restrict__ sqp, float* __restrict__ sqe){
  int i = blockIdx.x*256 + threadIdx.x;
  if(i >= NP) return;
  int b = i>>12, p = i&4095;
  const float* xb = x + b*12288;
  float a0 = xb[p], a1 = xb[4096+p], a2 = xb[8192+p];
  pts[i*3+0]=a0; pts[i*3+1]=a1; pts[i*3+2]=a2;
  sqp[i] = (a0*a0 + a1*a1) + a2*a2;
  float e0 = xb[p*3+0], e1 = xb[p*3+1], e2 = xb[p*3+2];
  xe0[i*3+0]=e0; xe0[i*3+1]=e1; xe0[i*3+2]=e2;
  sqe[i] = (e0*e0 + e1*e1) + e2*e2;
}

// ---------------- top-32 selection over a wave-private LDS column set ----------------
__device__ __forceinline__ void select32(float* dw, float gv[8], int gi[8], int l, int* __restrict__ out){
  for(int r=0;r<KK;r++){
    float v = gv[0]; int mi = gi[0];
    #pragma unroll
    for(int g=1; g<8; g++){ if(gv[g] < v || (gv[g]==v && gi[g]<mi)){ v=gv[g]; mi=gi[g]; } }
    #pragma unroll
    for(int off=32; off; off>>=1){
      float ov = __shfl_xor(v, off);
      int om = __shfl_xor(mi, off);
      if(ov < v || (ov==v && om<mi)){ v=ov; mi=om; }
    }
    if(l==0) out[r]=mi;
    if((mi&63)==l){
      dw[mi] = 3.4e38f;
      int gsel = mi>>9;
      #pragma unroll
      for(int g=0; g<8; g++){
        if(g == gsel){
          float bv = 3.4e38f; int bi = l;
          #pragma unroll
          for(int jj=0;jj<8;jj++){
            int m2 = l + (((g<<3)+jj)<<6);
            float dv = dw[m2];
            if(dv < bv){ bv=dv; bi=m2; }
          }
          gv[g]=bv; gi[g]=bi;
        }
      }
    }
  }
}

// ---------------- KNN for 3-channel points (fused distance + select) ----------------
__global__ __launch_bounds__(128) void k_knn3(const float* __restrict__ pnt, const float* __restrict__ sq,
                                              int* __restrict__ idx){
  __shared__ float dist[2][4096];
  int w = threadIdx.x>>6, l = threadIdx.x&63;
  int q = blockIdx.x*2 + w;
  int b = q>>12, qr = q&4095;
  const float* pb = pnt + (size_t)b*WN*3;
  const float* sb = sq + b*WN;
  float q0=pb[qr*3], q1=pb[qr*3+1], q2=pb[qr*3+2];
  float sqq = sb[qr];
  float* dw = dist[w];
  float gv[8]; int gi[8];
  #pragma unroll
  for(int g=0;g<8;g++){ gv[g]=3.4e38f; gi[g]=0; }
  #pragma unroll
  for(int j=0;j<64;j++){
    int m = l + (j<<6);
    float d0=pb[m*3], d1=pb[m*3+1], d2=pb[m*3+2];
    float dot = q0*d0 + q1*d1 + q2*d2;
    float d = (sqq - 2.0f*dot) + sb[m];
    dw[m] = d;
    if(d < gv[j>>3]){ gv[j>>3]=d; gi[j>>3]=m; }
  }
  select32(dw, gv, gi, l, idx + (size_t)q*KK);
}

// ---------------- KNN selection from precomputed D ----------------
__global__ __launch_bounds__(128) void k_knn_sel(const float* __restrict__ D, int* __restrict__ idx){
  __shared__ float dist[2][4096];
  int w = threadIdx.x>>6, l = threadIdx.x&63;
  int q = blockIdx.x*2 + w;
  int b = q>>12, qr = q&4095;
  const float* row = D + ((size_t)b<<24) + ((size_t)qr<<12);
  float* dw = dist[w];
  float gv[8]; int gi[8];
  #pragma unroll
  for(int g=0;g<8;g++){ gv[g]=3.4e38f; gi[g]=0; }
  #pragma unroll
  for(int j=0;j<64;j++){
    int m = l + (j<<6);
    float d = row[m];
    dw[m] = d;
    if(d < gv[j>>3]){ gv[j>>3]=d; gi[j>>3]=m; }
  }
  select32(dw, gv, gi, l, idx + (size_t)q*KK);
}

// ---------------- gaussian kernel conv: block per point, thread per center ----------------
__global__ __launch_bounds__(128) void k_gauss(const float* __restrict__ pts, const float* __restrict__ sqp,
                                               const int* __restrict__ idxP, const float* __restrict__ cen,
                                               float* __restrict__ kout){
  __shared__ float nbx[KK], nby[KK], nbz[KK], nsq[KK];
  int p = blockIdx.x; int b = p>>12; int t = threadIdx.x;
  if(t < KK){
    int id = idxP[(size_t)p*KK + t] + (b<<12);
    nbx[t]=pts[id*3]; nby[t]=pts[id*3+1]; nbz[t]=pts[id*3+2];
    nsq[t]=sqp[id];
  }
  __syncthreads();
  float c0=cen[t*3], c1=cen[t*3+1], c2=cen[t*3+2];
  float sqc=(c0*c0+c1*c1)+c2*c2;
  float acc=0.f;
  #pragma unroll
  for(int k=0;k<KK;k++){
    float dot = nbx[k]*c0 + nby[k]*c1 + nbz[k]*c2;
    float d = (nsq[k] - 2.0f*dot) + sqc;
    acc += expf(-0.5f*d);
  }
  kout[(size_t)((b<<7)+t)*4096 + (p&4095)] = acc;
}

// ---------------- finalize BN stats from per-wave partials ----------------
__global__ void k_fin(const float* __restrict__ psum, const float* __restrict__ psq, int NW, int C, float Nn,
                      const float* __restrict__ g, const float* __restrict__ be,
                      float* __restrict__ sc, float* __restrict__ sh){
  int o = blockIdx.x, t = threadIdx.x;
  float s=0.f, q=0.f;
  for(int w=t; w<NW; w+=256){ s += psum[(size_t)w*C+o]; q += psq[(size_t)w*C+o]; }
  __shared__ float ls[256], lq[256];
  ls[t]=s; lq[t]=q; __syncthreads();
  for(int st=128; st; st>>=1){ if(t<st){ ls[t]+=ls[t+st]; lq[t]+=lq[t+st]; } __syncthreads(); }
  if(t==0){
    float mu = ls[0]/Nn;
    float var = lq[0]/Nn - mu*mu; if(var<0.f) var=0.f;
    float s1 = g[o]*rsqrtf(var + EPSB);
    sc[o]=s1; sh[o]=be[o]-mu*s1;
  }
}

// ---------------- edge-conv 1 (Cin=3 -> 64) ----------------
__global__ __launch_bounds__(256) void k_ec1_h1(const float* __restrict__ xe0, const int* __restrict__ idx1,
                                                const float* __restrict__ w1, float* __restrict__ hbuf,
                                                float* __restrict__ psum, float* __restrict__ psq){
  int wid = (blockIdx.x*256 + threadIdx.x)>>6;   // < 1024
  int l = threadIdx.x&63;
  float wr[6];
  #pragma unroll
  for(int c=0;c<6;c++) wr[c] = w1[l*6+c];
  float s=0.f, ss=0.f;
  for(int p=wid; p<NP; p+=1024){
    int bb = (p>>12)<<12;
    float x0=xe0[p*3], x1=xe0[p*3+1], x2=xe0[p*3+2];
    const int* ip = idx1 + (size_t)p*KK;
    for(int k=0;k<KK;k++){
      int id = ip[k];
      const float* nb = xe0 + (size_t)(bb+id)*3;
      float h = wr[0]*(nb[0]-x0) + wr[1]*(nb[1]-x1) + wr[2]*(nb[2]-x2)
              + wr[3]*x0 + wr[4]*x1 + wr[5]*x2;
      hbuf[(size_t)(p*KK+k)*64 + l] = h;
      s += h; ss += h*h;
    }
  }
  psum[(size_t)wid*64+l]=s; psq[(size_t)wid*64+l]=ss;
}

__global__ __launch_bounds__(256) void k_ec1_h2(float* __restrict__ hbuf, const float* __restrict__ w2,
                                                const float* __restrict__ sc, const float* __restrict__ sh,
                                                float* __restrict__ psum, float* __restrict__ psq){
  int wid = (blockIdx.x*256 + threadIdx.x)>>6;   // < 1024
  int l = threadIdx.x&63;
  float wr[64];
  #pragma unroll
  for(int c=0;c<64;c+=4){ float4 v = *(const float4*)&w2[l*64+c]; wr[c]=v.x; wr[c+1]=v.y; wr[c+2]=v.z; wr[c+3]=v.w; }
  float s1=sc[l], t1=sh[l];
  float s=0.f, ss=0.f;
  for(int smp=wid; smp<NP*KK; smp+=1024){
    float y = lrelu(fmaf(hbuf[(size_t)smp*64+l], s1, t1));
    float a0=0.f, a1=0.f;
    #pragma unroll
    for(int c=0;c<64;c+=2){
      a0 = fmaf(rlane(y,c),   wr[c],   a0);
      a1 = fmaf(rlane(y,c+1), wr[c+1], a1);
    }
    float h2 = a0+a1;
    hbuf[(size_t)smp*64+l] = h2;
    s+=h2; ss+=h2*h2;
  }
  psum[(size_t)wid*64+l]=s; psq[(size_t)wid*64+l]=ss;
}

__global__ __launch_bounds__(256) void k_ec1_max(const float* __restrict__ hbuf, const float* __restrict__ sc,
                                                 const float* __restrict__ sh, float* __restrict__ xe1,
                                                 float* __restrict__ xe1T, float* __restrict__ sqx){
  int p = (blockIdx.x*256 + threadIdx.x)>>6;     // < 8192
  int l = threadIdx.x&63;
  float s1=sc[l], t1=sh[l];
  float mx = -3.4e38f;
  for(int k=0;k<KK;k++){
    float h = hbuf[(size_t)(p*KK+k)*64 + l];
    mx = fmaxf(mx, lrelu(fmaf(h,s1,t1)));
  }
  xe1[(size_t)p*64+l]=mx;
  int b=p>>12, pr=p&4095;
  xe1T[(size_t)(b*64+l)*4096 + pr]=mx;
  float sq = mx*mx;
  #pragma unroll
  for(int off=32; off; off>>=1) sq += __shfl_xor(sq, off);
  if(l==0) sqx[p]=sq;
}

// ---------------- D = sq_n - 2 X X^T + sq_m  (per batch, 128x128 tiles, 8x8/thread) ----------------
__global__ __launch_bounds__(256) void k_dgemm(const float* __restrict__ xT, const float* __restrict__ sqx,
                                               float* __restrict__ D){
  __shared__ float As[32*128], Bs2[32*128];
  int b = blockIdx.z;
  int m0 = blockIdx.y*128, n0 = blockIdx.x*128;
  int t = threadIdx.x;
  int tx = t&15, ty = t>>4;
  const float* xb = xT + (size_t)b*64*4096;
  float acc[8][8];
  #pragma unroll
  for(int i=0;i<8;i++){
    #pragma unroll
    for(int j=0;j<8;j++) acc[i][j]=0.f;
  }
  for(int kc=0;kc<2;kc++){
    __syncthreads();
    #pragma unroll
    for(int i=0;i<16;i++){
      int e = t + (i<<8);
      int k = e>>7, mm = e&127;
      As[k*128+mm]  = xb[(size_t)(kc*32+k)*4096 + m0+mm];
      Bs2[k*128+mm] = xb[(size_t)(kc*32+k)*4096 + n0+mm];
    }
    __syncthreads();
    #pragma unroll 4
    for(int k=0;k<32;k++){
      float av[8], bv[8];
      float4 A0 = *(float4*)&As[k*128 + ty*8];
      float4 A1 = *(float4*)&As[k*128 + ty*8+4];
      float4 B0 = *(float4*)&Bs2[k*128 + tx*8];
      float4 B1 = *(float4*)&Bs2[k*128 + tx*8+4];
      av[0]=A0.x; av[1]=A0.y; av[2]=A0.z; av[3]=A0.w; av[4]=A1.x; av[5]=A1.y; av[6]=A1.z; av[7]=A1.w;
      bv[0]=B0.x; bv[1]=B0.y; bv[2]=B0.z; bv[3]=B0.w; bv[4]=B1.x; bv[5]=B1.y; bv[6]=B1.z; bv[7]=B1.w;
      #pragma unroll
      for(int i=0;i<8;i++){
        #pragma unroll
        for(int j=0;j<8;j++) acc[i][j] = fmaf(av[i], bv[j], acc[i][j]);
      }
    }
  }
  const float* sb = sqx + (b<<12);
  float* Db = D + ((size_t)b<<24);
  #pragma unroll
  for(int i=0;i<8;i++){
    int r = m0 + ty*8 + i;
    float sqa = sb[r];
    float o[8];
    #pragma unroll
    for(int j=0;j<8;j++) o[j] = (sqa - 2.0f*acc[i][j]) + sb[n0+tx*8+j];
    *(float4*)&Db[(size_t)r*4096 + n0+tx*8]   = make_float4(o[0],o[1],o[2],o[3]);
    *(float4*)&Db[(size_t)r*4096 + n0+tx*8+4] = make_float4(o[4],o[5],o[6],o[7]);
  }
}

// ---------------- edge-conv 2 pass 1: gather-GEMM h1 = W1*[nbr-x ; x], write h1T[c][s], stats ----------------
__global__ __launch_bounds__(256) void k_ec2g1(const float* __restrict__ xe1, const int* __restrict__ idx2,
                                               const float* __restrict__ w1T, float* __restrict__ h1T,
                                               float* __restrict__ psum, float* __restrict__ psq){
  __shared__ float As[32*128];
  __shared__ float Bs[32*132];
  __shared__ float cts[256];
  __shared__ int nid[128];
  int t = threadIdx.x;
  int blk = blockIdx.x;
  int s0 = blk*128;
  int pbase = s0>>5;
  int bb = (s0>>17)<<12;
  if(t<128) nid[t] = (idx2[s0 + t] + bb)<<6;      // pre-scaled float row offset
  cts[t] = xe1[(size_t)(pbase + (t>>6))*64 + (t&63)];
  int tx = t&15, ty = t>>4;
  float acc[8][8];
  #pragma unroll
  for(int i=0;i<8;i++){
    #pragma unroll
    for(int j=0;j<8;j++) acc[i][j]=0.f;
  }
  for(int kc=0;kc<128;kc+=32){
    __syncthreads();
    #pragma unroll
    for(int i=0;i<16;i++){
      int e = t + (i<<8);
      int k = e>>7, m = e&127;
      As[e] = w1T[(kc+k)*128 + m];
    }
    #pragma unroll
    for(int i=0;i<4;i++){
      int e = t + (i<<8);
      int kg = e&7, n = e>>3;
      int c0 = (kc&63) + (kg<<2);
      float4 v;
      if(kc < 64){
        float4 a = *(const float4*)&xe1[nid[n] + c0];
        float4 c = *(const float4*)&cts[((n>>5)<<6) + c0];
        v = make_float4(a.x-c.x, a.y-c.y, a.z-c.z, a.w-c.w);
      } else {
        v = *(const float4*)&cts[((n>>5)<<6) + c0];
      }
      int base = (kg<<2)*132 + n;
      Bs[base]=v.x; Bs[base+132]=v.y; Bs[base+264]=v.z; Bs[base+396]=v.w;
    }
    __syncthreads();
    #pragma unroll 4
    for(int k=0;k<32;k++){
      float av[8], bv[8];
      float4 A0 = *(const float4*)&As[k*128 + ty*4];
      float4 A1 = *(const float4*)&As[k*128 + 64 + ty*4];
      float4 B0 = *(const float4*)&Bs[k*132 + tx*4];
      float4 B1 = *(const float4*)&Bs[k*132 + 64 + tx*4];
      av[0]=A0.x; av[1]=A0.y; av[2]=A0.z; av[3]=A0.w; av[4]=A1.x; av[5]=A1.y; av[6]=A1.z; av[7]=A1.w;
      bv[0]=B0.x; bv[1]=B0.y; bv[2]=B0.z; bv[3]=B0.w; bv[4]=B1.x; bv[5]=B1.y; bv[6]=B1.z; bv[7]=B1.w;
      #pragma unroll
      for(int i=0;i<8;i++){
        #pragma unroll
        for(int j=0;j<8;j++) acc[i][j] = fmaf(av[i], bv[j], acc[i][j]);
      }
    }
  }
  float* ob = h1T + s0;
  #pragma unroll
  for(int i=0;i<8;i++){
    int row = ((i>>2)<<6) + ty*4 + (i&3);
    *(float4*)&ob[(size_t)row*262144 + tx*4]      = make_float4(acc[i][0],acc[i][1],acc[i][2],acc[i][3]);
    *(float4*)&ob[(size_t)row*262144 + 64 + tx*4] = make_float4(acc[i][4],acc[i][5],acc[i][6],acc[i][7]);
    float sr = ((acc[i][0]+acc[i][1])+(acc[i][2]+acc[i][3])) + ((acc[i][4]+acc[i][5])+(acc[i][6]+acc[i][7]));
    float sq = ((acc[i][0]*acc[i][0]+acc[i][1]*acc[i][1])+(acc[i][2]*acc[i][2]+acc[i][3]*acc[i][3]))
             + ((acc[i][4]*acc[i][4]+acc[i][5]*acc[i][5])+(acc[i][6]*acc[i][6]+acc[i][7]*acc[i][7]));
    #pragma unroll
    for(int off=1; off<16; off<<=1){ sr += __shfl_xor(sr, off); sq += __shfl_xor(sq, off); }
    if(tx==0){ psum[(size_t)blk*128+row]=sr; psq[(size_t)blk*128+row]=sq; }
  }
}

// ---------------- edge-conv 2 pass 2: h2 = W2*lrelu(BN(h1)), stats + per-point max ----------------
__global__ __launch_bounds__(256) void k_ec2g2(const float* __restrict__ h1T, const float* __restrict__ w2T,
                                               const float* __restrict__ s1, const float* __restrict__ t1,
                                               float* __restrict__ h2max, float* __restrict__ psum,
                                               float* __restrict__ psq){
  __shared__ float As[32*128];
  __shared__ float Bs[32*132];
  int t = threadIdx.x;
  int blk = blockIdx.x;
  int s0 = blk*128;
  int pbase = s0>>5;
  int tx = t&15, ty = t>>4;
  float acc[8][8];
  #pragma unroll
  for(int i=0;i<8;i++){
    #pragma unroll
    for(int j=0;j<8;j++) acc[i][j]=0.f;
  }
  for(int kc=0;kc<128;kc+=32){
    __syncthreads();
    #pragma unroll
    for(int i=0;i<16;i++){
      int e = t + (i<<8);
      int k = e>>7, m = e&127;
      As[e] = w2T[(kc+k)*128 + m];
    }
    #pragma unroll
    for(int i=0;i<4;i++){
      int e = t + (i<<8);
      int k = e>>5, n4 = (e&31)<<2;
      float4 v = *(const float4*)&h1T[(size_t)(kc+k)*262144 + s0 + n4];
      float a = s1[kc+k], h = t1[kc+k];
      v.x = lrelu(fmaf(v.x,a,h)); v.y = lrelu(fmaf(v.y,a,h));
      v.z = lrelu(fmaf(v.z,a,h)); v.w = lrelu(fmaf(v.w,a,h));
      *(float4*)&Bs[k*132 + n4] = v;
    }
    __syncthreads();
    #pragma unroll 4
    for(int k=0;k<32;k++){
      float av[8], bv[8];
      float4 A0 = *(const float4*)&As[k*128 + ty*4];
      float4 A1 = *(const float4*)&As[k*128 + 64 + ty*4];
      float4 B0 = *(const float4*)&Bs[k*132 + tx*4];
      float4 B1 = *(const float4*)&Bs[k*132 + 64 + tx*4];
      av[0]=A0.x; av[1]=A0.y; av[2]=A0.z; av[3]=A0.w; av[4]=A1.x; av[5]=A1.y; av[6]=A1.z; av[7]=A1.w;
      bv[0]=B0.x; bv[1]=B0.y; bv[2]=B0.z; bv[3]=B0.w; bv[4]=B1.x; bv[5]=B1.y; bv[6]=B1.z; bv[7]=B1.w;
      #pragma unroll
      for(int i=0;i<8;i++){
        #pragma unroll
        for(int j=0;j<8;j++) acc[i][j] = fmaf(av[i], bv[j], acc[i][j]);
      }
    }
  }
  #pragma unroll
  for(int i=0;i<8;i++){
    int row = ((i>>2)<<6) + ty*4 + (i&3);
    float sr = ((acc[i][0]+acc[i][1])+(acc[i][2]+acc[i][3])) + ((acc[i][4]+acc[i][5])+(acc[i][6]+acc[i][7]));
    float sq = ((acc[i][0]*acc[i][0]+acc[i][1]*acc[i][1])+(acc[i][2]*acc[i][2]+acc[i][3]*acc[i][3]))
             + ((acc[i][4]*acc[i][4]+acc[i][5]*acc[i][5])+(acc[i][6]*acc[i][6]+acc[i][7]*acc[i][7]));
    #pragma unroll
    for(int off=1; off<16; off<<=1){ sr += __shfl_xor(sr, off); sq += __shfl_xor(sq, off); }
    if(tx==0){ psum[(size_t)blk*128+row]=sr; psq[(size_t)blk*128+row]=sq; }
    float m0 = fmaxf(fmaxf(acc[i][0],acc[i][1]), fmaxf(acc[i][2],acc[i][3]));
    float m1 = fmaxf(fmaxf(acc[i][4],acc[i][5]), fmaxf(acc[i][6],acc[i][7]));
    #pragma unroll
    for(int off=1; off<8; off<<=1){ m0 = fmaxf(m0, __shfl_xor(m0, off)); m1 = fmaxf(m1, __shfl_xor(m1, off)); }
    if((tx&7)==0){
      int pl = pbase + (tx>>3);
      h2max[(size_t)pl*128 + row]     = m0;
      h2max[(size_t)(pl+2)*128 + row] = m1;
    }
  }
}

// ---------------- xe2 = lrelu(BN(h2max)) in-place ----------------
__global__ void k_xe2fin(float* __restrict__ xe2, const float* __restrict__ s2, const float* __restrict__ t2){
  int i = blockIdx.x*256 + threadIdx.x;   // < NP*128 = 1048576
  if(i >= NP*128) return;
  int o = i&127;
  xe2[i] = lrelu(fmaf(xe2[i], s2[o], t2[o]));
}

// ---------------- hcat = [xe2 (flat-reinterpret) ; kernels_r] ----------------
__global__ void k_hcat(const float* __restrict__ xe2, const float* __restrict__ kr, float* __restrict__ hcat){
  size_t i = (size_t)blockIdx.x*256 + threadIdx.x;   // < 2*256*4096
  int b = (int)(i>>20);
  int r = (int)(i & 1048575);
  int ch = r>>12;
  float v;
  if(ch < 128) v = xe2[(size_t)b*524288 + r];
  else         v = kr [(size_t)(b*128 + (ch-128))*4096 + (r&4095)];
  hcat[i] = v;
}

// ---------------- generic small transpose (O,C)->(C,O) ----------------
__global__ void k_transpose(const float* __restrict__ w, float* __restrict__ wT, int O, int C){
  int i = blockIdx.x*256 + threadIdx.x;
  if(i >= O*C) return;
  int o = i / C, c = i % C;
  wT[(size_t)c*O + o] = w[i];
}

// ---------------- weight fp32 [M][K] -> bf16 fragment-linear ----------------
// frag-linear: region(x>>7, k>>6); short idx = region*8192 + ((((k>>5)&1)*8 + ((x>>4)&7))*512) + (((k>>3)&3)*16 + (x&15))*8 + (k&7)
__global__ void k_wprep(const float* __restrict__ w, short* __restrict__ wb, int M, int K){
  int tid = blockIdx.x*256 + threadIdx.x;    // < M*K/8
  int m = tid % M, kb8 = tid / M;
  int k0 = kb8*8;
  float4 v0 = *(const float4*)&w[(size_t)m*K + k0];
  float4 v1 = *(const float4*)&w[(size_t)m*K + k0 + 4];
  s8v r;
  r[0]=f2bf(v0.x); r[1]=f2bf(v0.y); r[2]=f2bf(v0.z); r[3]=f2bf(v0.w);
  r[4]=f2bf(v1.x); r[5]=f2bf(v1.y); r[6]=f2bf(v1.z); r[7]=f2bf(v1.w);
  int region = (m>>7)*(K>>6) + (k0>>6);
  int chunk = ((kb8>>2)&1)*8 + ((m>>4)&7);
  int lane = (kb8&3)*16 + (m&15);
  *(s8v*)&wb[(size_t)region*8192 + chunk*512 + lane*8] = r;
}

// ---------------- activations fp32 [2][K][4096] (+BN/lrelu) -> bf16 fragment-linear ----------------
__global__ void k_bprep(const float* __restrict__ in, const float* __restrict__ sc, const float* __restrict__ sh,
                        short* __restrict__ ob, int K){
  int tid = blockIdx.x*256 + threadIdx.x;    // < 8192*K/8 ; tid = kb8*8192 + n
  int n = tid & 8191, kb8 = tid >> 13;
  int k0 = kb8*8;
  int b = n>>12, s = n&4095;
  const float* ib = in + ((size_t)b*K + k0)*4096 + s;
  float v[8];
  #pragma unroll
  for(int j=0;j<8;j++) v[j] = ib[(size_t)j*4096];
  if(sc){
    #pragma unroll
    for(int j=0;j<8;j++) v[j] = lrelu(fmaf(v[j], sc[k0+j], sh[k0+j]));
  }
  s8v r;
  #pragma unroll
  for(int j=0;j<8;j++) r[j] = f2bf(v[j]);
  int region = (n>>7)*(K>>6) + (k0>>6);
  int chunk = ((kb8>>2)&1)*8 + ((n>>4)&7);
  int lane = (kb8&3)*16 + (n&15);
  *(s8v*)&ob[(size_t)region*8192 + chunk*512 + lane*8] = r;
}

// ---------------- bf16 MFMA GEMM: out[b][m][s] = sum_k A[m][k] B[k][n] ----------------
// A, B in fragment-linear layout; 128x128 tile, 4 waves (2x2), KSTEP=64.
__global__ __launch_bounds__(256) void k_gmm(const short* __restrict__ A, const short* __restrict__ B,
                                             float* __restrict__ out, int M, int K){
  __shared__ short sA[8192], sB[8192];
  int t = threadIdx.x;
  int lane = t&63;
  int w = t>>6;
  int wm4 = (w>>1)*4, wn4 = (w&1)*4;
  int mb = blockIdx.y, nb = blockIdx.x;
  int ksteps = K>>6;
  const short* AG = A + (size_t)mb*ksteps*8192;
  const short* BG = B + (size_t)nb*ksteps*8192;
  f4v acc[4][4];
  #pragma unroll
  for(int i=0;i<4;i++){
    #pragma unroll
    for(int j=0;j<4;j++) acc[i][j] = (f4v)(0.f);
  }
  for(int st=0; st<ksteps; ++st){
    __syncthreads();
    #pragma unroll
    for(int i=0;i<4;i++){
      int slot = t + i*256;
      *(s8v*)&sA[slot*8] = *(const s8v*)&AG[(size_t)st*8192 + slot*8];
      *(s8v*)&sB[slot*8] = *(const s8v*)&BG[(size_t)st*8192 + slot*8];
    }
    __syncthreads();
    #pragma unroll
    for(int kh=0;kh<2;kh++){
      s8v av[4], bv[4];
      #pragma unroll
      for(int f=0;f<4;f++) av[f] = *(const s8v*)&sA[(kh*8 + wm4 + f)*512 + lane*8];
      #pragma unroll
      for(int f=0;f<4;f++) bv[f] = *(const s8v*)&sB[(kh*8 + wn4 + f)*512 + lane*8];
      #pragma unroll
      for(int fm=0;fm<4;fm++){
        #pragma unroll
        for(int fn=0;fn<4;fn++)
          acc[fm][fn] = __builtin_amdgcn_mfma_f32_16x16x32_bf16(av[fm], bv[fn], acc[fm][fn], 0, 0, 0);
      }
    }
  }
  int l15 = lane&15, l4 = (lane>>4)*4;
  #pragma unroll
  for(int fm=0;fm<4;fm++){
    int mrow = mb*128 + wm4*16 + fm*16 + l4;
    #pragma unroll
    for(int fn=0;fn<4;fn++){
      int n = nb*128 + wn4*16 + fn*16 + l15;
      int b = n>>12, s = n&4095;
      float* ob = out + ((size_t)b*M + mrow)*4096 + s;
      #pragma unroll
      for(int r=0;r<4;r++) ob[(size_t)r*4096] = acc[fm][fn][r];
    }
  }
}

// ---------------- per-channel stats over (b, s) for cbr layers ----------------
__global__ void k_cstats(const float* __restrict__ buf, int C, const float* __restrict__ g,
                         const float* __restrict__ be, float* __restrict__ sc, float* __restrict__ sh){
  int o = blockIdx.x, t = threadIdx.x;
  float s=0.f, q=0.f;
  for(int i=t;i<8192;i+=256){
    int b=i>>12, ss_=i&4095;
    float v = buf[(size_t)(b*C+o)*4096 + ss_];
    s+=v; q+=v*v;
  }
  __shared__ float ls[256], lq[256];
  ls[t]=s; lq[t]=q; __syncthreads();
  for(int st=128; st; st>>=1){ if(t<st){ ls[t]+=ls[t+st]; lq[t]+=lq[t+st]; } __syncthreads(); }
  if(t==0){
    float mu = ls[0]/8192.f;
    float var = lq[0]/8192.f - mu*mu; if(var<0.f) var=0.f;
    float s1 = g[o]*rsqrtf(var + EPSB);
    sc[o]=s1; sh[o]=be[o]-mu*s1;
  }
}

// ---------------- final layer: 9 outputs + partial spatial max ----------------
__global__ __launch_bounds__(256) void k_final4(const float* __restrict__ c3, const float* __restrict__ w4T,
                                                const float* __restrict__ sc, const float* __restrict__ sh,
                                                float* __restrict__ pmax){
  int b = blockIdx.y, st = blockIdx.x;
  int t = threadIdx.x; int s = st*256 + t;
  float acc[9];
  #pragma unroll
  for(int j=0;j<9;j++) acc[j]=0.f;
  const float* ib = c3 + (size_t)b*256*4096;
  for(int c=0;c<256;c++){
    float x = lrelu(fmaf(ib[(size_t)c*4096+s], sc[c], sh[c]));
    #pragma unroll
    for(int j=0;j<9;j++) acc[j]=fmaf(x, w4T[c*9+j], acc[j]);
  }
  __shared__ float red[256];
  for(int j=0;j<9;j++){
    red[t]=acc[j]; __syncthreads();
    for(int stp=128; stp; stp>>=1){ if(t<stp) red[t]=fmaxf(red[t],red[t+stp]); __syncthreads(); }
    if(t==0) pmax[(b*16+st)*9 + j]=red[0];
    __syncthreads();
  }
}

__global__ void k_out(const float* __restrict__ pmax, float* __restrict__ out){
  int i = threadIdx.x;
  if(i<18){
    int b=i/9, o=i%9;
    float m=-3.4e38f;
    for(int k=0;k<16;k++) m=fmaxf(m, pmax[(b*16+k)*9+o]);
    out[i] = m + ((o==0||o==4||o==8)?1.f:0.f);
  }
}

// ---------------- launch ----------------
extern "C" void kernel_launch(void* const* d_in, const int* in_sizes, int n_in,
                              void* d_out, int out_size, void* d_ws, size_t ws_size,
                              hipStream_t stream){
  const float* x    = (const float*)d_in[0];
  const float* kc   = (const float*)d_in[1];
  const float* e1w1 = (const float*)d_in[2];
  const float* e1g1 = (const float*)d_in[3];
  const float* e1b1 = (const float*)d_in[4];
  const float* e1w2 = (const float*)d_in[5];
  const float* e1g2 = (const float*)d_in[6];
  const float* e1b2 = (const float*)d_in[7];
  const float* e2w1 = (const float*)d_in[8];
  const float* e2g1 = (const float*)d_in[9];
  const float* e2b1 = (const float*)d_in[10];
  const float* e2w2 = (const float*)d_in[11];
  const float* e2g2 = (const float*)d_in[12];
  const float* e2b2 = (const float*)d_in[13];
  const float* w1   = (const float*)d_in[14];
  const float* g1   = (const float*)d_in[15];
  const float* b1   = (const float*)d_in[16];
  const float* w2   = (const float*)d_in[17];
  const float* g2   = (const float*)d_in[18];
  const float* b2   = (const float*)d_in[19];
  const float* w3   = (const float*)d_in[20];
  const float* g3   = (const float*)d_in[21];
  const float* b3   = (const float*)d_in[22];
  const float* w4   = (const float*)d_in[23];

  if(ws_size < 156061696ull) return;
  char* ws = (char*)d_ws;
  float* pts   = (float*)(ws + 0);
  float* xe0   = (float*)(ws + 98304);
  float* sqp   = (float*)(ws + 196608);
  float* sqe   = (float*)(ws + 229376);
  float* sqx1  = (float*)(ws + 262144);
  float* xe1   = (float*)(ws + 294912);
  float* xe1T  = (float*)(ws + 2392064);
  float* xe2   = (float*)(ws + 4489216);
  float* kr    = (float*)(ws + 8683520);
  int*   idxP  = (int*)  (ws + 12877824);
  int*   idx1  = (int*)  (ws + 13926400);
  int*   idx2  = (int*)  (ws + 14974976);
  float* psum  = (float*)(ws + 16023552);
  float* psq   = (float*)(ws + 17072128);
  float* par   = (float*)(ws + 18120704);
  float* pmax  = (float*)(ws + 18153472);
  float* wT4   = (float*)(ws + 21827584);
  float* hbuf  = (float*)(ws + 21843968);
  // e2 weight transposes reuse the pts/xe0 region (dead by then)
  float* ew1T  = (float*)(ws + 0);
  float* ew2T  = (float*)(ws + 65536);
  // bf16 buffers live in the tail of hbuf (free during cbr phase)
  short* actB  = (short*)(ws + 88952832);    // 16 MB
  short* wb1   = (short*)(ws + 105730048);   // 512 KB
  short* wb2   = (short*)(ws + 106254336);   // 1 MB
  short* wb3   = (short*)(ws + 107302912);   // 256 KB

  float* e1s1 = par+0;    float* e1t1 = par+64;
  float* e1s2 = par+128;  float* e1t2 = par+192;
  float* e2s1 = par+256;  float* e2t1 = par+384;
  float* e2s2 = par+512;  float* e2t2 = par+640;
  float* c1s  = par+768;  float* c1t  = par+1792;
  float* c2s  = par+2816; float* c2t  = par+3328;
  float* c3s  = par+3840; float* c3t  = par+4096;

  float* hcat  = hbuf;
  float* c1out = hbuf + 2097152;
  float* c2out = hbuf + 10485760;
  float* c3out = hbuf + 14680064;

  hipLaunchKernelGGL(k_prep, dim3(32), dim3(256), 0, stream, x, pts, xe0, sqp, sqe);
  hipLaunchKernelGGL(k_knn3, dim3(4096), dim3(128), 0, stream, pts, sqp, idxP);
  hipLaunchKernelGGL(k_knn3, dim3(4096), dim3(128), 0, stream, xe0, sqe, idx1);
  hipLaunchKernelGGL(k_gauss, dim3(8192), dim3(128), 0, stream, pts, sqp, idxP, kc, kr);

  // edge-conv 1
  hipLaunchKernelGGL(k_ec1_h1, dim3(256), dim3(256), 0, stream, xe0, idx1, e1w1, hbuf, psum, psq);
  hipLaunchKernelGGL(k_fin, dim3(64), dim3(256), 0, stream, psum, psq, 1024, 64, 262144.f, e1g1, e1b1, e1s1, e1t1);
  hipLaunchKernelGGL(k_ec1_h2, dim3(256), dim3(256), 0, stream, hbuf, e1w2, e1s1, e1t1, psum, psq);
  hipLaunchKernelGGL(k_fin, dim3(64), dim3(256), 0, stream, psum, psq, 1024, 64, 262144.f, e1g2, e1b2, e1s2, e1t2);
  hipLaunchKernelGGL(k_ec1_max, dim3(2048), dim3(256), 0, stream, hbuf, e1s2, e1t2, xe1, xe1T, sqx1);

  // knn on 64-d features
  hipLaunchKernelGGL(k_dgemm, dim3(32,32,2), dim3(256), 0, stream, xe1T, sqx1, hbuf);
  hipLaunchKernelGGL(k_knn_sel, dim3(4096), dim3(128), 0, stream, hbuf, idx2);

  // edge-conv 2 (fp32 GEMM formulation, fused stats+max)
  hipLaunchKernelGGL(k_transpose, dim3(64), dim3(256), 0, stream, e2w1, ew1T, 128, 128);
  hipLaunchKernelGGL(k_transpose, dim3(64), dim3(256), 0, stream, e2w2, ew2T, 128, 128);
  hipLaunchKernelGGL(k_ec2g1, dim3(2048), dim3(256), 0, stream, xe1, idx2, ew1T, hbuf, psum, psq);
  hipLaunchKernelGGL(k_fin, dim3(128), dim3(256), 0, stream, psum, psq, 2048, 128, 262144.f, e2g1, e2b1, e2s1, e2t1);
  hipLaunchKernelGGL(k_ec2g2, dim3(2048), dim3(256), 0, stream, hbuf, ew2T, e2s1, e2t1, xe2, psum, psq);
  hipLaunchKernelGGL(k_fin, dim3(128), dim3(256), 0, stream, psum, psq, 2048, 128, 262144.f, e2g2, e2b2, e2s2, e2t2);
  hipLaunchKernelGGL(k_xe2fin, dim3(4096), dim3(256), 0, stream, xe2, e2s2, e2t2);

  // concat + bf16 MFMA cbr chain
  hipLaunchKernelGGL(k_hcat, dim3(8192), dim3(256), 0, stream, xe2, kr, hcat);
  hipLaunchKernelGGL(k_wprep, dim3(128), dim3(256), 0, stream, w1, wb1, 1024, 256);
  hipLaunchKernelGGL(k_wprep, dim3(256), dim3(256), 0, stream, w2, wb2, 512, 1024);
  hipLaunchKernelGGL(k_wprep, dim3(64),  dim3(256), 0, stream, w3, wb3, 256, 512);
  hipLaunchKernelGGL(k_transpose, dim3((9*256+255)/256), dim3(256), 0, stream, w4, wT4, 9, 256);

  hipLaunchKernelGGL(k_bprep, dim3(1024), dim3(256), 0, stream, hcat, (const float*)nullptr, (const float*)nullptr, actB, 256);
  hipLaunchKernelGGL(k_gmm, dim3(64,8), dim3(256), 0, stream, wb1, actB, c1out, 1024, 256);
  hipLaunchKernelGGL(k_cstats, dim3(1024), dim3(256), 0, stream, c1out, 1024, g1, b1, c1s, c1t);

  hipLaunchKernelGGL(k_bprep, dim3(4096), dim3(256), 0, stream, c1out, c1s, c1t, actB, 1024);
  hipLaunchKernelGGL(k_gmm, dim3(64,4), dim3(256), 0, stream, wb2, actB, c2out, 512, 1024);
  hipLaunchKernelGGL(k_cstats, dim3(512), dim3(256), 0, stream, c2out, 512, g2, b2, c2s, c2t);

  hipLaunchKernelGGL(k_bprep, dim3(2048), dim3(256), 0, stream, c2out, c2s, c2t, actB, 512);
  hipLaunchKernelGGL(k_gmm, dim3(64,2), dim3(256), 0, stream, wb3, actB, c3out, 256, 512);
  hipLaunchKernelGGL(k_cstats, dim3(256), dim3(256), 0, stream, c3out, 256, g3, b3, c3s, c3t);

  hipLaunchKernelGGL(k_final4, dim3(16,2), dim3(256), 0, stream, c3out, wT4, c3s, c3t, pmax);
  hipLaunchKernelGGL(k_out, dim3(1), dim3(32), 0, stream, pmax, (float*)d_out);
}

// Round 6
// 1005.332 us; speedup vs baseline: 2.4691x; 1.2388x over previous
//
#include <hip/hip_runtime.h>
#include <math.h>

#define WN 4096
#define NP 8192
#define KK 32
#define EPSB 1e-5f

typedef __attribute__((ext_vector_type(8))) short s8v;
typedef __attribute__((ext_vector_type(4))) float f4v;

__device__ __forceinline__ float lrelu(float x){ return fmaxf(x, 0.01f*x); }
__device__ __forceinline__ float rlane(float v, int c){
  return __int_as_float(__builtin_amdgcn_readlane(__float_as_int(v), c));
}
__device__ __forceinline__ short f2bf(float f){
  unsigned u = __float_as_uint(f);
  u = (u + 0x7fffu + ((u>>16)&1u)) >> 16;
  return (short)u;
}

// ---------------- prep: build pts (b,p,3), xe0 (b,p,3) and squared norms ----------------
__global__ void k_prep(const float* __restrict__ x, float* __restrict__ pts, float* __restrict__ xe0,
                       float* __restrict__ sqp, float* __restrict__ sqe){
  int i = blockIdx.x*256 + threadIdx.x;
  if(i >= NP) return;
  int b = i>>12, p = i&4095;
  const float* xb = x + b*12288;
  float a0 = xb[p], a1 = xb[4096+p], a2 = xb[8192+p];
  pts[i*3+0]=a0; pts[i*3+1]=a1; pts[i*3+2]=a2;
  sqp[i] = (a0*a0 + a1*a1) + a2*a2;
  float e0 = xb[p*3+0], e1 = xb[p*3+1], e2 = xb[p*3+2];
  xe0[i*3+0]=e0; xe0[i*3+1]=e1; xe0[i*3+2]=e2;
  sqe[i] = (e0*e0 + e1*e1) + e2*e2;
}

// ---------------- streaming wave top-32: sorted (d,idx) list in lanes 0..31, no LDS ----------------
// Insert the wave's 64 candidates (d, m) into the ascending list (lv,li).
__device__ __forceinline__ void topk_stream(float d, int m, int l, float& lv, int& li){
  float thr = rlane(lv, 31);
  int ti = __builtin_amdgcn_readlane(li, 31);
  unsigned long long mask = __ballot(d < thr || (d == thr && m < ti));
  while(mask){
    int s = __ffsll((unsigned long long)mask) - 1;
    float cd = __shfl(d, s);
    int cm = __shfl(m, s);
    unsigned long long less = __ballot(lv < cd || (lv == cd && li < cm));
    int pos = __popcll(less & 0xffffffffULL);
    float uv = __shfl_up(lv, 1);
    int ui = __shfl_up(li, 1);
    if(l < 32){
      if(l == pos){ lv = cd; li = cm; }
      else if(l > pos){ lv = uv; li = ui; }
    }
    mask &= mask - 1;
    if(mask){
      thr = rlane(lv, 31);
      ti = __builtin_amdgcn_readlane(li, 31);
      mask &= __ballot(d < thr || (d == thr && m < ti));
    }
  }
}

// ---------------- KNN for 3-channel points (fused distance + streaming select) ----------------
__global__ __launch_bounds__(256) void k_knn3(const float* __restrict__ pnt, const float* __restrict__ sq,
                                              int* __restrict__ idx){
  int l = threadIdx.x&63;
  int q = blockIdx.x*4 + (threadIdx.x>>6);
  int b = q>>12, qr = q&4095;
  const float* pb = pnt + (size_t)b*WN*3;
  const float* sb = sq + b*WN;
  float q0=pb[qr*3], q1=pb[qr*3+1], q2=pb[qr*3+2];
  float sqq = sb[qr];
  float lv = 3.4e38f; int li = 0x7fffffff;
  #pragma unroll 4
  for(int j=0;j<64;j++){
    int m = l + (j<<6);
    float d0=pb[m*3], d1=pb[m*3+1], d2=pb[m*3+2];
    float dot = q0*d0 + q1*d1 + q2*d2;
    float d = (sqq - 2.0f*dot) + sb[m];
    topk_stream(d, m, l, lv, li);
  }
  if(l < 32) idx[(size_t)q*KK + l] = li;
}

// ---------------- KNN selection from precomputed D (streaming select) ----------------
__global__ __launch_bounds__(256) void k_knn_sel(const float* __restrict__ D, int* __restrict__ idx){
  int l = threadIdx.x&63;
  int q = blockIdx.x*4 + (threadIdx.x>>6);
  int b = q>>12, qr = q&4095;
  const float* row = D + ((size_t)b<<24) + ((size_t)qr<<12);
  float lv = 3.4e38f; int li = 0x7fffffff;
  #pragma unroll 4
  for(int j=0;j<64;j++){
    int m = l + (j<<6);
    float d = row[m];
    topk_stream(d, m, l, lv, li);
  }
  if(l < 32) idx[(size_t)q*KK + l] = li;
}

// ---------------- gaussian kernel conv: block per point, thread per center ----------------
__global__ __launch_bounds__(128) void k_gauss(const float* __restrict__ pts, const float* __restrict__ sqp,
                                               const int* __restrict__ idxP, const float* __restrict__ cen,
                                               float* __restrict__ kout){
  __shared__ float nbx[KK], nby[KK], nbz[KK], nsq[KK];
  int p = blockIdx.x; int b = p>>12; int t = threadIdx.x;
  if(t < KK){
    int id = idxP[(size_t)p*KK + t] + (b<<12);
    nbx[t]=pts[id*3]; nby[t]=pts[id*3+1]; nbz[t]=pts[id*3+2];
    nsq[t]=sqp[id];
  }
  __syncthreads();
  float c0=cen[t*3], c1=cen[t*3+1], c2=cen[t*3+2];
  float sqc=(c0*c0+c1*c1)+c2*c2;
  float acc=0.f;
  #pragma unroll
  for(int k=0;k<KK;k++){
    float dot = nbx[k]*c0 + nby[k]*c1 + nbz[k]*c2;
    float d = (nsq[k] - 2.0f*dot) + sqc;
    acc += expf(-0.5f*d);
  }
  kout[(size_t)((b<<7)+t)*4096 + (p&4095)] = acc;
}

// ---------------- finalize BN stats from per-wave partials ----------------
__global__ void k_fin(const float* __restrict__ psum, const float* __restrict__ psq, int NW, int C, float Nn,
                      const float* __restrict__ g, const float* __restrict__ be,
                      float* __restrict__ sc, float* __restrict__ sh){
  int o = blockIdx.x, t = threadIdx.x;
  float s=0.f, q=0.f;
  for(int w=t; w<NW; w+=256){ s += psum[(size_t)w*C+o]; q += psq[(size_t)w*C+o]; }
  __shared__ float ls[256], lq[256];
  ls[t]=s; lq[t]=q; __syncthreads();
  for(int st=128; st; st>>=1){ if(t<st){ ls[t]+=ls[t+st]; lq[t]+=lq[t+st]; } __syncthreads(); }
  if(t==0){
    float mu = ls[0]/Nn;
    float var = lq[0]/Nn - mu*mu; if(var<0.f) var=0.f;
    float s1 = g[o]*rsqrtf(var + EPSB);
    sc[o]=s1; sh[o]=be[o]-mu*s1;
  }
}

// ---------------- edge-conv 1 (Cin=3 -> 64) ----------------
__global__ __launch_bounds__(256) void k_ec1_h1(const float* __restrict__ xe0, const int* __restrict__ idx1,
                                                const float* __restrict__ w1, float* __restrict__ hbuf,
                                                float* __restrict__ psum, float* __restrict__ psq){
  int wid = (blockIdx.x*256 + threadIdx.x)>>6;   // < 1024
  int l = threadIdx.x&63;
  float wr[6];
  #pragma unroll
  for(int c=0;c<6;c++) wr[c] = w1[l*6+c];
  float s=0.f, ss=0.f;
  for(int p=wid; p<NP; p+=1024){
    int bb = (p>>12)<<12;
    float x0=xe0[p*3], x1=xe0[p*3+1], x2=xe0[p*3+2];
    const int* ip = idx1 + (size_t)p*KK;
    for(int k=0;k<KK;k++){
      int id = ip[k];
      const float* nb = xe0 + (size_t)(bb+id)*3;
      float h = wr[0]*(nb[0]-x0) + wr[1]*(nb[1]-x1) + wr[2]*(nb[2]-x2)
              + wr[3]*x0 + wr[4]*x1 + wr[5]*x2;
      hbuf[(size_t)(p*KK+k)*64 + l] = h;
      s += h; ss += h*h;
    }
  }
  psum[(size_t)wid*64+l]=s; psq[(size_t)wid*64+l]=ss;
}

__global__ __launch_bounds__(256) void k_ec1_h2(float* __restrict__ hbuf, const float* __restrict__ w2,
                                                const float* __restrict__ sc, const float* __restrict__ sh,
                                                float* __restrict__ psum, float* __restrict__ psq){
  int wid = (blockIdx.x*256 + threadIdx.x)>>6;   // < 1024
  int l = threadIdx.x&63;
  float wr[64];
  #pragma unroll
  for(int c=0;c<64;c+=4){ float4 v = *(const float4*)&w2[l*64+c]; wr[c]=v.x; wr[c+1]=v.y; wr[c+2]=v.z; wr[c+3]=v.w; }
  float s1=sc[l], t1=sh[l];
  float s=0.f, ss=0.f;
  for(int smp=wid; smp<NP*KK; smp+=1024){
    float y = lrelu(fmaf(hbuf[(size_t)smp*64+l], s1, t1));
    float a0=0.f, a1=0.f;
    #pragma unroll
    for(int c=0;c<64;c+=2){
      a0 = fmaf(rlane(y,c),   wr[c],   a0);
      a1 = fmaf(rlane(y,c+1), wr[c+1], a1);
    }
    float h2 = a0+a1;
    hbuf[(size_t)smp*64+l] = h2;
    s+=h2; ss+=h2*h2;
  }
  psum[(size_t)wid*64+l]=s; psq[(size_t)wid*64+l]=ss;
}

__global__ __launch_bounds__(256) void k_ec1_max(const float* __restrict__ hbuf, const float* __restrict__ sc,
                                                 const float* __restrict__ sh, float* __restrict__ xe1,
                                                 float* __restrict__ xe1T, float* __restrict__ sqx){
  int p = (blockIdx.x*256 + threadIdx.x)>>6;     // < 8192
  int l = threadIdx.x&63;
  float s1=sc[l], t1=sh[l];
  float mx = -3.4e38f;
  for(int k=0;k<KK;k++){
    float h = hbuf[(size_t)(p*KK+k)*64 + l];
    mx = fmaxf(mx, lrelu(fmaf(h,s1,t1)));
  }
  xe1[(size_t)p*64+l]=mx;
  int b=p>>12, pr=p&4095;
  xe1T[(size_t)(b*64+l)*4096 + pr]=mx;
  float sq = mx*mx;
  #pragma unroll
  for(int off=32; off; off>>=1) sq += __shfl_xor(sq, off);
  if(l==0) sqx[p]=sq;
}

// ---------------- D = sq_n - 2 X X^T + sq_m  (per batch, 128x128 tiles, 8x8/thread) ----------------
__global__ __launch_bounds__(256) void k_dgemm(const float* __restrict__ xT, const float* __restrict__ sqx,
                                               float* __restrict__ D){
  __shared__ float As[32*128], Bs2[32*128];
  int b = blockIdx.z;
  int m0 = blockIdx.y*128, n0 = blockIdx.x*128;
  int t = threadIdx.x;
  int tx = t&15, ty = t>>4;
  const float* xb = xT + (size_t)b*64*4096;
  float acc[8][8];
  #pragma unroll
  for(int i=0;i<8;i++){
    #pragma unroll
    for(int j=0;j<8;j++) acc[i][j]=0.f;
  }
  for(int kc=0;kc<2;kc++){
    __syncthreads();
    #pragma unroll
    for(int i=0;i<16;i++){
      int e = t + (i<<8);
      int k = e>>7, mm = e&127;
      As[k*128+mm]  = xb[(size_t)(kc*32+k)*4096 + m0+mm];
      Bs2[k*128+mm] = xb[(size_t)(kc*32+k)*4096 + n0+mm];
    }
    __syncthreads();
    #pragma unroll 4
    for(int k=0;k<32;k++){
      float av[8], bv[8];
      float4 A0 = *(float4*)&As[k*128 + ty*8];
      float4 A1 = *(float4*)&As[k*128 + ty*8+4];
      float4 B0 = *(float4*)&Bs2[k*128 + tx*8];
      float4 B1 = *(float4*)&Bs2[k*128 + tx*8+4];
      av[0]=A0.x; av[1]=A0.y; av[2]=A0.z; av[3]=A0.w; av[4]=A1.x; av[5]=A1.y; av[6]=A1.z; av[7]=A1.w;
      bv[0]=B0.x; bv[1]=B0.y; bv[2]=B0.z; bv[3]=B0.w; bv[4]=B1.x; bv[5]=B1.y; bv[6]=B1.z; bv[7]=B1.w;
      #pragma unroll
      for(int i=0;i<8;i++){
        #pragma unroll
        for(int j=0;j<8;j++) acc[i][j] = fmaf(av[i], bv[j], acc[i][j]);
      }
    }
  }
  const float* sb = sqx + (b<<12);
  float* Db = D + ((size_t)b<<24);
  #pragma unroll
  for(int i=0;i<8;i++){
    int r = m0 + ty*8 + i;
    float sqa = sb[r];
    float o[8];
    #pragma unroll
    for(int j=0;j<8;j++) o[j] = (sqa - 2.0f*acc[i][j]) + sb[n0+tx*8+j];
    *(float4*)&Db[(size_t)r*4096 + n0+tx*8]   = make_float4(o[0],o[1],o[2],o[3]);
    *(float4*)&Db[(size_t)r*4096 + n0+tx*8+4] = make_float4(o[4],o[5],o[6],o[7]);
  }
}

// ---------------- edge-conv 2 pass 1: gather-GEMM h1 = W1*[nbr-x ; x], write h1T[c][s], stats ----------------
__global__ __launch_bounds__(256) void k_ec2g1(const float* __restrict__ xe1, const int* __restrict__ idx2,
                                               const float* __restrict__ w1T, float* __restrict__ h1T,
                                               float* __restrict__ psum, float* __restrict__ psq){
  __shared__ float As[32*128];
  __shared__ float Bs[32*132];
  __shared__ float cts[256];
  __shared__ int nid[128];
  int t = threadIdx.x;
  int blk = blockIdx.x;
  int s0 = blk*128;
  int pbase = s0>>5;
  int bb = (s0>>17)<<12;
  if(t<128) nid[t] = (idx2[s0 + t] + bb)<<6;      // pre-scaled float row offset
  cts[t] = xe1[(size_t)(pbase + (t>>6))*64 + (t&63)];
  int tx = t&15, ty = t>>4;
  float acc[8][8];
  #pragma unroll
  for(int i=0;i<8;i++){
    #pragma unroll
    for(int j=0;j<8;j++) acc[i][j]=0.f;
  }
  for(int kc=0;kc<128;kc+=32){
    __syncthreads();
    #pragma unroll
    for(int i=0;i<16;i++){
      int e = t + (i<<8);
      int k = e>>7, m = e&127;
      As[e] = w1T[(kc+k)*128 + m];
    }
    #pragma unroll
    for(int i=0;i<4;i++){
      int e = t + (i<<8);
      int kg = e&7, n = e>>3;
      int c0 = (kc&63) + (kg<<2);
      float4 v;
      if(kc < 64){
        float4 a = *(const float4*)&xe1[nid[n] + c0];
        float4 c = *(const float4*)&cts[((n>>5)<<6) + c0];
        v = make_float4(a.x-c.x, a.y-c.y, a.z-c.z, a.w-c.w);
      } else {
        v = *(const float4*)&cts[((n>>5)<<6) + c0];
      }
      int base = (kg<<2)*132 + n;
      Bs[base]=v.x; Bs[base+132]=v.y; Bs[base+264]=v.z; Bs[base+396]=v.w;
    }
    __syncthreads();
    #pragma unroll 4
    for(int k=0;k<32;k++){
      float av[8], bv[8];
      float4 A0 = *(const float4*)&As[k*128 + ty*4];
      float4 A1 = *(const float4*)&As[k*128 + 64 + ty*4];
      float4 B0 = *(const float4*)&Bs[k*132 + tx*4];
      float4 B1 = *(const float4*)&Bs[k*132 + 64 + tx*4];
      av[0]=A0.x; av[1]=A0.y; av[2]=A0.z; av[3]=A0.w; av[4]=A1.x; av[5]=A1.y; av[6]=A1.z; av[7]=A1.w;
      bv[0]=B0.x; bv[1]=B0.y; bv[2]=B0.z; bv[3]=B0.w; bv[4]=B1.x; bv[5]=B1.y; bv[6]=B1.z; bv[7]=B1.w;
      #pragma unroll
      for(int i=0;i<8;i++){
        #pragma unroll
        for(int j=0;j<8;j++) acc[i][j] = fmaf(av[i], bv[j], acc[i][j]);
      }
    }
  }
  float* ob = h1T + s0;
  #pragma unroll
  for(int i=0;i<8;i++){
    int row = ((i>>2)<<6) + ty*4 + (i&3);
    *(float4*)&ob[(size_t)row*262144 + tx*4]      = make_float4(acc[i][0],acc[i][1],acc[i][2],acc[i][3]);
    *(float4*)&ob[(size_t)row*262144 + 64 + tx*4] = make_float4(acc[i][4],acc[i][5],acc[i][6],acc[i][7]);
    float sr = ((acc[i][0]+acc[i][1])+(acc[i][2]+acc[i][3])) + ((acc[i][4]+acc[i][5])+(acc[i][6]+acc[i][7]));
    float sq = ((acc[i][0]*acc[i][0]+acc[i][1]*acc[i][1])+(acc[i][2]*acc[i][2]+acc[i][3]*acc[i][3]))
             + ((acc[i][4]*acc[i][4]+acc[i][5]*acc[i][5])+(acc[i][6]*acc[i][6]+acc[i][7]*acc[i][7]));
    #pragma unroll
    for(int off=1; off<16; off<<=1){ sr += __shfl_xor(sr, off); sq += __shfl_xor(sq, off); }
    if(tx==0){ psum[(size_t)blk*128+row]=sr; psq[(size_t)blk*128+row]=sq; }
  }
}

// ---------------- edge-conv 2 pass 2: h2 = W2*lrelu(BN(h1)), stats + per-point max ----------------
__global__ __launch_bounds__(256) void k_ec2g2(const float* __restrict__ h1T, const float* __restrict__ w2T,
                                               const float* __restrict__ s1, const float* __restrict__ t1,
                                               float* __restrict__ h2max, float* __restrict__ psum,
                                               float* __restrict__ psq){
  __shared__ float As[32*128];
  __shared__ float Bs[32*132];
  int t = threadIdx.x;
  int blk = blockIdx.x;
  int s0 = blk*128;
  int pbase = s0>>5;
  int tx = t&15, ty = t>>4;
  float acc[8][8];
  #pragma unroll
  for(int i=0;i<8;i++){
    #pragma unroll
    for(int j=0;j<8;j++) acc[i][j]=0.f;
  }
  for(int kc=0;kc<128;kc+=32){
    __syncthreads();
    #pragma unroll
    for(int i=0;i<16;i++){
      int e = t + (i<<8);
      int k = e>>7, m = e&127;
      As[e] = w2T[(kc+k)*128 + m];
    }
    #pragma unroll
    for(int i=0;i<4;i++){
      int e = t + (i<<8);
      int k = e>>5, n4 = (e&31)<<2;
      float4 v = *(const float4*)&h1T[(size_t)(kc+k)*262144 + s0 + n4];
      float a = s1[kc+k], h = t1[kc+k];
      v.x = lrelu(fmaf(v.x,a,h)); v.y = lrelu(fmaf(v.y,a,h));
      v.z = lrelu(fmaf(v.z,a,h)); v.w = lrelu(fmaf(v.w,a,h));
      *(float4*)&Bs[k*132 + n4] = v;
    }
    __syncthreads();
    #pragma unroll 4
    for(int k=0;k<32;k++){
      float av[8], bv[8];
      float4 A0 = *(const float4*)&As[k*128 + ty*4];
      float4 A1 = *(const float4*)&As[k*128 + 64 + ty*4];
      float4 B0 = *(const float4*)&Bs[k*132 + tx*4];
      float4 B1 = *(const float4*)&Bs[k*132 + 64 + tx*4];
      av[0]=A0.x; av[1]=A0.y; av[2]=A0.z; av[3]=A0.w; av[4]=A1.x; av[5]=A1.y; av[6]=A1.z; av[7]=A1.w;
      bv[0]=B0.x; bv[1]=B0.y; bv[2]=B0.z; bv[3]=B0.w; bv[4]=B1.x; bv[5]=B1.y; bv[6]=B1.z; bv[7]=B1.w;
      #pragma unroll
      for(int i=0;i<8;i++){
        #pragma unroll
        for(int j=0;j<8;j++) acc[i][j] = fmaf(av[i], bv[j], acc[i][j]);
      }
    }
  }
  #pragma unroll
  for(int i=0;i<8;i++){
    int row = ((i>>2)<<6) + ty*4 + (i&3);
    float sr = ((acc[i][0]+acc[i][1])+(acc[i][2]+acc[i][3])) + ((acc[i][4]+acc[i][5])+(acc[i][6]+acc[i][7]));
    float sq = ((acc[i][0]*acc[i][0]+acc[i][1]*acc[i][1])+(acc[i][2]*acc[i][2]+acc[i][3]*acc[i][3]))
             + ((acc[i][4]*acc[i][4]+acc[i][5]*acc[i][5])+(acc[i][6]*acc[i][6]+acc[i][7]*acc[i][7]));
    #pragma unroll
    for(int off=1; off<16; off<<=1){ sr += __shfl_xor(sr, off); sq += __shfl_xor(sq, off); }
    if(tx==0){ psum[(size_t)blk*128+row]=sr; psq[(size_t)blk*128+row]=sq; }
    float m0 = fmaxf(fmaxf(acc[i][0],acc[i][1]), fmaxf(acc[i][2],acc[i][3]));
    float m1 = fmaxf(fmaxf(acc[i][4],acc[i][5]), fmaxf(acc[i][6],acc[i][7]));
    #pragma unroll
    for(int off=1; off<8; off<<=1){ m0 = fmaxf(m0, __shfl_xor(m0, off)); m1 = fmaxf(m1, __shfl_xor(m1, off)); }
    if((tx&7)==0){
      int pl = pbase + (tx>>3);
      h2max[(size_t)pl*128 + row]     = m0;
      h2max[(size_t)(pl+2)*128 + row] = m1;
    }
  }
}

// ---------------- xe2 = lrelu(BN(h2max)) in-place ----------------
__global__ void k_xe2fin(float* __restrict__ xe2, const float* __restrict__ s2, const float* __restrict__ t2){
  int i = blockIdx.x*256 + threadIdx.x;   // < NP*128 = 1048576
  if(i >= NP*128) return;
  int o = i&127;
  xe2[i] = lrelu(fmaf(xe2[i], s2[o], t2[o]));
}

// ---------------- hcat = [xe2 (flat-reinterpret) ; kernels_r] ----------------
__global__ void k_hcat(const float* __restrict__ xe2, const float* __restrict__ kr, float* __restrict__ hcat){
  size_t i = (size_t)blockIdx.x*256 + threadIdx.x;   // < 2*256*4096
  int b = (int)(i>>20);
  int r = (int)(i & 1048575);
  int ch = r>>12;
  float v;
  if(ch < 128) v = xe2[(size_t)b*524288 + r];
  else         v = kr [(size_t)(b*128 + (ch-128))*4096 + (r&4095)];
  hcat[i] = v;
}

// ---------------- generic small transpose (O,C)->(C,O) ----------------
__global__ void k_transpose(const float* __restrict__ w, float* __restrict__ wT, int O, int C){
  int i = blockIdx.x*256 + threadIdx.x;
  if(i >= O*C) return;
  int o = i / C, c = i % C;
  wT[(size_t)c*O + o] = w[i];
}

// ---------------- weight fp32 [M][K] -> bf16 fragment-linear ----------------
__global__ void k_wprep(const float* __restrict__ w, short* __restrict__ wb, int M, int K){
  int tid = blockIdx.x*256 + threadIdx.x;    // < M*K/8
  int m = tid % M, kb8 = tid / M;
  int k0 = kb8*8;
  float4 v0 = *(const float4*)&w[(size_t)m*K + k0];
  float4 v1 = *(const float4*)&w[(size_t)m*K + k0 + 4];
  s8v r;
  r[0]=f2bf(v0.x); r[1]=f2bf(v0.y); r[2]=f2bf(v0.z); r[3]=f2bf(v0.w);
  r[4]=f2bf(v1.x); r[5]=f2bf(v1.y); r[6]=f2bf(v1.z); r[7]=f2bf(v1.w);
  int region = (m>>7)*(K>>6) + (k0>>6);
  int chunk = ((kb8>>2)&1)*8 + ((m>>4)&7);
  int lane = (kb8&3)*16 + (m&15);
  *(s8v*)&wb[(size_t)region*8192 + chunk*512 + lane*8] = r;
}

// ---------------- activations fp32 [2][K][4096] (+BN/lrelu) -> bf16 fragment-linear ----------------
__global__ void k_bprep(const float* __restrict__ in, const float* __restrict__ sc, const float* __restrict__ sh,
                        short* __restrict__ ob, int K){
  int tid = blockIdx.x*256 + threadIdx.x;    // < 8192*K/8 ; tid = kb8*8192 + n
  int n = tid & 8191, kb8 = tid >> 13;
  int k0 = kb8*8;
  int b = n>>12, s = n&4095;
  const float* ib = in + ((size_t)b*K + k0)*4096 + s;
  float v[8];
  #pragma unroll
  for(int j=0;j<8;j++) v[j] = ib[(size_t)j*4096];
  if(sc){
    #pragma unroll
    for(int j=0;j<8;j++) v[j] = lrelu(fmaf(v[j], sc[k0+j], sh[k0+j]));
  }
  s8v r;
  #pragma unroll
  for(int j=0;j<8;j++) r[j] = f2bf(v[j]);
  int region = (n>>7)*(K>>6) + (k0>>6);
  int chunk = ((kb8>>2)&1)*8 + ((n>>4)&7);
  int lane = (kb8&3)*16 + (n&15);
  *(s8v*)&ob[(size_t)region*8192 + chunk*512 + lane*8] = r;
}

// ---------------- bf16 MFMA GEMM: out[b][m][s] = sum_k A[m][k] B[k][n] ----------------
__global__ __launch_bounds__(256) void k_gmm(const short* __restrict__ A, const short* __restrict__ B,
                                             float* __restrict__ out, int M, int K){
  __shared__ short sA[8192], sB[8192];
  int t = threadIdx.x;
  int lane = t&63;
  int w = t>>6;
  int wm4 = (w>>1)*4, wn4 = (w&1)*4;
  int mb = blockIdx.y, nb = blockIdx.x;
  int ksteps = K>>6;
  const short* AG = A + (size_t)mb*ksteps*8192;
  const short* BG = B + (size_t)nb*ksteps*8192;
  f4v acc[4][4];
  #pragma unroll
  for(int i=0;i<4;i++){
    #pragma unroll
    for(int j=0;j<4;j++) acc[i][j] = (f4v)(0.f);
  }
  for(int st=0; st<ksteps; ++st){
    __syncthreads();
    #pragma unroll
    for(int i=0;i<4;i++){
      int slot = t + i*256;
      *(s8v*)&sA[slot*8] = *(const s8v*)&AG[(size_t)st*8192 + slot*8];
      *(s8v*)&sB[slot*8] = *(const s8v*)&BG[(size_t)st*8192 + slot*8];
    }
    __syncthreads();
    #pragma unroll
    for(int kh=0;kh<2;kh++){
      s8v av[4], bv[4];
      #pragma unroll
      for(int f=0;f<4;f++) av[f] = *(const s8v*)&sA[(kh*8 + wm4 + f)*512 + lane*8];
      #pragma unroll
      for(int f=0;f<4;f++) bv[f] = *(const s8v*)&sB[(kh*8 + wn4 + f)*512 + lane*8];
      #pragma unroll
      for(int fm=0;fm<4;fm++){
        #pragma unroll
        for(int fn=0;fn<4;fn++)
          acc[fm][fn] = __builtin_amdgcn_mfma_f32_16x16x32_bf16(av[fm], bv[fn], acc[fm][fn], 0, 0, 0);
      }
    }
  }
  int l15 = lane&15, l4 = (lane>>4)*4;
  #pragma unroll
  for(int fm=0;fm<4;fm++){
    int mrow = mb*128 + wm4*16 + fm*16 + l4;
    #pragma unroll
    for(int fn=0;fn<4;fn++){
      int n = nb*128 + wn4*16 + fn*16 + l15;
      int b = n>>12, s = n&4095;
      float* ob = out + ((size_t)b*M + mrow)*4096 + s;
      #pragma unroll
      for(int r=0;r<4;r++) ob[(size_t)r*4096] = acc[fm][fn][r];
    }
  }
}

// ---------------- per-channel stats over (b, s) for cbr layers ----------------
__global__ void k_cstats(const float* __restrict__ buf, int C, const float* __restrict__ g,
                         const float* __restrict__ be, float* __restrict__ sc, float* __restrict__ sh){
  int o = blockIdx.x, t = threadIdx.x;
  float s=0.f, q=0.f;
  for(int i=t;i<8192;i+=256){
    int b=i>>12, ss_=i&4095;
    float v = buf[(size_t)(b*C+o)*4096 + ss_];
    s+=v; q+=v*v;
  }
  __shared__ float ls[256], lq[256];
  ls[t]=s; lq[t]=q; __syncthreads();
  for(int st=128; st; st>>=1){ if(t<st){ ls[t]+=ls[t+st]; lq[t]+=lq[t+st]; } __syncthreads(); }
  if(t==0){
    float mu = ls[0]/8192.f;
    float var = lq[0]/8192.f - mu*mu; if(var<0.f) var=0.f;
    float s1 = g[o]*rsqrtf(var + EPSB);
    sc[o]=s1; sh[o]=be[o]-mu*s1;
  }
}

// ---------------- final layer: 9 outputs + partial spatial max ----------------
__global__ __launch_bounds__(256) void k_final4(const float* __restrict__ c3, const float* __restrict__ w4T,
                                                const float* __restrict__ sc, const float* __restrict__ sh,
                                                float* __restrict__ pmax){
  int b = blockIdx.y, st = blockIdx.x;
  int t = threadIdx.x; int s = st*256 + t;
  float acc[9];
  #pragma unroll
  for(int j=0;j<9;j++) acc[j]=0.f;
  const float* ib = c3 + (size_t)b*256*4096;
  for(int c=0;c<256;c++){
    float x = lrelu(fmaf(ib[(size_t)c*4096+s], sc[c], sh[c]));
    #pragma unroll
    for(int j=0;j<9;j++) acc[j]=fmaf(x, w4T[c*9+j], acc[j]);
  }
  __shared__ float red[256];
  for(int j=0;j<9;j++){
    red[t]=acc[j]; __syncthreads();
    for(int stp=128; stp; stp>>=1){ if(t<stp) red[t]=fmaxf(red[t],red[t+stp]); __syncthreads(); }
    if(t==0) pmax[(b*16+st)*9 + j]=red[0];
    __syncthreads();
  }
}

__global__ void k_out(const float* __restrict__ pmax, float* __restrict__ out){
  int i = threadIdx.x;
  if(i<18){
    int b=i/9, o=i%9;
    float m=-3.4e38f;
    for(int k=0;k<16;k++) m=fmaxf(m, pmax[(b*16+k)*9+o]);
    out[i] = m + ((o==0||o==4||o==8)?1.f:0.f);
  }
}

// ---------------- launch ----------------
extern "C" void kernel_launch(void* const* d_in, const int* in_sizes, int n_in,
                              void* d_out, int out_size, void* d_ws, size_t ws_size,
                              hipStream_t stream){
  const float* x    = (const float*)d_in[0];
  const float* kc   = (const float*)d_in[1];
  const float* e1w1 = (const float*)d_in[2];
  const float* e1g1 = (const float*)d_in[3];
  const float* e1b1 = (const float*)d_in[4];
  const float* e1w2 = (const float*)d_in[5];
  const float* e1g2 = (const float*)d_in[6];
  const float* e1b2 = (const float*)d_in[7];
  const float* e2w1 = (const float*)d_in[8];
  const float* e2g1 = (const float*)d_in[9];
  const float* e2b1 = (const float*)d_in[10];
  const float* e2w2 = (const float*)d_in[11];
  const float* e2g2 = (const float*)d_in[12];
  const float* e2b2 = (const float*)d_in[13];
  const float* w1   = (const float*)d_in[14];
  const float* g1   = (const float*)d_in[15];
  const float* b1   = (const float*)d_in[16];
  const float* w2   = (const float*)d_in[17];
  const float* g2   = (const float*)d_in[18];
  const float* b2   = (const float*)d_in[19];
  const float* w3   = (const float*)d_in[20];
  const float* g3   = (const float*)d_in[21];
  const float* b3   = (const float*)d_in[22];
  const float* w4   = (const float*)d_in[23];

  if(ws_size < 156061696ull) return;
  char* ws = (char*)d_ws;
  float* pts   = (float*)(ws + 0);
  float* xe0   = (float*)(ws + 98304);
  float* sqp   = (float*)(ws + 196608);
  float* sqe   = (float*)(ws + 229376);
  float* sqx1  = (float*)(ws + 262144);
  float* xe1   = (float*)(ws + 294912);
  float* xe1T  = (float*)(ws + 2392064);
  float* xe2   = (float*)(ws + 4489216);
  float* kr    = (float*)(ws + 8683520);
  int*   idxP  = (int*)  (ws + 12877824);
  int*   idx1  = (int*)  (ws + 13926400);
  int*   idx2  = (int*)  (ws + 14974976);
  float* psum  = (float*)(ws + 16023552);
  float* psq   = (float*)(ws + 17072128);
  float* par   = (float*)(ws + 18120704);
  float* pmax  = (float*)(ws + 18153472);
  float* wT4   = (float*)(ws + 21827584);
  float* hbuf  = (float*)(ws + 21843968);
  float* ew1T  = (float*)(ws + 0);
  float* ew2T  = (float*)(ws + 65536);
  short* actB  = (short*)(ws + 88952832);    // 16 MB
  short* wb1   = (short*)(ws + 105730048);   // 512 KB
  short* wb2   = (short*)(ws + 106254336);   // 1 MB
  short* wb3   = (short*)(ws + 107302912);   // 256 KB

  float* e1s1 = par+0;    float* e1t1 = par+64;
  float* e1s2 = par+128;  float* e1t2 = par+192;
  float* e2s1 = par+256;  float* e2t1 = par+384;
  float* e2s2 = par+512;  float* e2t2 = par+640;
  float* c1s  = par+768;  float* c1t  = par+1792;
  float* c2s  = par+2816; float* c2t  = par+3328;
  float* c3s  = par+3840; float* c3t  = par+4096;

  float* hcat  = hbuf;
  float* c1out = hbuf + 2097152;
  float* c2out = hbuf + 10485760;
  float* c3out = hbuf + 14680064;

  hipLaunchKernelGGL(k_prep, dim3(32), dim3(256), 0, stream, x, pts, xe0, sqp, sqe);
  hipLaunchKernelGGL(k_knn3, dim3(2048), dim3(256), 0, stream, pts, sqp, idxP);
  hipLaunchKernelGGL(k_knn3, dim3(2048), dim3(256), 0, stream, xe0, sqe, idx1);
  hipLaunchKernelGGL(k_gauss, dim3(8192), dim3(128), 0, stream, pts, sqp, idxP, kc, kr);

  // edge-conv 1
  hipLaunchKernelGGL(k_ec1_h1, dim3(256), dim3(256), 0, stream, xe0, idx1, e1w1, hbuf, psum, psq);
  hipLaunchKernelGGL(k_fin, dim3(64), dim3(256), 0, stream, psum, psq, 1024, 64, 262144.f, e1g1, e1b1, e1s1, e1t1);
  hipLaunchKernelGGL(k_ec1_h2, dim3(256), dim3(256), 0, stream, hbuf, e1w2, e1s1, e1t1, psum, psq);
  hipLaunchKernelGGL(k_fin, dim3(64), dim3(256), 0, stream, psum, psq, 1024, 64, 262144.f, e1g2, e1b2, e1s2, e1t2);
  hipLaunchKernelGGL(k_ec1_max, dim3(2048), dim3(256), 0, stream, hbuf, e1s2, e1t2, xe1, xe1T, sqx1);

  // knn on 64-d features
  hipLaunchKernelGGL(k_dgemm, dim3(32,32,2), dim3(256), 0, stream, xe1T, sqx1, hbuf);
  hipLaunchKernelGGL(k_knn_sel, dim3(2048), dim3(256), 0, stream, hbuf, idx2);

  // edge-conv 2 (fp32 GEMM formulation, fused stats+max)
  hipLaunchKernelGGL(k_transpose, dim3(64), dim3(256), 0, stream, e2w1, ew1T, 128, 128);
  hipLaunchKernelGGL(k_transpose, dim3(64), dim3(256), 0, stream, e2w2, ew2T, 128, 128);
  hipLaunchKernelGGL(k_ec2g1, dim3(2048), dim3(256), 0, stream, xe1, idx2, ew1T, hbuf, psum, psq);
  hipLaunchKernelGGL(k_fin, dim3(128), dim3(256), 0, stream, psum, psq, 2048, 128, 262144.f, e2g1, e2b1, e2s1, e2t1);
  hipLaunchKernelGGL(k_ec2g2, dim3(2048), dim3(256), 0, stream, hbuf, ew2T, e2s1, e2t1, xe2, psum, psq);
  hipLaunchKernelGGL(k_fin, dim3(128), dim3(256), 0, stream, psum, psq, 2048, 128, 262144.f, e2g2, e2b2, e2s2, e2t2);
  hipLaunchKernelGGL(k_xe2fin, dim3(4096), dim3(256), 0, stream, xe2, e2s2, e2t2);

  // concat + bf16 MFMA cbr chain
  hipLaunchKernelGGL(k_hcat, dim3(8192), dim3(256), 0, stream, xe2, kr, hcat);
  hipLaunchKernelGGL(k_wprep, dim3(128), dim3(256), 0, stream, w1, wb1, 1024, 256);
  hipLaunchKernelGGL(k_wprep, dim3(256), dim3(256), 0, stream, w2, wb2, 512, 1024);
  hipLaunchKernelGGL(k_wprep, dim3(64),  dim3(256), 0, stream, w3, wb3, 256, 512);
  hipLaunchKernelGGL(k_transpose, dim3((9*256+255)/256), dim3(256), 0, stream, w4, wT4, 9, 256);

  hipLaunchKernelGGL(k_bprep, dim3(1024), dim3(256), 0, stream, hcat, (const float*)nullptr, (const float*)nullptr, actB, 256);
  hipLaunchKernelGGL(k_gmm, dim3(64,8), dim3(256), 0, stream, wb1, actB, c1out, 1024, 256);
  hipLaunchKernelGGL(k_cstats, dim3(1024), dim3(256), 0, stream, c1out, 1024, g1, b1, c1s, c1t);

  hipLaunchKernelGGL(k_bprep, dim3(4096), dim3(256), 0, stream, c1out, c1s, c1t, actB, 1024);
  hipLaunchKernelGGL(k_gmm, dim3(64,4), dim3(256), 0, stream, wb2, actB, c2out, 512, 1024);
  hipLaunchKernelGGL(k_cstats, dim3(512), dim3(256), 0, stream, c2out, 512, g2, b2, c2s, c2t);

  hipLaunchKernelGGL(k_bprep, dim3(2048), dim3(256), 0, stream, c2out, c2s, c2t, actB, 512);
  hipLaunchKernelGGL(k_gmm, dim3(64,2), dim3(256), 0, stream, wb3, actB, c3out, 256, 512);
  hipLaunchKernelGGL(k_cstats, dim3(256), dim3(256), 0, stream, c3out, 256, g3, b3, c3s, c3t);

  hipLaunchKernelGGL(k_final4, dim3(16,2), dim3(256), 0, stream, c3out, wT4, c3s, c3t, pmax);
  hipLaunchKernelGGL(k_out, dim3(1), dim3(32), 0, stream, pmax, (float*)d_out);
}

// Round 8
// 900.168 us; speedup vs baseline: 2.7576x; 1.1168x over previous
//
#include <hip/hip_runtime.h>
#include <math.h>

#define WN 4096
#define NP 8192
#define KK 32
#define EPSB 1e-5f

typedef __attribute__((ext_vector_type(8))) short s8v;
typedef __attribute__((ext_vector_type(4))) float f4v;

__device__ __forceinline__ float lrelu(float x){ return fmaxf(x, 0.01f*x); }
__device__ __forceinline__ float rlane(float v, int c){
  return __int_as_float(__builtin_amdgcn_readlane(__float_as_int(v), c));
}
__device__ __forceinline__ short f2bf(float f){
  unsigned u = __float_as_uint(f);
  u = (u + 0x7fffu + ((u>>16)&1u)) >> 16;
  return (short)u;
}

// ---------------- prep ----------------
__global__ void k_prep(const float* __restrict__ x, float* __restrict__ pts, float* __restrict__ xe0,
                       float* __restrict__ sqp, float* __restrict__ sqe){
  int i = blockIdx.x*256 + threadIdx.x;
  if(i >= NP) return;
  int b = i>>12, p = i&4095;
  const float* xb = x + b*12288;
  float a0 = xb[p], a1 = xb[4096+p], a2 = xb[8192+p];
  pts[i*3+0]=a0; pts[i*3+1]=a1; pts[i*3+2]=a2;
  sqp[i] = (a0*a0 + a1*a1) + a2*a2;
  float e0 = xb[p*3+0], e1 = xb[p*3+1], e2 = xb[p*3+2];
  xe0[i*3+0]=e0; xe0[i*3+1]=e1; xe0[i*3+2]=e2;
  sqe[i] = (e0*e0 + e1*e1) + e2*e2;
}

// ---------------- streaming wave top-32 ----------------
__device__ __forceinline__ void topk_stream(float d, int m, int l, float& lv, int& li){
  float thr = rlane(lv, 31);
  int ti = __builtin_amdgcn_readlane(li, 31);
  unsigned long long mask = __ballot(d < thr || (d == thr && m < ti));
  while(mask){
    int s = __ffsll((unsigned long long)mask) - 1;
    float cd = __shfl(d, s);
    int cm = __shfl(m, s);
    unsigned long long less = __ballot(lv < cd || (lv == cd && li < cm));
    int pos = __popcll(less & 0xffffffffULL);
    float uv = __shfl_up(lv, 1);
    int ui = __shfl_up(li, 1);
    if(l < 32){
      if(l == pos){ lv = cd; li = cm; }
      else if(l > pos){ lv = uv; li = ui; }
    }
    mask &= mask - 1;
    if(mask){
      thr = rlane(lv, 31);
      ti = __builtin_amdgcn_readlane(li, 31);
      mask &= __ballot(d < thr || (d == thr && m < ti));
    }
  }
}

__global__ __launch_bounds__(256) void k_knn3(const float* __restrict__ pnt, const float* __restrict__ sq,
                                              int* __restrict__ idx){
  int l = threadIdx.x&63;
  int q = blockIdx.x*4 + (threadIdx.x>>6);
  int b = q>>12, qr = q&4095;
  const float* pb = pnt + (size_t)b*WN*3;
  const float* sb = sq + b*WN;
  float q0=pb[qr*3], q1=pb[qr*3+1], q2=pb[qr*3+2];
  float sqq = sb[qr];
  float lv = 3.4e38f; int li = 0x7fffffff;
  #pragma unroll 4
  for(int j=0;j<64;j++){
    int m = l + (j<<6);
    float d0=pb[m*3], d1=pb[m*3+1], d2=pb[m*3+2];
    float dot = q0*d0 + q1*d1 + q2*d2;
    float d = (sqq - 2.0f*dot) + sb[m];
    topk_stream(d, m, l, lv, li);
  }
  if(l < 32) idx[(size_t)q*KK + l] = li;
}

__global__ __launch_bounds__(256) void k_knn_sel(const float* __restrict__ D, int* __restrict__ idx){
  int l = threadIdx.x&63;
  int q = blockIdx.x*4 + (threadIdx.x>>6);
  int b = q>>12, qr = q&4095;
  const float* row = D + ((size_t)b<<24) + ((size_t)qr<<12);
  float lv = 3.4e38f; int li = 0x7fffffff;
  #pragma unroll 4
  for(int j=0;j<64;j++){
    int m = l + (j<<6);
    float d = row[m];
    topk_stream(d, m, l, lv, li);
  }
  if(l < 32) idx[(size_t)q*KK + l] = li;
}

// ---------------- gaussian kernel conv ----------------
__global__ __launch_bounds__(128) void k_gauss(const float* __restrict__ pts, const float* __restrict__ sqp,
                                               const int* __restrict__ idxP, const float* __restrict__ cen,
                                               float* __restrict__ kout){
  __shared__ float nbx[KK], nby[KK], nbz[KK], nsq[KK];
  int p = blockIdx.x; int b = p>>12; int t = threadIdx.x;
  if(t < KK){
    int id = idxP[(size_t)p*KK + t] + (b<<12);
    nbx[t]=pts[id*3]; nby[t]=pts[id*3+1]; nbz[t]=pts[id*3+2];
    nsq[t]=sqp[id];
  }
  __syncthreads();
  float c0=cen[t*3], c1=cen[t*3+1], c2=cen[t*3+2];
  float sqc=(c0*c0+c1*c1)+c2*c2;
  float acc=0.f;
  #pragma unroll
  for(int k=0;k<KK;k++){
    float dot = nbx[k]*c0 + nby[k]*c1 + nbz[k]*c2;
    float d = (nsq[k] - 2.0f*dot) + sqc;
    acc += expf(-0.5f*d);
  }
  kout[(size_t)((b<<7)+t)*4096 + (p&4095)] = acc;
}

// ---------------- finalize BN stats ----------------
__global__ void k_fin(const float* __restrict__ psum, const float* __restrict__ psq, int NW, int C, float Nn,
                      const float* __restrict__ g, const float* __restrict__ be,
                      float* __restrict__ sc, float* __restrict__ sh){
  int o = blockIdx.x, t = threadIdx.x;
  float s=0.f, q=0.f;
  for(int w=t; w<NW; w+=256){ s += psum[(size_t)w*C+o]; q += psq[(size_t)w*C+o]; }
  __shared__ float ls[256], lq[256];
  ls[t]=s; lq[t]=q; __syncthreads();
  for(int st=128; st; st>>=1){ if(t<st){ ls[t]+=ls[t+st]; lq[t]+=lq[t+st]; } __syncthreads(); }
  if(t==0){
    float mu = ls[0]/Nn;
    float var = lq[0]/Nn - mu*mu; if(var<0.f) var=0.f;
    float s1 = g[o]*rsqrtf(var + EPSB);
    sc[o]=s1; sh[o]=be[o]-mu*s1;
  }
}

// ---------------- edge-conv 1: stats-only h1 pass (h1 recomputed later, never stored) ----------------
__global__ __launch_bounds__(256) void k_ec1s(const float* __restrict__ xe0, const int* __restrict__ idx1,
                                              const float* __restrict__ w1,
                                              float* __restrict__ psum, float* __restrict__ psq){
  int wid = (blockIdx.x*256 + threadIdx.x)>>6;   // < 1024
  int l = threadIdx.x&63;
  float wr[6];
  #pragma unroll
  for(int c=0;c<6;c++) wr[c] = w1[l*6+c];
  float s=0.f, ss=0.f;
  for(int p=wid; p<NP; p+=1024){
    int bb = (p>>12)<<12;
    float x0=xe0[p*3], x1=xe0[p*3+1], x2=xe0[p*3+2];
    const int* ip = idx1 + (size_t)p*KK;
    for(int k=0;k<KK;k++){
      int id = ip[k];
      const float* nb = xe0 + (size_t)(bb+id)*3;
      float h = wr[0]*(nb[0]-x0) + wr[1]*(nb[1]-x1) + wr[2]*(nb[2]-x2)
              + wr[3]*x0 + wr[4]*x1 + wr[5]*x2;
      s += h; ss += h*h;
    }
  }
  psum[(size_t)wid*64+l]=s; psq[(size_t)wid*64+l]=ss;
}

// ---------------- edge-conv 1 fused: rebuild y1 tile in LDS, GEMM h2=W2*y1, stats + per-point max ----------------
__global__ __launch_bounds__(256) void k_ec1g2(const float* __restrict__ xe0, const int* __restrict__ idx1,
                                               const float* __restrict__ w1, const float* __restrict__ w2T,
                                               const float* __restrict__ s1, const float* __restrict__ t1,
                                               float* __restrict__ h2m, float* __restrict__ psum,
                                               float* __restrict__ psq){
  __shared__ float As[64*64];
  __shared__ float Bs[64*132];
  __shared__ float feat[6][128];
  __shared__ float w1l[384];
  int t = threadIdx.x;
  int blk = blockIdx.x;
  int s0 = blk*128;
  int pbase = s0>>5;
  int bb = (s0>>17)<<12;
  #pragma unroll
  for(int i=0;i<16;i++) As[t + i*256] = w2T[t + i*256];
  for(int i=t; i<384; i+=256) w1l[i] = w1[i];   // FIX: block has 256 threads, w1 has 384 elems
  if(t < 128){
    int s = s0 + t;
    int p = pbase + (t>>5);
    int id = bb + idx1[s];
    const float* nb = xe0 + (size_t)id*3;
    const float* xc = xe0 + (size_t)p*3;
    float x0 = xc[0], x1 = xc[1], x2 = xc[2];
    feat[0][t] = nb[0]-x0; feat[1][t] = nb[1]-x1; feat[2][t] = nb[2]-x2;
    feat[3][t] = x0; feat[4][t] = x1; feat[5][t] = x2;
  }
  __syncthreads();
  #pragma unroll
  for(int i=0;i<32;i++){
    int e = t + (i<<8);
    int k = e>>7, n = e&127;
    float h = w1l[k*6+0]*feat[0][n] + w1l[k*6+1]*feat[1][n] + w1l[k*6+2]*feat[2][n]
            + w1l[k*6+3]*feat[3][n] + w1l[k*6+4]*feat[4][n] + w1l[k*6+5]*feat[5][n];
    Bs[k*132 + n] = lrelu(fmaf(h, s1[k], t1[k]));
  }
  __syncthreads();
  int tx = t&15, ty = t>>4;
  float acc[4][8];
  #pragma unroll
  for(int i=0;i<4;i++){
    #pragma unroll
    for(int j=0;j<8;j++) acc[i][j]=0.f;
  }
  #pragma unroll 4
  for(int k=0;k<64;k++){
    float4 a  = *(const float4*)&As[k*64 + ty*4];
    float4 b0 = *(const float4*)&Bs[k*132 + tx*4];
    float4 b1 = *(const float4*)&Bs[k*132 + 64 + tx*4];
    float av[4] = {a.x,a.y,a.z,a.w};
    float bv[8] = {b0.x,b0.y,b0.z,b0.w,b1.x,b1.y,b1.z,b1.w};
    #pragma unroll
    for(int i=0;i<4;i++){
      #pragma unroll
      for(int j=0;j<8;j++) acc[i][j] = fmaf(av[i], bv[j], acc[i][j]);
    }
  }
  #pragma unroll
  for(int i=0;i<4;i++){
    int m = ty*4 + i;
    float sr = ((acc[i][0]+acc[i][1])+(acc[i][2]+acc[i][3])) + ((acc[i][4]+acc[i][5])+(acc[i][6]+acc[i][7]));
    float sq = ((acc[i][0]*acc[i][0]+acc[i][1]*acc[i][1])+(acc[i][2]*acc[i][2]+acc[i][3]*acc[i][3]))
             + ((acc[i][4]*acc[i][4]+acc[i][5]*acc[i][5])+(acc[i][6]*acc[i][6]+acc[i][7]*acc[i][7]));
    #pragma unroll
    for(int off=1; off<16; off<<=1){ sr += __shfl_xor(sr, off); sq += __shfl_xor(sq, off); }
    if(tx==0){ psum[(size_t)blk*64+m]=sr; psq[(size_t)blk*64+m]=sq; }
    float m0 = fmaxf(fmaxf(acc[i][0],acc[i][1]), fmaxf(acc[i][2],acc[i][3]));
    float m1 = fmaxf(fmaxf(acc[i][4],acc[i][5]), fmaxf(acc[i][6],acc[i][7]));
    #pragma unroll
    for(int off=1; off<8; off<<=1){ m0 = fmaxf(m0, __shfl_xor(m0, off)); m1 = fmaxf(m1, __shfl_xor(m1, off)); }
    if((tx&7)==0){
      int pl = pbase + (tx>>3);
      h2m[(size_t)pl*64 + m]     = m0;
      h2m[(size_t)(pl+2)*64 + m] = m1;
    }
  }
}

// ---------------- ec1 finalize: xe1 = lrelu(BN2(h2max)), emit xe1T + row norms ----------------
__global__ __launch_bounds__(256) void k_ec1fin(const float* __restrict__ h2m, const float* __restrict__ s2,
                                                const float* __restrict__ t2, float* __restrict__ xe1,
                                                float* __restrict__ xe1T, float* __restrict__ sqx){
  int gid = blockIdx.x*256 + threadIdx.x;  // < NP*64
  int p = gid>>6, l = gid&63;
  float v = lrelu(fmaf(h2m[(size_t)p*64+l], s2[l], t2[l]));
  xe1[(size_t)p*64+l] = v;
  int b=p>>12, pr=p&4095;
  xe1T[(size_t)(b*64+l)*4096 + pr] = v;
  float sq = v*v;
  #pragma unroll
  for(int off=32; off; off>>=1) sq += __shfl_xor(sq, off);
  if(l==0) sqx[p]=sq;
}

// ---------------- D = sq_n - 2 X X^T + sq_m ----------------
__global__ __launch_bounds__(256) void k_dgemm(const float* __restrict__ xT, const float* __restrict__ sqx,
                                               float* __restrict__ D){
  __shared__ float As[32*128], Bs2[32*128];
  int b = blockIdx.z;
  int m0 = blockIdx.y*128, n0 = blockIdx.x*128;
  int t = threadIdx.x;
  int tx = t&15, ty = t>>4;
  const float* xb = xT + (size_t)b*64*4096;
  float acc[8][8];
  #pragma unroll
  for(int i=0;i<8;i++){
    #pragma unroll
    for(int j=0;j<8;j++) acc[i][j]=0.f;
  }
  for(int kc=0;kc<2;kc++){
    __syncthreads();
    #pragma unroll
    for(int i=0;i<16;i++){
      int e = t + (i<<8);
      int k = e>>7, mm = e&127;
      As[k*128+mm]  = xb[(size_t)(kc*32+k)*4096 + m0+mm];
      Bs2[k*128+mm] = xb[(size_t)(kc*32+k)*4096 + n0+mm];
    }
    __syncthreads();
    #pragma unroll 4
    for(int k=0;k<32;k++){
      float av[8], bv[8];
      float4 A0 = *(float4*)&As[k*128 + ty*8];
      float4 A1 = *(float4*)&As[k*128 + ty*8+4];
      float4 B0 = *(float4*)&Bs2[k*128 + tx*8];
      float4 B1 = *(float4*)&Bs2[k*128 + tx*8+4];
      av[0]=A0.x; av[1]=A0.y; av[2]=A0.z; av[3]=A0.w; av[4]=A1.x; av[5]=A1.y; av[6]=A1.z; av[7]=A1.w;
      bv[0]=B0.x; bv[1]=B0.y; bv[2]=B0.z; bv[3]=B0.w; bv[4]=B1.x; bv[5]=B1.y; bv[6]=B1.z; bv[7]=B1.w;
      #pragma unroll
      for(int i=0;i<8;i++){
        #pragma unroll
        for(int j=0;j<8;j++) acc[i][j] = fmaf(av[i], bv[j], acc[i][j]);
      }
    }
  }
  const float* sb = sqx + (b<<12);
  float* Db = D + ((size_t)b<<24);
  #pragma unroll
  for(int i=0;i<8;i++){
    int r = m0 + ty*8 + i;
    float sqa = sb[r];
    float o[8];
    #pragma unroll
    for(int j=0;j<8;j++) o[j] = (sqa - 2.0f*acc[i][j]) + sb[n0+tx*8+j];
    *(float4*)&Db[(size_t)r*4096 + n0+tx*8]   = make_float4(o[0],o[1],o[2],o[3]);
    *(float4*)&Db[(size_t)r*4096 + n0+tx*8+4] = make_float4(o[4],o[5],o[6],o[7]);
  }
}

// ---------------- edge-conv 2 pass 1 ----------------
__global__ __launch_bounds__(256) void k_ec2g1(const float* __restrict__ xe1, const int* __restrict__ idx2,
                                               const float* __restrict__ w1T, float* __restrict__ h1T,
                                               float* __restrict__ psum, float* __restrict__ psq){
  __shared__ float As[32*128];
  __shared__ float Bs[32*132];
  __shared__ float cts[256];
  __shared__ int nid[128];
  int t = threadIdx.x;
  int blk = blockIdx.x;
  int s0 = blk*128;
  int pbase = s0>>5;
  int bb = (s0>>17)<<12;
  if(t<128) nid[t] = (idx2[s0 + t] + bb)<<6;
  cts[t] = xe1[(size_t)(pbase + (t>>6))*64 + (t&63)];
  int tx = t&15, ty = t>>4;
  float acc[8][8];
  #pragma unroll
  for(int i=0;i<8;i++){
    #pragma unroll
    for(int j=0;j<8;j++) acc[i][j]=0.f;
  }
  for(int kc=0;kc<128;kc+=32){
    __syncthreads();
    #pragma unroll
    for(int i=0;i<16;i++){
      int e = t + (i<<8);
      int k = e>>7, m = e&127;
      As[e] = w1T[(kc+k)*128 + m];
    }
    #pragma unroll
    for(int i=0;i<4;i++){
      int e = t + (i<<8);
      int kg = e&7, n = e>>3;
      int c0 = (kc&63) + (kg<<2);
      float4 v;
      if(kc < 64){
        float4 a = *(const float4*)&xe1[nid[n] + c0];
        float4 c = *(const float4*)&cts[((n>>5)<<6) + c0];
        v = make_float4(a.x-c.x, a.y-c.y, a.z-c.z, a.w-c.w);
      } else {
        v = *(const float4*)&cts[((n>>5)<<6) + c0];
      }
      int base = (kg<<2)*132 + n;
      Bs[base]=v.x; Bs[base+132]=v.y; Bs[base+264]=v.z; Bs[base+396]=v.w;
    }
    __syncthreads();
    #pragma unroll 4
    for(int k=0;k<32;k++){
      float av[8], bv[8];
      float4 A0 = *(const float4*)&As[k*128 + ty*4];
      float4 A1 = *(const float4*)&As[k*128 + 64 + ty*4];
      float4 B0 = *(const float4*)&Bs[k*132 + tx*4];
      float4 B1 = *(const float4*)&Bs[k*132 + 64 + tx*4];
      av[0]=A0.x; av[1]=A0.y; av[2]=A0.z; av[3]=A0.w; av[4]=A1.x; av[5]=A1.y; av[6]=A1.z; av[7]=A1.w;
      bv[0]=B0.x; bv[1]=B0.y; bv[2]=B0.z; bv[3]=B0.w; bv[4]=B1.x; bv[5]=B1.y; bv[6]=B1.z; bv[7]=B1.w;
      #pragma unroll
      for(int i=0;i<8;i++){
        #pragma unroll
        for(int j=0;j<8;j++) acc[i][j] = fmaf(av[i], bv[j], acc[i][j]);
      }
    }
  }
  float* ob = h1T + s0;
  #pragma unroll
  for(int i=0;i<8;i++){
    int row = ((i>>2)<<6) + ty*4 + (i&3);
    *(float4*)&ob[(size_t)row*262144 + tx*4]      = make_float4(acc[i][0],acc[i][1],acc[i][2],acc[i][3]);
    *(float4*)&ob[(size_t)row*262144 + 64 + tx*4] = make_float4(acc[i][4],acc[i][5],acc[i][6],acc[i][7]);
    float sr = ((acc[i][0]+acc[i][1])+(acc[i][2]+acc[i][3])) + ((acc[i][4]+acc[i][5])+(acc[i][6]+acc[i][7]));
    float sq = ((acc[i][0]*acc[i][0]+acc[i][1]*acc[i][1])+(acc[i][2]*acc[i][2]+acc[i][3]*acc[i][3]))
             + ((acc[i][4]*acc[i][4]+acc[i][5]*acc[i][5])+(acc[i][6]*acc[i][6]+acc[i][7]*acc[i][7]));
    #pragma unroll
    for(int off=1; off<16; off<<=1){ sr += __shfl_xor(sr, off); sq += __shfl_xor(sq, off); }
    if(tx==0){ psum[(size_t)blk*128+row]=sr; psq[(size_t)blk*128+row]=sq; }
  }
}

// ---------------- edge-conv 2 pass 2 ----------------
__global__ __launch_bounds__(256) void k_ec2g2(const float* __restrict__ h1T, const float* __restrict__ w2T,
                                               const float* __restrict__ s1, const float* __restrict__ t1,
                                               float* __restrict__ h2max, float* __restrict__ psum,
                                               float* __restrict__ psq){
  __shared__ float As[32*128];
  __shared__ float Bs[32*132];
  int t = threadIdx.x;
  int blk = blockIdx.x;
  int s0 = blk*128;
  int pbase = s0>>5;
  int tx = t&15, ty = t>>4;
  float acc[8][8];
  #pragma unroll
  for(int i=0;i<8;i++){
    #pragma unroll
    for(int j=0;j<8;j++) acc[i][j]=0.f;
  }
  for(int kc=0;kc<128;kc+=32){
    __syncthreads();
    #pragma unroll
    for(int i=0;i<16;i++){
      int e = t + (i<<8);
      int k = e>>7, m = e&127;
      As[e] = w2T[(kc+k)*128 + m];
    }
    #pragma unroll
    for(int i=0;i<4;i++){
      int e = t + (i<<8);
      int k = e>>5, n4 = (e&31)<<2;
      float4 v = *(const float4*)&h1T[(size_t)(kc+k)*262144 + s0 + n4];
      float a = s1[kc+k], h = t1[kc+k];
      v.x = lrelu(fmaf(v.x,a,h)); v.y = lrelu(fmaf(v.y,a,h));
      v.z = lrelu(fmaf(v.z,a,h)); v.w = lrelu(fmaf(v.w,a,h));
      *(float4*)&Bs[k*132 + n4] = v;
    }
    __syncthreads();
    #pragma unroll 4
    for(int k=0;k<32;k++){
      float av[8], bv[8];
      float4 A0 = *(const float4*)&As[k*128 + ty*4];
      float4 A1 = *(const float4*)&As[k*128 + 64 + ty*4];
      float4 B0 = *(const float4*)&Bs[k*132 + tx*4];
      float4 B1 = *(const float4*)&Bs[k*132 + 64 + tx*4];
      av[0]=A0.x; av[1]=A0.y; av[2]=A0.z; av[3]=A0.w; av[4]=A1.x; av[5]=A1.y; av[6]=A1.z; av[7]=A1.w;
      bv[0]=B0.x; bv[1]=B0.y; bv[2]=B0.z; bv[3]=B0.w; bv[4]=B1.x; bv[5]=B1.y; bv[6]=B1.z; bv[7]=B1.w;
      #pragma unroll
      for(int i=0;i<8;i++){
        #pragma unroll
        for(int j=0;j<8;j++) acc[i][j] = fmaf(av[i], bv[j], acc[i][j]);
      }
    }
  }
  #pragma unroll
  for(int i=0;i<8;i++){
    int row = ((i>>2)<<6) + ty*4 + (i&3);
    float sr = ((acc[i][0]+acc[i][1])+(acc[i][2]+acc[i][3])) + ((acc[i][4]+acc[i][5])+(acc[i][6]+acc[i][7]));
    float sq = ((acc[i][0]*acc[i][0]+acc[i][1]*acc[i][1])+(acc[i][2]*acc[i][2]+acc[i][3]*acc[i][3]))
             + ((acc[i][4]*acc[i][4]+acc[i][5]*acc[i][5])+(acc[i][6]*acc[i][6]+acc[i][7]*acc[i][7]));
    #pragma unroll
    for(int off=1; off<16; off<<=1){ sr += __shfl_xor(sr, off); sq += __shfl_xor(sq, off); }
    if(tx==0){ psum[(size_t)blk*128+row]=sr; psq[(size_t)blk*128+row]=sq; }
    float m0 = fmaxf(fmaxf(acc[i][0],acc[i][1]), fmaxf(acc[i][2],acc[i][3]));
    float m1 = fmaxf(fmaxf(acc[i][4],acc[i][5]), fmaxf(acc[i][6],acc[i][7]));
    #pragma unroll
    for(int off=1; off<8; off<<=1){ m0 = fmaxf(m0, __shfl_xor(m0, off)); m1 = fmaxf(m1, __shfl_xor(m1, off)); }
    if((tx&7)==0){
      int pl = pbase + (tx>>3);
      h2max[(size_t)pl*128 + row]     = m0;
      h2max[(size_t)(pl+2)*128 + row] = m1;
    }
  }
}

// ---------------- xe2 = lrelu(BN(h2max)) in-place ----------------
__global__ void k_xe2fin(float* __restrict__ xe2, const float* __restrict__ s2, const float* __restrict__ t2){
  int i = blockIdx.x*256 + threadIdx.x;   // < NP*128
  if(i >= NP*128) return;
  int o = i&127;
  xe2[i] = lrelu(fmaf(xe2[i], s2[o], t2[o]));
}

// ---------------- hcat ----------------
__global__ void k_hcat(const float* __restrict__ xe2, const float* __restrict__ kr, float* __restrict__ hcat){
  size_t i = (size_t)blockIdx.x*256 + threadIdx.x;
  int b = (int)(i>>20);
  int r = (int)(i & 1048575);
  int ch = r>>12;
  float v;
  if(ch < 128) v = xe2[(size_t)b*524288 + r];
  else         v = kr [(size_t)(b*128 + (ch-128))*4096 + (r&4095)];
  hcat[i] = v;
}

// ---------------- generic small transpose ----------------
__global__ void k_transpose(const float* __restrict__ w, float* __restrict__ wT, int O, int C){
  int i = blockIdx.x*256 + threadIdx.x;
  if(i >= O*C) return;
  int o = i / C, c = i % C;
  wT[(size_t)c*O + o] = w[i];
}

// ---------------- weight fp32 -> bf16 fragment-linear ----------------
__global__ void k_wprep(const float* __restrict__ w, short* __restrict__ wb, int M, int K){
  int tid = blockIdx.x*256 + threadIdx.x;
  int m = tid % M, kb8 = tid / M;
  int k0 = kb8*8;
  float4 v0 = *(const float4*)&w[(size_t)m*K + k0];
  float4 v1 = *(const float4*)&w[(size_t)m*K + k0 + 4];
  s8v r;
  r[0]=f2bf(v0.x); r[1]=f2bf(v0.y); r[2]=f2bf(v0.z); r[3]=f2bf(v0.w);
  r[4]=f2bf(v1.x); r[5]=f2bf(v1.y); r[6]=f2bf(v1.z); r[7]=f2bf(v1.w);
  int region = (m>>7)*(K>>6) + (k0>>6);
  int chunk = ((kb8>>2)&1)*8 + ((m>>4)&7);
  int lane = (kb8&3)*16 + (m&15);
  *(s8v*)&wb[(size_t)region*8192 + chunk*512 + lane*8] = r;
}

// ---------------- activations -> bf16 fragment-linear ----------------
__global__ void k_bprep(const float* __restrict__ in, const float* __restrict__ sc, const float* __restrict__ sh,
                        short* __restrict__ ob, int K){
  int tid = blockIdx.x*256 + threadIdx.x;
  int n = tid & 8191, kb8 = tid >> 13;
  int k0 = kb8*8;
  int b = n>>12, s = n&4095;
  const float* ib = in + ((size_t)b*K + k0)*4096 + s;
  float v[8];
  #pragma unroll
  for(int j=0;j<8;j++) v[j] = ib[(size_t)j*4096];
  if(sc){
    #pragma unroll
    for(int j=0;j<8;j++) v[j] = lrelu(fmaf(v[j], sc[k0+j], sh[k0+j]));
  }
  s8v r;
  #pragma unroll
  for(int j=0;j<8;j++) r[j] = f2bf(v[j]);
  int region = (n>>7)*(K>>6) + (k0>>6);
  int chunk = ((kb8>>2)&1)*8 + ((n>>4)&7);
  int lane = (kb8&3)*16 + (n&15);
  *(s8v*)&ob[(size_t)region*8192 + chunk*512 + lane*8] = r;
}

// ---------------- bf16 MFMA GEMM ----------------
__global__ __launch_bounds__(256) void k_gmm(const short* __restrict__ A, const short* __restrict__ B,
                                             float* __restrict__ out, int M, int K){
  __shared__ short sA[8192], sB[8192];
  int t = threadIdx.x;
  int lane = t&63;
  int w = t>>6;
  int wm4 = (w>>1)*4, wn4 = (w&1)*4;
  int mb = blockIdx.y, nb = blockIdx.x;
  int ksteps = K>>6;
  const short* AG = A + (size_t)mb*ksteps*8192;
  const short* BG = B + (size_t)nb*ksteps*8192;
  f4v acc[4][4];
  #pragma unroll
  for(int i=0;i<4;i++){
    #pragma unroll
    for(int j=0;j<4;j++) acc[i][j] = (f4v)(0.f);
  }
  for(int st=0; st<ksteps; ++st){
    __syncthreads();
    #pragma unroll
    for(int i=0;i<4;i++){
      int slot = t + i*256;
      *(s8v*)&sA[slot*8] = *(const s8v*)&AG[(size_t)st*8192 + slot*8];
      *(s8v*)&sB[slot*8] = *(const s8v*)&BG[(size_t)st*8192 + slot*8];
    }
    __syncthreads();
    #pragma unroll
    for(int kh=0;kh<2;kh++){
      s8v av[4], bv[4];
      #pragma unroll
      for(int f=0;f<4;f++) av[f] = *(const s8v*)&sA[(kh*8 + wm4 + f)*512 + lane*8];
      #pragma unroll
      for(int f=0;f<4;f++) bv[f] = *(const s8v*)&sB[(kh*8 + wn4 + f)*512 + lane*8];
      #pragma unroll
      for(int fm=0;fm<4;fm++){
        #pragma unroll
        for(int fn=0;fn<4;fn++)
          acc[fm][fn] = __builtin_amdgcn_mfma_f32_16x16x32_bf16(av[fm], bv[fn], acc[fm][fn], 0, 0, 0);
      }
    }
  }
  int l15 = lane&15, l4 = (lane>>4)*4;
  #pragma unroll
  for(int fm=0;fm<4;fm++){
    int mrow = mb*128 + wm4*16 + fm*16 + l4;
    #pragma unroll
    for(int fn=0;fn<4;fn++){
      int n = nb*128 + wn4*16 + fn*16 + l15;
      int b = n>>12, s = n&4095;
      float* ob = out + ((size_t)b*M + mrow)*4096 + s;
      #pragma unroll
      for(int r=0;r<4;r++) ob[(size_t)r*4096] = acc[fm][fn][r];
    }
  }
}

// ---------------- per-channel stats for cbr layers ----------------
__global__ void k_cstats(const float* __restrict__ buf, int C, const float* __restrict__ g,
                         const float* __restrict__ be, float* __restrict__ sc, float* __restrict__ sh){
  int o = blockIdx.x, t = threadIdx.x;
  float s=0.f, q=0.f;
  for(int i=t;i<8192;i+=256){
    int b=i>>12, ss_=i&4095;
    float v = buf[(size_t)(b*C+o)*4096 + ss_];
    s+=v; q+=v*v;
  }
  __shared__ float ls[256], lq[256];
  ls[t]=s; lq[t]=q; __syncthreads();
  for(int st=128; st; st>>=1){ if(t<st){ ls[t]+=ls[t+st]; lq[t]+=lq[t+st]; } __syncthreads(); }
  if(t==0){
    float mu = ls[0]/8192.f;
    float var = lq[0]/8192.f - mu*mu; if(var<0.f) var=0.f;
    float s1 = g[o]*rsqrtf(var + EPSB);
    sc[o]=s1; sh[o]=be[o]-mu*s1;
  }
}

// ---------------- final layer ----------------
__global__ __launch_bounds__(256) void k_final4(const float* __restrict__ c3, const float* __restrict__ w4T,
                                                const float* __restrict__ sc, const float* __restrict__ sh,
                                                float* __restrict__ pmax){
  int b = blockIdx.y, st = blockIdx.x;
  int t = threadIdx.x; int s = st*256 + t;
  float acc[9];
  #pragma unroll
  for(int j=0;j<9;j++) acc[j]=0.f;
  const float* ib = c3 + (size_t)b*256*4096;
  for(int c=0;c<256;c++){
    float x = lrelu(fmaf(ib[(size_t)c*4096+s], sc[c], sh[c]));
    #pragma unroll
    for(int j=0;j<9;j++) acc[j]=fmaf(x, w4T[c*9+j], acc[j]);
  }
  __shared__ float red[256];
  for(int j=0;j<9;j++){
    red[t]=acc[j]; __syncthreads();
    for(int stp=128; stp; stp>>=1){ if(t<stp) red[t]=fmaxf(red[t],red[t+stp]); __syncthreads(); }
    if(t==0) pmax[(b*16+st)*9 + j]=red[0];
    __syncthreads();
  }
}

__global__ void k_out(const float* __restrict__ pmax, float* __restrict__ out){
  int i = threadIdx.x;
  if(i<18){
    int b=i/9, o=i%9;
    float m=-3.4e38f;
    for(int k=0;k<16;k++) m=fmaxf(m, pmax[(b*16+k)*9+o]);
    out[i] = m + ((o==0||o==4||o==8)?1.f:0.f);
  }
}

// ---------------- launch ----------------
extern "C" void kernel_launch(void* const* d_in, const int* in_sizes, int n_in,
                              void* d_out, int out_size, void* d_ws, size_t ws_size,
                              hipStream_t stream){
  const float* x    = (const float*)d_in[0];
  const float* kc   = (const float*)d_in[1];
  const float* e1w1 = (const float*)d_in[2];
  const float* e1g1 = (const float*)d_in[3];
  const float* e1b1 = (const float*)d_in[4];
  const float* e1w2 = (const float*)d_in[5];
  const float* e1g2 = (const float*)d_in[6];
  const float* e1b2 = (const float*)d_in[7];
  const float* e2w1 = (const float*)d_in[8];
  const float* e2g1 = (const float*)d_in[9];
  const float* e2b1 = (const float*)d_in[10];
  const float* e2w2 = (const float*)d_in[11];
  const float* e2g2 = (const float*)d_in[12];
  const float* e2b2 = (const float*)d_in[13];
  const float* w1   = (const float*)d_in[14];
  const float* g1   = (const float*)d_in[15];
  const float* b1   = (const float*)d_in[16];
  const float* w2   = (const float*)d_in[17];
  const float* g2   = (const float*)d_in[18];
  const float* b2   = (const float*)d_in[19];
  const float* w3   = (const float*)d_in[20];
  const float* g3   = (const float*)d_in[21];
  const float* b3   = (const float*)d_in[22];
  const float* w4   = (const float*)d_in[23];

  if(ws_size < 156061696ull) return;
  char* ws = (char*)d_ws;
  float* pts   = (float*)(ws + 0);
  float* xe0   = (float*)(ws + 98304);
  float* sqp   = (float*)(ws + 196608);
  float* sqe   = (float*)(ws + 229376);
  float* sqx1  = (float*)(ws + 262144);
  float* xe1   = (float*)(ws + 294912);
  float* xe1T  = (float*)(ws + 2392064);
  float* xe2   = (float*)(ws + 4489216);
  float* kr    = (float*)(ws + 8683520);
  int*   idxP  = (int*)  (ws + 12877824);
  int*   idx1  = (int*)  (ws + 13926400);
  int*   idx2  = (int*)  (ws + 14974976);
  float* psum  = (float*)(ws + 16023552);
  float* psq   = (float*)(ws + 17072128);
  float* par   = (float*)(ws + 18120704);
  float* pmax  = (float*)(ws + 18153472);
  float* e1w2T = (float*)(ws + 18157568);
  float* wT4   = (float*)(ws + 21827584);
  float* hbuf  = (float*)(ws + 21843968);
  float* ew1T  = (float*)(ws + 0);
  float* ew2T  = (float*)(ws + 65536);
  short* actB  = (short*)(ws + 88952832);
  short* wb1   = (short*)(ws + 105730048);
  short* wb2   = (short*)(ws + 106254336);
  short* wb3   = (short*)(ws + 107302912);

  float* e1s1 = par+0;    float* e1t1 = par+64;
  float* e1s2 = par+128;  float* e1t2 = par+192;
  float* e2s1 = par+256;  float* e2t1 = par+384;
  float* e2s2 = par+512;  float* e2t2 = par+640;
  float* c1s  = par+768;  float* c1t  = par+1792;
  float* c2s  = par+2816; float* c2t  = par+3328;
  float* c3s  = par+3840; float* c3t  = par+4096;

  float* hcat  = hbuf;
  float* c1out = hbuf + 2097152;
  float* c2out = hbuf + 10485760;
  float* c3out = hbuf + 14680064;

  hipLaunchKernelGGL(k_prep, dim3(32), dim3(256), 0, stream, x, pts, xe0, sqp, sqe);
  hipLaunchKernelGGL(k_knn3, dim3(2048), dim3(256), 0, stream, pts, sqp, idxP);
  hipLaunchKernelGGL(k_knn3, dim3(2048), dim3(256), 0, stream, xe0, sqe, idx1);
  hipLaunchKernelGGL(k_gauss, dim3(8192), dim3(128), 0, stream, pts, sqp, idxP, kc, kr);

  // edge-conv 1 (recompute-h1 GEMM formulation; h1 never hits HBM)
  hipLaunchKernelGGL(k_transpose, dim3(16), dim3(256), 0, stream, e1w2, e1w2T, 64, 64);
  hipLaunchKernelGGL(k_ec1s, dim3(256), dim3(256), 0, stream, xe0, idx1, e1w1, psum, psq);
  hipLaunchKernelGGL(k_fin, dim3(64), dim3(256), 0, stream, psum, psq, 1024, 64, 262144.f, e1g1, e1b1, e1s1, e1t1);
  hipLaunchKernelGGL(k_ec1g2, dim3(2048), dim3(256), 0, stream, xe0, idx1, e1w1, e1w2T, e1s1, e1t1, hbuf, psum, psq);
  hipLaunchKernelGGL(k_fin, dim3(64), dim3(256), 0, stream, psum, psq, 2048, 64, 262144.f, e1g2, e1b2, e1s2, e1t2);
  hipLaunchKernelGGL(k_ec1fin, dim3(2048), dim3(256), 0, stream, hbuf, e1s2, e1t2, xe1, xe1T, sqx1);

  // knn on 64-d features
  hipLaunchKernelGGL(k_dgemm, dim3(32,32,2), dim3(256), 0, stream, xe1T, sqx1, hbuf);
  hipLaunchKernelGGL(k_knn_sel, dim3(2048), dim3(256), 0, stream, hbuf, idx2);

  // edge-conv 2 (fp32 GEMM formulation, fused stats+max)
  hipLaunchKernelGGL(k_transpose, dim3(64), dim3(256), 0, stream, e2w1, ew1T, 128, 128);
  hipLaunchKernelGGL(k_transpose, dim3(64), dim3(256), 0, stream, e2w2, ew2T, 128, 128);
  hipLaunchKernelGGL(k_ec2g1, dim3(2048), dim3(256), 0, stream, xe1, idx2, ew1T, hbuf, psum, psq);
  hipLaunchKernelGGL(k_fin, dim3(128), dim3(256), 0, stream, psum, psq, 2048, 128, 262144.f, e2g1, e2b1, e2s1, e2t1);
  hipLaunchKernelGGL(k_ec2g2, dim3(2048), dim3(256), 0, stream, hbuf, ew2T, e2s1, e2t1, xe2, psum, psq);
  hipLaunchKernelGGL(k_fin, dim3(128), dim3(256), 0, stream, psum, psq, 2048, 128, 262144.f, e2g2, e2b2, e2s2, e2t2);
  hipLaunchKernelGGL(k_xe2fin, dim3(4096), dim3(256), 0, stream, xe2, e2s2, e2t2);

  // concat + bf16 MFMA cbr chain
  hipLaunchKernelGGL(k_hcat, dim3(8192), dim3(256), 0, stream, xe2, kr, hcat);
  hipLaunchKernelGGL(k_wprep, dim3(128), dim3(256), 0, stream, w1, wb1, 1024, 256);
  hipLaunchKernelGGL(k_wprep, dim3(256), dim3(256), 0, stream, w2, wb2, 512, 1024);
  hipLaunchKernelGGL(k_wprep, dim3(64),  dim3(256), 0, stream, w3, wb3, 256, 512);
  hipLaunchKernelGGL(k_transpose, dim3((9*256+255)/256), dim3(256), 0, stream, w4, wT4, 9, 256);

  hipLaunchKernelGGL(k_bprep, dim3(1024), dim3(256), 0, stream, hcat, (const float*)nullptr, (const float*)nullptr, actB, 256);
  hipLaunchKernelGGL(k_gmm, dim3(64,8), dim3(256), 0, stream, wb1, actB, c1out, 1024, 256);
  hipLaunchKernelGGL(k_cstats, dim3(1024), dim3(256), 0, stream, c1out, 1024, g1, b1, c1s, c1t);

  hipLaunchKernelGGL(k_bprep, dim3(4096), dim3(256), 0, stream, c1out, c1s, c1t, actB, 1024);
  hipLaunchKernelGGL(k_gmm, dim3(64,4), dim3(256), 0, stream, wb2, actB, c2out, 512, 1024);
  hipLaunchKernelGGL(k_cstats, dim3(512), dim3(256), 0, stream, c2out, 512, g2, b2, c2s, c2t);

  hipLaunchKernelGGL(k_bprep, dim3(2048), dim3(256), 0, stream, c2out, c2s, c2t, actB, 512);
  hipLaunchKernelGGL(k_gmm, dim3(64,2), dim3(256), 0, stream, wb3, actB, c3out, 256, 512);
  hipLaunchKernelGGL(k_cstats, dim3(256), dim3(256), 0, stream, c3out, 256, g3, b3, c3s, c3t);

  hipLaunchKernelGGL(k_final4, dim3(16,2), dim3(256), 0, stream, c3out, wT4, c3s, c3t, pmax);
  hipLaunchKernelGGL(k_out, dim3(1), dim3(32), 0, stream, pmax, (float*)d_out);
}

// Round 9
// 783.709 us; speedup vs baseline: 3.1674x; 1.1486x over previous
//
#include <hip/hip_runtime.h>
#include <math.h>

#define WN 4096
#define NP 8192
#define KK 32
#define EPSB 1e-5f

typedef __attribute__((ext_vector_type(8))) short s8v;
typedef __attribute__((ext_vector_type(4))) float f4v;

__device__ __forceinline__ float lrelu(float x){ return fmaxf(x, 0.01f*x); }
__device__ __forceinline__ float rlane(float v, int c){
  return __int_as_float(__builtin_amdgcn_readlane(__float_as_int(v), c));
}
__device__ __forceinline__ short f2bf(float f){
  unsigned u = __float_as_uint(f);
  u = (u + 0x7fffu + ((u>>16)&1u)) >> 16;
  return (short)u;
}

// ---------------- prep ----------------
__global__ void k_prep(const float* __restrict__ x, float* __restrict__ pts, float* __restrict__ xe0,
                       float* __restrict__ sqp, float* __restrict__ sqe){
  int i = blockIdx.x*256 + threadIdx.x;
  if(i >= NP) return;
  int b = i>>12, p = i&4095;
  const float* xb = x + b*12288;
  float a0 = xb[p], a1 = xb[4096+p], a2 = xb[8192+p];
  pts[i*3+0]=a0; pts[i*3+1]=a1; pts[i*3+2]=a2;
  sqp[i] = (a0*a0 + a1*a1) + a2*a2;
  float e0 = xb[p*3+0], e1 = xb[p*3+1], e2 = xb[p*3+2];
  xe0[i*3+0]=e0; xe0[i*3+1]=e1; xe0[i*3+2]=e2;
  sqe[i] = (e0*e0 + e1*e1) + e2*e2;
}

// ---------------- streaming wave top-32 ----------------
__device__ __forceinline__ void topk_stream(float d, int m, int l, float& lv, int& li){
  float thr = rlane(lv, 31);
  int ti = __builtin_amdgcn_readlane(li, 31);
  unsigned long long mask = __ballot(d < thr || (d == thr && m < ti));
  while(mask){
    int s = __ffsll((unsigned long long)mask) - 1;
    float cd = __shfl(d, s);
    int cm = __shfl(m, s);
    unsigned long long less = __ballot(lv < cd || (lv == cd && li < cm));
    int pos = __popcll(less & 0xffffffffULL);
    float uv = __shfl_up(lv, 1);
    int ui = __shfl_up(li, 1);
    if(l < 32){
      if(l == pos){ lv = cd; li = cm; }
      else if(l > pos){ lv = uv; li = ui; }
    }
    mask &= mask - 1;
    if(mask){
      thr = rlane(lv, 31);
      ti = __builtin_amdgcn_readlane(li, 31);
      mask &= __ballot(d < thr || (d == thr && m < ti));
    }
  }
}

__global__ __launch_bounds__(256) void k_knn3(const float* __restrict__ pnt, const float* __restrict__ sq,
                                              int* __restrict__ idx){
  int l = threadIdx.x&63;
  int q = blockIdx.x*4 + (threadIdx.x>>6);
  int b = q>>12, qr = q&4095;
  const float* pb = pnt + (size_t)b*WN*3;
  const float* sb = sq + b*WN;
  float q0=pb[qr*3], q1=pb[qr*3+1], q2=pb[qr*3+2];
  float sqq = sb[qr];
  float lv = 3.4e38f; int li = 0x7fffffff;
  #pragma unroll 4
  for(int j=0;j<64;j++){
    int m = l + (j<<6);
    float d0=pb[m*3], d1=pb[m*3+1], d2=pb[m*3+2];
    float dot = q0*d0 + q1*d1 + q2*d2;
    float d = (sqq - 2.0f*dot) + sb[m];
    topk_stream(d, m, l, lv, li);
  }
  if(l < 32) idx[(size_t)q*KK + l] = li;
}

__global__ __launch_bounds__(256) void k_knn_sel(const float* __restrict__ D, int* __restrict__ idx){
  int l = threadIdx.x&63;
  int q = blockIdx.x*4 + (threadIdx.x>>6);
  int b = q>>12, qr = q&4095;
  const float* row = D + ((size_t)b<<24) + ((size_t)qr<<12);
  float lv = 3.4e38f; int li = 0x7fffffff;
  #pragma unroll 4
  for(int j=0;j<64;j++){
    int m = l + (j<<6);
    float d = row[m];
    topk_stream(d, m, l, lv, li);
  }
  if(l < 32) idx[(size_t)q*KK + l] = li;
}

// ---------------- gaussian kernel conv ----------------
__global__ __launch_bounds__(128) void k_gauss(const float* __restrict__ pts, const float* __restrict__ sqp,
                                               const int* __restrict__ idxP, const float* __restrict__ cen,
                                               float* __restrict__ kout){
  __shared__ float nbx[KK], nby[KK], nbz[KK], nsq[KK];
  int p = blockIdx.x; int b = p>>12; int t = threadIdx.x;
  if(t < KK){
    int id = idxP[(size_t)p*KK + t] + (b<<12);
    nbx[t]=pts[id*3]; nby[t]=pts[id*3+1]; nbz[t]=pts[id*3+2];
    nsq[t]=sqp[id];
  }
  __syncthreads();
  float c0=cen[t*3], c1=cen[t*3+1], c2=cen[t*3+2];
  float sqc=(c0*c0+c1*c1)+c2*c2;
  float acc=0.f;
  #pragma unroll
  for(int k=0;k<KK;k++){
    float dot = nbx[k]*c0 + nby[k]*c1 + nbz[k]*c2;
    float d = (nsq[k] - 2.0f*dot) + sqc;
    acc += expf(-0.5f*d);
  }
  kout[(size_t)((b<<7)+t)*4096 + (p&4095)] = acc;
}

// ---------------- finalize BN stats ----------------
__global__ void k_fin(const float* __restrict__ psum, const float* __restrict__ psq, int NW, int C, float Nn,
                      const float* __restrict__ g, const float* __restrict__ be,
                      float* __restrict__ sc, float* __restrict__ sh){
  int o = blockIdx.x, t = threadIdx.x;
  float s=0.f, q=0.f;
  for(int w=t; w<NW; w+=256){ s += psum[(size_t)w*C+o]; q += psq[(size_t)w*C+o]; }
  __shared__ float ls[256], lq[256];
  ls[t]=s; lq[t]=q; __syncthreads();
  for(int st=128; st; st>>=1){ if(t<st){ ls[t]+=ls[t+st]; lq[t]+=lq[t+st]; } __syncthreads(); }
  if(t==0){
    float mu = ls[0]/Nn;
    float var = lq[0]/Nn - mu*mu; if(var<0.f) var=0.f;
    float s1 = g[o]*rsqrtf(var + EPSB);
    sc[o]=s1; sh[o]=be[o]-mu*s1;
  }
}

// ---------------- edge-conv 1: stats-only h1 pass ----------------
__global__ __launch_bounds__(256) void k_ec1s(const float* __restrict__ xe0, const int* __restrict__ idx1,
                                              const float* __restrict__ w1,
                                              float* __restrict__ psum, float* __restrict__ psq){
  int wid = (blockIdx.x*256 + threadIdx.x)>>6;   // < 1024
  int l = threadIdx.x&63;
  float wr[6];
  #pragma unroll
  for(int c=0;c<6;c++) wr[c] = w1[l*6+c];
  float s=0.f, ss=0.f;
  for(int p=wid; p<NP; p+=1024){
    int bb = (p>>12)<<12;
    float x0=xe0[p*3], x1=xe0[p*3+1], x2=xe0[p*3+2];
    const int* ip = idx1 + (size_t)p*KK;
    for(int k=0;k<KK;k++){
      int id = ip[k];
      const float* nb = xe0 + (size_t)(bb+id)*3;
      float h = wr[0]*(nb[0]-x0) + wr[1]*(nb[1]-x1) + wr[2]*(nb[2]-x2)
              + wr[3]*x0 + wr[4]*x1 + wr[5]*x2;
      s += h; ss += h*h;
    }
  }
  psum[(size_t)wid*64+l]=s; psq[(size_t)wid*64+l]=ss;
}

// ---------------- edge-conv 1 fused ----------------
__global__ __launch_bounds__(256) void k_ec1g2(const float* __restrict__ xe0, const int* __restrict__ idx1,
                                               const float* __restrict__ w1, const float* __restrict__ w2T,
                                               const float* __restrict__ s1, const float* __restrict__ t1,
                                               float* __restrict__ h2m, float* __restrict__ psum,
                                               float* __restrict__ psq){
  __shared__ float As[64*64];
  __shared__ float Bs[64*132];
  __shared__ float feat[6][128];
  __shared__ float w1l[384];
  int t = threadIdx.x;
  int blk = blockIdx.x;
  int s0 = blk*128;
  int pbase = s0>>5;
  int bb = (s0>>17)<<12;
  #pragma unroll
  for(int i=0;i<16;i++) As[t + i*256] = w2T[t + i*256];
  for(int i=t; i<384; i+=256) w1l[i] = w1[i];
  if(t < 128){
    int s = s0 + t;
    int p = pbase + (t>>5);
    int id = bb + idx1[s];
    const float* nb = xe0 + (size_t)id*3;
    const float* xc = xe0 + (size_t)p*3;
    float x0 = xc[0], x1 = xc[1], x2 = xc[2];
    feat[0][t] = nb[0]-x0; feat[1][t] = nb[1]-x1; feat[2][t] = nb[2]-x2;
    feat[3][t] = x0; feat[4][t] = x1; feat[5][t] = x2;
  }
  __syncthreads();
  #pragma unroll
  for(int i=0;i<32;i++){
    int e = t + (i<<8);
    int k = e>>7, n = e&127;
    float h = w1l[k*6+0]*feat[0][n] + w1l[k*6+1]*feat[1][n] + w1l[k*6+2]*feat[2][n]
            + w1l[k*6+3]*feat[3][n] + w1l[k*6+4]*feat[4][n] + w1l[k*6+5]*feat[5][n];
    Bs[k*132 + n] = lrelu(fmaf(h, s1[k], t1[k]));
  }
  __syncthreads();
  int tx = t&15, ty = t>>4;
  float acc[4][8];
  #pragma unroll
  for(int i=0;i<4;i++){
    #pragma unroll
    for(int j=0;j<8;j++) acc[i][j]=0.f;
  }
  #pragma unroll 4
  for(int k=0;k<64;k++){
    float4 a  = *(const float4*)&As[k*64 + ty*4];
    float4 b0 = *(const float4*)&Bs[k*132 + tx*4];
    float4 b1 = *(const float4*)&Bs[k*132 + 64 + tx*4];
    float av[4] = {a.x,a.y,a.z,a.w};
    float bv[8] = {b0.x,b0.y,b0.z,b0.w,b1.x,b1.y,b1.z,b1.w};
    #pragma unroll
    for(int i=0;i<4;i++){
      #pragma unroll
      for(int j=0;j<8;j++) acc[i][j] = fmaf(av[i], bv[j], acc[i][j]);
    }
  }
  #pragma unroll
  for(int i=0;i<4;i++){
    int m = ty*4 + i;
    float sr = ((acc[i][0]+acc[i][1])+(acc[i][2]+acc[i][3])) + ((acc[i][4]+acc[i][5])+(acc[i][6]+acc[i][7]));
    float sq = ((acc[i][0]*acc[i][0]+acc[i][1]*acc[i][1])+(acc[i][2]*acc[i][2]+acc[i][3]*acc[i][3]))
             + ((acc[i][4]*acc[i][4]+acc[i][5]*acc[i][5])+(acc[i][6]*acc[i][6]+acc[i][7]*acc[i][7]));
    #pragma unroll
    for(int off=1; off<16; off<<=1){ sr += __shfl_xor(sr, off); sq += __shfl_xor(sq, off); }
    if(tx==0){ psum[(size_t)blk*64+m]=sr; psq[(size_t)blk*64+m]=sq; }
    float m0 = fmaxf(fmaxf(acc[i][0],acc[i][1]), fmaxf(acc[i][2],acc[i][3]));
    float m1 = fmaxf(fmaxf(acc[i][4],acc[i][5]), fmaxf(acc[i][6],acc[i][7]));
    #pragma unroll
    for(int off=1; off<8; off<<=1){ m0 = fmaxf(m0, __shfl_xor(m0, off)); m1 = fmaxf(m1, __shfl_xor(m1, off)); }
    if((tx&7)==0){
      int pl = pbase + (tx>>3);
      h2m[(size_t)pl*64 + m]     = m0;
      h2m[(size_t)(pl+2)*64 + m] = m1;
    }
  }
}

// ---------------- ec1 finalize ----------------
__global__ __launch_bounds__(256) void k_ec1fin(const float* __restrict__ h2m, const float* __restrict__ s2,
                                                const float* __restrict__ t2, float* __restrict__ xe1,
                                                float* __restrict__ xe1T, float* __restrict__ sqx){
  int gid = blockIdx.x*256 + threadIdx.x;  // < NP*64
  int p = gid>>6, l = gid&63;
  float v = lrelu(fmaf(h2m[(size_t)p*64+l], s2[l], t2[l]));
  xe1[(size_t)p*64+l] = v;
  int b=p>>12, pr=p&4095;
  xe1T[(size_t)(b*64+l)*4096 + pr] = v;
  float sq = v*v;
  #pragma unroll
  for(int off=32; off; off>>=1) sq += __shfl_xor(sq, off);
  if(l==0) sqx[p]=sq;
}

// ---------------- D = sq_n - 2 X X^T + sq_m ----------------
__global__ __launch_bounds__(256) void k_dgemm(const float* __restrict__ xT, const float* __restrict__ sqx,
                                               float* __restrict__ D){
  __shared__ float As[32*128], Bs2[32*128];
  int b = blockIdx.z;
  int m0 = blockIdx.y*128, n0 = blockIdx.x*128;
  int t = threadIdx.x;
  int tx = t&15, ty = t>>4;
  const float* xb = xT + (size_t)b*64*4096;
  float acc[8][8];
  #pragma unroll
  for(int i=0;i<8;i++){
    #pragma unroll
    for(int j=0;j<8;j++) acc[i][j]=0.f;
  }
  for(int kc=0;kc<2;kc++){
    __syncthreads();
    #pragma unroll
    for(int i=0;i<16;i++){
      int e = t + (i<<8);
      int k = e>>7, mm = e&127;
      As[k*128+mm]  = xb[(size_t)(kc*32+k)*4096 + m0+mm];
      Bs2[k*128+mm] = xb[(size_t)(kc*32+k)*4096 + n0+mm];
    }
    __syncthreads();
    #pragma unroll 4
    for(int k=0;k<32;k++){
      float av[8], bv[8];
      float4 A0 = *(float4*)&As[k*128 + ty*8];
      float4 A1 = *(float4*)&As[k*128 + ty*8+4];
      float4 B0 = *(float4*)&Bs2[k*128 + tx*8];
      float4 B1 = *(float4*)&Bs2[k*128 + tx*8+4];
      av[0]=A0.x; av[1]=A0.y; av[2]=A0.z; av[3]=A0.w; av[4]=A1.x; av[5]=A1.y; av[6]=A1.z; av[7]=A1.w;
      bv[0]=B0.x; bv[1]=B0.y; bv[2]=B0.z; bv[3]=B0.w; bv[4]=B1.x; bv[5]=B1.y; bv[6]=B1.z; bv[7]=B1.w;
      #pragma unroll
      for(int i=0;i<8;i++){
        #pragma unroll
        for(int j=0;j<8;j++) acc[i][j] = fmaf(av[i], bv[j], acc[i][j]);
      }
    }
  }
  const float* sb = sqx + (b<<12);
  float* Db = D + ((size_t)b<<24);
  #pragma unroll
  for(int i=0;i<8;i++){
    int r = m0 + ty*8 + i;
    float sqa = sb[r];
    float o[8];
    #pragma unroll
    for(int j=0;j<8;j++) o[j] = (sqa - 2.0f*acc[i][j]) + sb[n0+tx*8+j];
    *(float4*)&Db[(size_t)r*4096 + n0+tx*8]   = make_float4(o[0],o[1],o[2],o[3]);
    *(float4*)&Db[(size_t)r*4096 + n0+tx*8+4] = make_float4(o[4],o[5],o[6],o[7]);
  }
}

// ---------------- edge-conv 2 pass 1 (bf16 MFMA gather-GEMM) ----------------
// block = 128 samples (4 points) x 128 out-ch, K=128. h1 stored sample-major [s][128].
__global__ __launch_bounds__(256) void k_ec2m1(const float* __restrict__ xe1, const int* __restrict__ idx2,
                                               const short* __restrict__ wb, float* __restrict__ h1,
                                               float* __restrict__ psum, float* __restrict__ psq){
  __shared__ short sA[8192], sB[8192];
  __shared__ float cts[4][64];
  __shared__ int nid[128];
  __shared__ float srs[2][128], srq[2][128];
  int t = threadIdx.x;
  int blk = blockIdx.x;
  int s0 = blk*128;
  int pbase = s0>>5;
  int bb = (s0>>17)<<12;
  if(t<128) nid[t] = (idx2[s0+t] + bb)<<6;
  cts[t>>6][t&63] = xe1[(size_t)(pbase + (t>>6))*64 + (t&63)];
  int lane = t&63, w = t>>6;
  int wm4 = (w>>1)*4, wn4 = (w&1)*4;
  f4v acc[4][4];
  #pragma unroll
  for(int i=0;i<4;i++){
    #pragma unroll
    for(int j=0;j<4;j++) acc[i][j] = (f4v)(0.f);
  }
  for(int st=0; st<2; ++st){
    __syncthreads();
    #pragma unroll
    for(int i=0;i<4;i++){
      int slot = t + i*256;
      *(s8v*)&sA[slot*8] = *(const s8v*)&wb[st*8192 + slot*8];
      int chunk = slot>>6, li = slot&63;
      int n = (chunk&7)*16 + (li&15);
      int c = ((chunk>>3)<<5) + ((li>>4)<<3);
      float v[8];
      if(st==0){
        const float* src = xe1 + nid[n] + c;
        float4 a0 = *(const float4*)src;
        float4 a1 = *(const float4*)(src+4);
        const float* cc = &cts[n>>5][c];
        float4 c0 = *(const float4*)cc;
        float4 c1 = *(const float4*)(cc+4);
        v[0]=a0.x-c0.x; v[1]=a0.y-c0.y; v[2]=a0.z-c0.z; v[3]=a0.w-c0.w;
        v[4]=a1.x-c1.x; v[5]=a1.y-c1.y; v[6]=a1.z-c1.z; v[7]=a1.w-c1.w;
      } else {
        const float* cc = &cts[n>>5][c];
        float4 c0 = *(const float4*)cc;
        float4 c1 = *(const float4*)(cc+4);
        v[0]=c0.x; v[1]=c0.y; v[2]=c0.z; v[3]=c0.w;
        v[4]=c1.x; v[5]=c1.y; v[6]=c1.z; v[7]=c1.w;
      }
      s8v r;
      #pragma unroll
      for(int j=0;j<8;j++) r[j] = f2bf(v[j]);
      *(s8v*)&sB[slot*8] = r;
    }
    __syncthreads();
    #pragma unroll
    for(int kh=0;kh<2;kh++){
      s8v av[4], bv[4];
      #pragma unroll
      for(int f=0;f<4;f++) av[f] = *(const s8v*)&sA[(kh*8 + wm4 + f)*512 + lane*8];
      #pragma unroll
      for(int f=0;f<4;f++) bv[f] = *(const s8v*)&sB[(kh*8 + wn4 + f)*512 + lane*8];
      #pragma unroll
      for(int fm=0;fm<4;fm++){
        #pragma unroll
        for(int fn=0;fn<4;fn++)
          acc[fm][fn] = __builtin_amdgcn_mfma_f32_16x16x32_bf16(av[fm], bv[fn], acc[fm][fn], 0, 0, 0);
      }
    }
  }
  int l15 = lane&15, l4 = (lane>>4)<<2;
  #pragma unroll
  for(int fm=0;fm<4;fm++){
    int mb_ = wm4*16 + fm*16 + l4;
    #pragma unroll
    for(int fn=0;fn<4;fn++){
      int n = wn4*16 + fn*16 + l15;
      *(float4*)&h1[(size_t)(s0+n)*128 + mb_] =
        make_float4(acc[fm][fn][0], acc[fm][fn][1], acc[fm][fn][2], acc[fm][fn][3]);
    }
    #pragma unroll
    for(int r=0;r<4;r++){
      float sr = (acc[fm][0][r]+acc[fm][1][r]) + (acc[fm][2][r]+acc[fm][3][r]);
      float sq = (acc[fm][0][r]*acc[fm][0][r]+acc[fm][1][r]*acc[fm][1][r])
               + (acc[fm][2][r]*acc[fm][2][r]+acc[fm][3][r]*acc[fm][3][r]);
      #pragma unroll
      for(int off=1; off<16; off<<=1){ sr += __shfl_xor(sr, off); sq += __shfl_xor(sq, off); }
      if(l15==0){ srs[w&1][mb_+r] = sr; srq[w&1][mb_+r] = sq; }
    }
  }
  __syncthreads();
  if(t<128){
    psum[(size_t)blk*128+t] = srs[0][t]+srs[1][t];
    psq[(size_t)blk*128+t]  = srq[0][t]+srq[1][t];
  }
}

// ---------------- edge-conv 2 pass 2 (bf16 MFMA, fused BN1+lrelu, stats + per-point max) ----------------
__global__ __launch_bounds__(256) void k_ec2m2(const float* __restrict__ h1, const short* __restrict__ wb,
                                               const float* __restrict__ s1, const float* __restrict__ t1,
                                               float* __restrict__ h2max, float* __restrict__ psum,
                                               float* __restrict__ psq){
  __shared__ short sA[8192], sB[8192];
  __shared__ float bnS[128], bnT[128];
  __shared__ float srs[2][128], srq[2][128];
  int t = threadIdx.x;
  int blk = blockIdx.x;
  int s0 = blk*128;
  int pbase = s0>>5;
  if(t<128){ bnS[t]=s1[t]; bnT[t]=t1[t]; }
  int lane = t&63, w = t>>6;
  int wm4 = (w>>1)*4, wn4 = (w&1)*4;
  f4v acc[4][4];
  #pragma unroll
  for(int i=0;i<4;i++){
    #pragma unroll
    for(int j=0;j<4;j++) acc[i][j] = (f4v)(0.f);
  }
  for(int st=0; st<2; ++st){
    __syncthreads();
    #pragma unroll
    for(int i=0;i<4;i++){
      int slot = t + i*256;
      *(s8v*)&sA[slot*8] = *(const s8v*)&wb[st*8192 + slot*8];
      int chunk = slot>>6, li = slot&63;
      int n = (chunk&7)*16 + (li&15);
      int c = st*64 + ((chunk>>3)<<5) + ((li>>4)<<3);
      const float* src = h1 + (size_t)(s0+n)*128 + c;
      float4 a0 = *(const float4*)src;
      float4 a1 = *(const float4*)(src+4);
      float v[8] = {a0.x,a0.y,a0.z,a0.w,a1.x,a1.y,a1.z,a1.w};
      s8v r;
      #pragma unroll
      for(int j=0;j<8;j++) r[j] = f2bf(lrelu(fmaf(v[j], bnS[c+j], bnT[c+j])));
      *(s8v*)&sB[slot*8] = r;
    }
    __syncthreads();
    #pragma unroll
    for(int kh=0;kh<2;kh++){
      s8v av[4], bv[4];
      #pragma unroll
      for(int f=0;f<4;f++) av[f] = *(const s8v*)&sA[(kh*8 + wm4 + f)*512 + lane*8];
      #pragma unroll
      for(int f=0;f<4;f++) bv[f] = *(const s8v*)&sB[(kh*8 + wn4 + f)*512 + lane*8];
      #pragma unroll
      for(int fm=0;fm<4;fm++){
        #pragma unroll
        for(int fn=0;fn<4;fn++)
          acc[fm][fn] = __builtin_amdgcn_mfma_f32_16x16x32_bf16(av[fm], bv[fn], acc[fm][fn], 0, 0, 0);
      }
    }
  }
  int l15 = lane&15, l4 = (lane>>4)<<2;
  int pp0 = wn4>>1;   // wn4=0 -> points 0,1 ; wn4=4 -> points 2,3
  #pragma unroll
  for(int fm=0;fm<4;fm++){
    int mb_ = wm4*16 + fm*16 + l4;
    #pragma unroll
    for(int r=0;r<4;r++){
      float sr = (acc[fm][0][r]+acc[fm][1][r]) + (acc[fm][2][r]+acc[fm][3][r]);
      float sq = (acc[fm][0][r]*acc[fm][0][r]+acc[fm][1][r]*acc[fm][1][r])
               + (acc[fm][2][r]*acc[fm][2][r]+acc[fm][3][r]*acc[fm][3][r]);
      float m0 = fmaxf(acc[fm][0][r], acc[fm][1][r]);
      float m1 = fmaxf(acc[fm][2][r], acc[fm][3][r]);
      #pragma unroll
      for(int off=1; off<16; off<<=1){ sr += __shfl_xor(sr, off); sq += __shfl_xor(sq, off); }
      #pragma unroll
      for(int off=1; off<16; off<<=1){ m0 = fmaxf(m0, __shfl_xor(m0, off)); m1 = fmaxf(m1, __shfl_xor(m1, off)); }
      if(l15==0){
        srs[w&1][mb_+r] = sr; srq[w&1][mb_+r] = sq;
        h2max[(size_t)(pbase+pp0)*128   + mb_+r] = m0;
        h2max[(size_t)(pbase+pp0+1)*128 + mb_+r] = m1;
      }
    }
  }
  __syncthreads();
  if(t<128){
    psum[(size_t)blk*128+t] = srs[0][t]+srs[1][t];
    psq[(size_t)blk*128+t]  = srq[0][t]+srq[1][t];
  }
}

// ---------------- xe2 = lrelu(BN(h2max)) in-place ----------------
__global__ void k_xe2fin(float* __restrict__ xe2, const float* __restrict__ s2, const float* __restrict__ t2){
  int i = blockIdx.x*256 + threadIdx.x;   // < NP*128
  if(i >= NP*128) return;
  int o = i&127;
  xe2[i] = lrelu(fmaf(xe2[i], s2[o], t2[o]));
}

// ---------------- hcat ----------------
__global__ void k_hcat(const float* __restrict__ xe2, const float* __restrict__ kr, float* __restrict__ hcat){
  size_t i = (size_t)blockIdx.x*256 + threadIdx.x;
  int b = (int)(i>>20);
  int r = (int)(i & 1048575);
  int ch = r>>12;
  float v;
  if(ch < 128) v = xe2[(size_t)b*524288 + r];
  else         v = kr [(size_t)(b*128 + (ch-128))*4096 + (r&4095)];
  hcat[i] = v;
}

// ---------------- generic small transpose ----------------
__global__ void k_transpose(const float* __restrict__ w, float* __restrict__ wT, int O, int C){
  int i = blockIdx.x*256 + threadIdx.x;
  if(i >= O*C) return;
  int o = i / C, c = i % C;
  wT[(size_t)c*O + o] = w[i];
}

// ---------------- weight fp32 -> bf16 fragment-linear ----------------
__global__ void k_wprep(const float* __restrict__ w, short* __restrict__ wb, int M, int K){
  int tid = blockIdx.x*256 + threadIdx.x;
  int m = tid % M, kb8 = tid / M;
  int k0 = kb8*8;
  float4 v0 = *(const float4*)&w[(size_t)m*K + k0];
  float4 v1 = *(const float4*)&w[(size_t)m*K + k0 + 4];
  s8v r;
  r[0]=f2bf(v0.x); r[1]=f2bf(v0.y); r[2]=f2bf(v0.z); r[3]=f2bf(v0.w);
  r[4]=f2bf(v1.x); r[5]=f2bf(v1.y); r[6]=f2bf(v1.z); r[7]=f2bf(v1.w);
  int region = (m>>7)*(K>>6) + (k0>>6);
  int chunk = ((kb8>>2)&1)*8 + ((m>>4)&7);
  int lane = (kb8&3)*16 + (m&15);
  *(s8v*)&wb[(size_t)region*8192 + chunk*512 + lane*8] = r;
}

// ---------------- activations -> bf16 fragment-linear ----------------
__global__ void k_bprep(const float* __restrict__ in, const float* __restrict__ sc, const float* __restrict__ sh,
                        short* __restrict__ ob, int K){
  int tid = blockIdx.x*256 + threadIdx.x;
  int n = tid & 8191, kb8 = tid >> 13;
  int k0 = kb8*8;
  int b = n>>12, s = n&4095;
  const float* ib = in + ((size_t)b*K + k0)*4096 + s;
  float v[8];
  #pragma unroll
  for(int j=0;j<8;j++) v[j] = ib[(size_t)j*4096];
  if(sc){
    #pragma unroll
    for(int j=0;j<8;j++) v[j] = lrelu(fmaf(v[j], sc[k0+j], sh[k0+j]));
  }
  s8v r;
  #pragma unroll
  for(int j=0;j<8;j++) r[j] = f2bf(v[j]);
  int region = (n>>7)*(K>>6) + (k0>>6);
  int chunk = ((kb8>>2)&1)*8 + ((n>>4)&7);
  int lane = (kb8&3)*16 + (n&15);
  *(s8v*)&ob[(size_t)region*8192 + chunk*512 + lane*8] = r;
}

// ---------------- bf16 MFMA GEMM ----------------
__global__ __launch_bounds__(256) void k_gmm(const short* __restrict__ A, const short* __restrict__ B,
                                             float* __restrict__ out, int M, int K){
  __shared__ short sA[8192], sB[8192];
  int t = threadIdx.x;
  int lane = t&63;
  int w = t>>6;
  int wm4 = (w>>1)*4, wn4 = (w&1)*4;
  int mb = blockIdx.y, nb = blockIdx.x;
  int ksteps = K>>6;
  const short* AG = A + (size_t)mb*ksteps*8192;
  const short* BG = B + (size_t)nb*ksteps*8192;
  f4v acc[4][4];
  #pragma unroll
  for(int i=0;i<4;i++){
    #pragma unroll
    for(int j=0;j<4;j++) acc[i][j] = (f4v)(0.f);
  }
  for(int st=0; st<ksteps; ++st){
    __syncthreads();
    #pragma unroll
    for(int i=0;i<4;i++){
      int slot = t + i*256;
      *(s8v*)&sA[slot*8] = *(const s8v*)&AG[(size_t)st*8192 + slot*8];
      *(s8v*)&sB[slot*8] = *(const s8v*)&BG[(size_t)st*8192 + slot*8];
    }
    __syncthreads();
    #pragma unroll
    for(int kh=0;kh<2;kh++){
      s8v av[4], bv[4];
      #pragma unroll
      for(int f=0;f<4;f++) av[f] = *(const s8v*)&sA[(kh*8 + wm4 + f)*512 + lane*8];
      #pragma unroll
      for(int f=0;f<4;f++) bv[f] = *(const s8v*)&sB[(kh*8 + wn4 + f)*512 + lane*8];
      #pragma unroll
      for(int fm=0;fm<4;fm++){
        #pragma unroll
        for(int fn=0;fn<4;fn++)
          acc[fm][fn] = __builtin_amdgcn_mfma_f32_16x16x32_bf16(av[fm], bv[fn], acc[fm][fn], 0, 0, 0);
      }
    }
  }
  int l15 = lane&15, l4 = (lane>>4)*4;
  #pragma unroll
  for(int fm=0;fm<4;fm++){
    int mrow = mb*128 + wm4*16 + fm*16 + l4;
    #pragma unroll
    for(int fn=0;fn<4;fn++){
      int n = nb*128 + wn4*16 + fn*16 + l15;
      int b = n>>12, s = n&4095;
      float* ob = out + ((size_t)b*M + mrow)*4096 + s;
      #pragma unroll
      for(int r=0;r<4;r++) ob[(size_t)r*4096] = acc[fm][fn][r];
    }
  }
}

// ---------------- per-channel stats for cbr layers ----------------
__global__ void k_cstats(const float* __restrict__ buf, int C, const float* __restrict__ g,
                         const float* __restrict__ be, float* __restrict__ sc, float* __restrict__ sh){
  int o = blockIdx.x, t = threadIdx.x;
  float s=0.f, q=0.f;
  for(int i=t;i<8192;i+=256){
    int b=i>>12, ss_=i&4095;
    float v = buf[(size_t)(b*C+o)*4096 + ss_];
    s+=v; q+=v*v;
  }
  __shared__ float ls[256], lq[256];
  ls[t]=s; lq[t]=q; __syncthreads();
  for(int st=128; st; st>>=1){ if(t<st){ ls[t]+=ls[t+st]; lq[t]+=lq[t+st]; } __syncthreads(); }
  if(t==0){
    float mu = ls[0]/8192.f;
    float var = lq[0]/8192.f - mu*mu; if(var<0.f) var=0.f;
    float s1 = g[o]*rsqrtf(var + EPSB);
    sc[o]=s1; sh[o]=be[o]-mu*s1;
  }
}

// ---------------- final layer ----------------
__global__ __launch_bounds__(256) void k_final4(const float* __restrict__ c3, const float* __restrict__ w4T,
                                                const float* __restrict__ sc, const float* __restrict__ sh,
                                                float* __restrict__ pmax){
  int b = blockIdx.y, st = blockIdx.x;
  int t = threadIdx.x; int s = st*256 + t;
  float acc[9];
  #pragma unroll
  for(int j=0;j<9;j++) acc[j]=0.f;
  const float* ib = c3 + (size_t)b*256*4096;
  for(int c=0;c<256;c++){
    float x = lrelu(fmaf(ib[(size_t)c*4096+s], sc[c], sh[c]));
    #pragma unroll
    for(int j=0;j<9;j++) acc[j]=fmaf(x, w4T[c*9+j], acc[j]);
  }
  __shared__ float red[256];
  for(int j=0;j<9;j++){
    red[t]=acc[j]; __syncthreads();
    for(int stp=128; stp; stp>>=1){ if(t<stp) red[t]=fmaxf(red[t],red[t+stp]); __syncthreads(); }
    if(t==0) pmax[(b*16+st)*9 + j]=red[0];
    __syncthreads();
  }
}

__global__ void k_out(const float* __restrict__ pmax, float* __restrict__ out){
  int i = threadIdx.x;
  if(i<18){
    int b=i/9, o=i%9;
    float m=-3.4e38f;
    for(int k=0;k<16;k++) m=fmaxf(m, pmax[(b*16+k)*9+o]);
    out[i] = m + ((o==0||o==4||o==8)?1.f:0.f);
  }
}

// ---------------- launch ----------------
extern "C" void kernel_launch(void* const* d_in, const int* in_sizes, int n_in,
                              void* d_out, int out_size, void* d_ws, size_t ws_size,
                              hipStream_t stream){
  const float* x    = (const float*)d_in[0];
  const float* kc   = (const float*)d_in[1];
  const float* e1w1 = (const float*)d_in[2];
  const float* e1g1 = (const float*)d_in[3];
  const float* e1b1 = (const float*)d_in[4];
  const float* e1w2 = (const float*)d_in[5];
  const float* e1g2 = (const float*)d_in[6];
  const float* e1b2 = (const float*)d_in[7];
  const float* e2w1 = (const float*)d_in[8];
  const float* e2g1 = (const float*)d_in[9];
  const float* e2b1 = (const float*)d_in[10];
  const float* e2w2 = (const float*)d_in[11];
  const float* e2g2 = (const float*)d_in[12];
  const float* e2b2 = (const float*)d_in[13];
  const float* w1   = (const float*)d_in[14];
  const float* g1   = (const float*)d_in[15];
  const float* b1   = (const float*)d_in[16];
  const float* w2   = (const float*)d_in[17];
  const float* g2   = (const float*)d_in[18];
  const float* b2   = (const float*)d_in[19];
  const float* w3   = (const float*)d_in[20];
  const float* g3   = (const float*)d_in[21];
  const float* b3   = (const float*)d_in[22];
  const float* w4   = (const float*)d_in[23];

  if(ws_size < 156061696ull) return;
  char* ws = (char*)d_ws;
  float* pts   = (float*)(ws + 0);
  float* xe0   = (float*)(ws + 98304);
  float* sqp   = (float*)(ws + 196608);
  float* sqe   = (float*)(ws + 229376);
  float* sqx1  = (float*)(ws + 262144);
  float* xe1   = (float*)(ws + 294912);
  float* xe1T  = (float*)(ws + 2392064);
  float* xe2   = (float*)(ws + 4489216);
  float* kr    = (float*)(ws + 8683520);
  int*   idxP  = (int*)  (ws + 12877824);
  int*   idx1  = (int*)  (ws + 13926400);
  int*   idx2  = (int*)  (ws + 14974976);
  float* psum  = (float*)(ws + 16023552);
  float* psq   = (float*)(ws + 17072128);
  float* par   = (float*)(ws + 18120704);
  float* pmax  = (float*)(ws + 18153472);
  float* e1w2T = (float*)(ws + 18157568);
  float* wT4   = (float*)(ws + 21827584);
  float* hbuf  = (float*)(ws + 21843968);
  // bf16 fragment-packed ec2 weights reuse the dead pts/xe0 region
  short* wbe1  = (short*)(ws + 0);       // 32 KB
  short* wbe2  = (short*)(ws + 65536);   // 32 KB
  short* actB  = (short*)(ws + 88952832);
  short* wb1   = (short*)(ws + 105730048);
  short* wb2   = (short*)(ws + 106254336);
  short* wb3   = (short*)(ws + 107302912);

  float* e1s1 = par+0;    float* e1t1 = par+64;
  float* e1s2 = par+128;  float* e1t2 = par+192;
  float* e2s1 = par+256;  float* e2t1 = par+384;
  float* e2s2 = par+512;  float* e2t2 = par+640;
  float* c1s  = par+768;  float* c1t  = par+1792;
  float* c2s  = par+2816; float* c2t  = par+3328;
  float* c3s  = par+3840; float* c3t  = par+4096;

  float* hcat  = hbuf;
  float* c1out = hbuf + 2097152;
  float* c2out = hbuf + 10485760;
  float* c3out = hbuf + 14680064;

  hipLaunchKernelGGL(k_prep, dim3(32), dim3(256), 0, stream, x, pts, xe0, sqp, sqe);
  hipLaunchKernelGGL(k_knn3, dim3(2048), dim3(256), 0, stream, pts, sqp, idxP);
  hipLaunchKernelGGL(k_knn3, dim3(2048), dim3(256), 0, stream, xe0, sqe, idx1);
  hipLaunchKernelGGL(k_gauss, dim3(8192), dim3(128), 0, stream, pts, sqp, idxP, kc, kr);

  // edge-conv 1 (recompute-h1 GEMM formulation)
  hipLaunchKernelGGL(k_transpose, dim3(16), dim3(256), 0, stream, e1w2, e1w2T, 64, 64);
  hipLaunchKernelGGL(k_ec1s, dim3(256), dim3(256), 0, stream, xe0, idx1, e1w1, psum, psq);
  hipLaunchKernelGGL(k_fin, dim3(64), dim3(256), 0, stream, psum, psq, 1024, 64, 262144.f, e1g1, e1b1, e1s1, e1t1);
  hipLaunchKernelGGL(k_ec1g2, dim3(2048), dim3(256), 0, stream, xe0, idx1, e1w1, e1w2T, e1s1, e1t1, hbuf, psum, psq);
  hipLaunchKernelGGL(k_fin, dim3(64), dim3(256), 0, stream, psum, psq, 2048, 64, 262144.f, e1g2, e1b2, e1s2, e1t2);
  hipLaunchKernelGGL(k_ec1fin, dim3(2048), dim3(256), 0, stream, hbuf, e1s2, e1t2, xe1, xe1T, sqx1);

  // knn on 64-d features
  hipLaunchKernelGGL(k_dgemm, dim3(32,32,2), dim3(256), 0, stream, xe1T, sqx1, hbuf);
  hipLaunchKernelGGL(k_knn_sel, dim3(2048), dim3(256), 0, stream, hbuf, idx2);

  // edge-conv 2 (bf16 MFMA formulation, fused stats+max)
  hipLaunchKernelGGL(k_wprep, dim3(8), dim3(256), 0, stream, e2w1, wbe1, 128, 128);
  hipLaunchKernelGGL(k_wprep, dim3(8), dim3(256), 0, stream, e2w2, wbe2, 128, 128);
  hipLaunchKernelGGL(k_ec2m1, dim3(2048), dim3(256), 0, stream, xe1, idx2, wbe1, hbuf, psum, psq);
  hipLaunchKernelGGL(k_fin, dim3(128), dim3(256), 0, stream, psum, psq, 2048, 128, 262144.f, e2g1, e2b1, e2s1, e2t1);
  hipLaunchKernelGGL(k_ec2m2, dim3(2048), dim3(256), 0, stream, hbuf, wbe2, e2s1, e2t1, xe2, psum, psq);
  hipLaunchKernelGGL(k_fin, dim3(128), dim3(256), 0, stream, psum, psq, 2048, 128, 262144.f, e2g2, e2b2, e2s2, e2t2);
  hipLaunchKernelGGL(k_xe2fin, dim3(4096), dim3(256), 0, stream, xe2, e2s2, e2t2);

  // concat + bf16 MFMA cbr chain
  hipLaunchKernelGGL(k_hcat, dim3(8192), dim3(256), 0, stream, xe2, kr, hcat);
  hipLaunchKernelGGL(k_wprep, dim3(128), dim3(256), 0, stream, w1, wb1, 1024, 256);
  hipLaunchKernelGGL(k_wprep, dim3(256), dim3(256), 0, stream, w2, wb2, 512, 1024);
  hipLaunchKernelGGL(k_wprep, dim3(64),  dim3(256), 0, stream, w3, wb3, 256, 512);
  hipLaunchKernelGGL(k_transpose, dim3((9*256+255)/256), dim3(256), 0, stream, w4, wT4, 9, 256);

  hipLaunchKernelGGL(k_bprep, dim3(1024), dim3(256), 0, stream, hcat, (const float*)nullptr, (const float*)nullptr, actB, 256);
  hipLaunchKernelGGL(k_gmm, dim3(64,8), dim3(256), 0, stream, wb1, actB, c1out, 1024, 256);
  hipLaunchKernelGGL(k_cstats, dim3(1024), dim3(256), 0, stream, c1out, 1024, g1, b1, c1s, c1t);

  hipLaunchKernelGGL(k_bprep, dim3(4096), dim3(256), 0, stream, c1out, c1s, c1t, actB, 1024);
  hipLaunchKernelGGL(k_gmm, dim3(64,4), dim3(256), 0, stream, wb2, actB, c2out, 512, 1024);
  hipLaunchKernelGGL(k_cstats, dim3(512), dim3(256), 0, stream, c2out, 512, g2, b2, c2s, c2t);

  hipLaunchKernelGGL(k_bprep, dim3(2048), dim3(256), 0, stream, c2out, c2s, c2t, actB, 512);
  hipLaunchKernelGGL(k_gmm, dim3(64,2), dim3(256), 0, stream, wb3, actB, c3out, 256, 512);
  hipLaunchKernelGGL(k_cstats, dim3(256), dim3(256), 0, stream, c3out, 256, g3, b3, c3s, c3t);

  hipLaunchKernelGGL(k_final4, dim3(16,2), dim3(256), 0, stream, c3out, wT4, c3s, c3t, pmax);
  hipLaunchKernelGGL(k_out, dim3(1), dim3(32), 0, stream, pmax, (float*)d_out);
}

// Round 10
// 750.555 us; speedup vs baseline: 3.3073x; 1.0442x over previous
//
#include <hip/hip_runtime.h>
#include <math.h>

#define WN 4096
#define NP 8192
#define KK 32
#define EPSB 1e-5f

typedef __attribute__((ext_vector_type(8))) short s8v;
typedef __attribute__((ext_vector_type(4))) float f4v;

__device__ __forceinline__ float lrelu(float x){ return fmaxf(x, 0.01f*x); }
__device__ __forceinline__ float rlane(float v, int c){
  return __int_as_float(__builtin_amdgcn_readlane(__float_as_int(v), c));
}
__device__ __forceinline__ short f2bf(float f){
  unsigned u = __float_as_uint(f);
  u = (u + 0x7fffu + ((u>>16)&1u)) >> 16;
  return (short)u;
}

// ---------------- prep ----------------
__global__ void k_prep(const float* __restrict__ x, float* __restrict__ pts, float* __restrict__ xe0,
                       float* __restrict__ sqp, float* __restrict__ sqe){
  int i = blockIdx.x*256 + threadIdx.x;
  if(i >= NP) return;
  int b = i>>12, p = i&4095;
  const float* xb = x + b*12288;
  float a0 = xb[p], a1 = xb[4096+p], a2 = xb[8192+p];
  pts[i*3+0]=a0; pts[i*3+1]=a1; pts[i*3+2]=a2;
  sqp[i] = (a0*a0 + a1*a1) + a2*a2;
  float e0 = xb[p*3+0], e1 = xb[p*3+1], e2 = xb[p*3+2];
  xe0[i*3+0]=e0; xe0[i*3+1]=e1; xe0[i*3+2]=e2;
  sqe[i] = (e0*e0 + e1*e1) + e2*e2;
}

// ---------------- bitonic sort of 64 (d, idx) pairs across lanes, ascending lexicographic ----------------
__device__ __forceinline__ void bitonic64(float& d, int& m, int l){
  #pragma unroll
  for(int k=2;k<=64;k<<=1){
    #pragma unroll
    for(int j=k>>1;j>0;j>>=1){
      float pd = __shfl_xor(d, j);
      int pm = __shfl_xor(m, j);
      bool pLess = (pd < d) || (pd == d && pm < m);
      bool dirUp = ((l & k) == 0);
      bool lower = ((l & j) == 0);
      bool take = dirUp ? (lower ? pLess : !pLess) : (lower ? !pLess : pLess);
      if(take){ d = pd; m = pm; }
    }
  }
}

// ---------------- streaming wave top-32 ----------------
__device__ __forceinline__ void topk_stream(float d, int m, int l, float& lv, int& li){
  float thr = rlane(lv, 31);
  int ti = __builtin_amdgcn_readlane(li, 31);
  unsigned long long mask = __ballot(d < thr || (d == thr && m < ti));
  while(mask){
    int s = __ffsll((unsigned long long)mask) - 1;
    float cd = __shfl(d, s);
    int cm = __shfl(m, s);
    unsigned long long less = __ballot(lv < cd || (lv == cd && li < cm));
    int pos = __popcll(less & 0xffffffffULL);
    float uv = __shfl_up(lv, 1);
    int ui = __shfl_up(li, 1);
    if(l < 32){
      if(l == pos){ lv = cd; li = cm; }
      else if(l > pos){ lv = uv; li = ui; }
    }
    mask &= mask - 1;
    if(mask){
      thr = rlane(lv, 31);
      ti = __builtin_amdgcn_readlane(li, 31);
      mask &= __ballot(d < thr || (d == thr && m < ti));
    }
  }
}

__global__ __launch_bounds__(256) void k_knn3(const float* __restrict__ pnt, const float* __restrict__ sq,
                                              int* __restrict__ idx){
  int l = threadIdx.x&63;
  int q = blockIdx.x*4 + (threadIdx.x>>6);
  int b = q>>12, qr = q&4095;
  const float* pb = pnt + (size_t)b*WN*3;
  const float* sb = sq + b*WN;
  float q0=pb[qr*3], q1=pb[qr*3+1], q2=pb[qr*3+2];
  float sqq = sb[qr];
  // batch 0 via full bitonic sort -> initial sorted top-32 + tight threshold
  float dd; int mm = l;
  {
    float d0=pb[l*3], d1=pb[l*3+1], d2=pb[l*3+2];
    float dot = q0*d0 + q1*d1 + q2*d2;
    dd = (sqq - 2.0f*dot) + sb[l];
  }
  bitonic64(dd, mm, l);
  float lv = (l<32) ? dd : 3.4e38f;
  int li = (l<32) ? mm : 0x7fffffff;
  #pragma unroll 4
  for(int j=1;j<64;j++){
    int m = l + (j<<6);
    float d0=pb[m*3], d1=pb[m*3+1], d2=pb[m*3+2];
    float dot = q0*d0 + q1*d1 + q2*d2;
    float d = (sqq - 2.0f*dot) + sb[m];
    topk_stream(d, m, l, lv, li);
  }
  if(l < 32) idx[(size_t)q*KK + l] = li;
}

__global__ __launch_bounds__(256) void k_knn_sel(const float* __restrict__ D, int* __restrict__ idx){
  int l = threadIdx.x&63;
  int q = blockIdx.x*4 + (threadIdx.x>>6);
  int b = q>>12, qr = q&4095;
  const float* row = D + ((size_t)b<<24) + ((size_t)qr<<12);
  float dd = row[l]; int mm = l;
  bitonic64(dd, mm, l);
  float lv = (l<32) ? dd : 3.4e38f;
  int li = (l<32) ? mm : 0x7fffffff;
  #pragma unroll 4
  for(int j=1;j<64;j++){
    int m = l + (j<<6);
    float d = row[m];
    topk_stream(d, m, l, lv, li);
  }
  if(l < 32) idx[(size_t)q*KK + l] = li;
}

// ---------------- gaussian kernel conv ----------------
__global__ __launch_bounds__(128) void k_gauss(const float* __restrict__ pts, const float* __restrict__ sqp,
                                               const int* __restrict__ idxP, const float* __restrict__ cen,
                                               float* __restrict__ kout){
  __shared__ float nbx[KK], nby[KK], nbz[KK], nsq[KK];
  int p = blockIdx.x; int b = p>>12; int t = threadIdx.x;
  if(t < KK){
    int id = idxP[(size_t)p*KK + t] + (b<<12);
    nbx[t]=pts[id*3]; nby[t]=pts[id*3+1]; nbz[t]=pts[id*3+2];
    nsq[t]=sqp[id];
  }
  __syncthreads();
  float c0=cen[t*3], c1=cen[t*3+1], c2=cen[t*3+2];
  float sqc=(c0*c0+c1*c1)+c2*c2;
  float acc=0.f;
  #pragma unroll
  for(int k=0;k<KK;k++){
    float dot = nbx[k]*c0 + nby[k]*c1 + nbz[k]*c2;
    float d = (nsq[k] - 2.0f*dot) + sqc;
    acc += __expf(-0.5f*d);
  }
  kout[(size_t)((b<<7)+t)*4096 + (p&4095)] = acc;
}

// ---------------- finalize BN stats ----------------
__global__ void k_fin(const float* __restrict__ psum, const float* __restrict__ psq, int NW, int C, float Nn,
                      const float* __restrict__ g, const float* __restrict__ be,
                      float* __restrict__ sc, float* __restrict__ sh){
  int o = blockIdx.x, t = threadIdx.x;
  float s=0.f, q=0.f;
  for(int w=t; w<NW; w+=256){ s += psum[(size_t)w*C+o]; q += psq[(size_t)w*C+o]; }
  __shared__ float ls[256], lq[256];
  ls[t]=s; lq[t]=q; __syncthreads();
  for(int st=128; st; st>>=1){ if(t<st){ ls[t]+=ls[t+st]; lq[t]+=lq[t+st]; } __syncthreads(); }
  if(t==0){
    float mu = ls[0]/Nn;
    float var = lq[0]/Nn - mu*mu; if(var<0.f) var=0.f;
    float s1 = g[o]*rsqrtf(var + EPSB);
    sc[o]=s1; sh[o]=be[o]-mu*s1;
  }
}

// ---------------- edge-conv 1 BN1 stats via feature moments: h = W1*f is linear ----------------
// pmom[v][2048]: per-wave partial sums of {f_i*f_j (i<=j): 21, f_i: 6}
__global__ __launch_bounds__(256) void k_ec1mom(const float* __restrict__ xe0, const int* __restrict__ idx1,
                                                float* __restrict__ pmom){
  int tid = blockIdx.x*256 + threadIdx.x;      // < 131072
  int l = threadIdx.x & 63;
  int wid = tid >> 6;                           // < 2048
  float a[27];
  #pragma unroll
  for(int v=0;v<27;v++) a[v]=0.f;
  #pragma unroll
  for(int u=0;u<2;u++){
    int s = tid*2 + u;                          // < 262144
    int p = s>>5;
    int bb = (p>>12)<<12;
    int id = bb + idx1[s];
    const float* nb = xe0 + (size_t)id*3;
    const float* xc = xe0 + (size_t)p*3;
    float f[6];
    f[0]=nb[0]-xc[0]; f[1]=nb[1]-xc[1]; f[2]=nb[2]-xc[2];
    f[3]=xc[0]; f[4]=xc[1]; f[5]=xc[2];
    int v=0;
    #pragma unroll
    for(int i=0;i<6;i++){
      #pragma unroll
      for(int j=i;j<6;j++){ a[v] = fmaf(f[i], f[j], a[v]); v++; }
    }
    #pragma unroll
    for(int i=0;i<6;i++) a[21+i] += f[i];
  }
  #pragma unroll
  for(int v=0;v<27;v++){
    float t = a[v];
    #pragma unroll
    for(int off=32; off; off>>=1) t += __shfl_xor(t, off);
    if(l==0) pmom[v*2048 + wid] = t;
  }
}

__global__ void k_msum(const float* __restrict__ pmom, float* __restrict__ mom){
  int v = blockIdx.x; int t = threadIdx.x;
  float s=0.f;
  for(int i=t;i<2048;i+=256) s += pmom[v*2048+i];
  __shared__ float ls[256];
  ls[t]=s; __syncthreads();
  for(int st=128; st; st>>=1){ if(t<st) ls[t]+=ls[t+st]; __syncthreads(); }
  if(t==0) mom[v]=ls[0];
}

// s1/t1 from moments: E[h]=w.Sf/N ; E[h^2]=w^T M w / N
__global__ void k_ec1bn(const float* __restrict__ mom, const float* __restrict__ w1,
                        const float* __restrict__ g, const float* __restrict__ be,
                        float* __restrict__ sc, float* __restrict__ sh){
  __shared__ float M[27];
  int t = threadIdx.x;
  if(t<27) M[t]=mom[t];
  __syncthreads();
  if(t<64){
    float w[6];
    #pragma unroll
    for(int c=0;c<6;c++) w[c]=w1[t*6+c];
    float qf=0.f, m1=0.f;
    int v=0;
    #pragma unroll
    for(int i=0;i<6;i++){
      #pragma unroll
      for(int j=i;j<6;j++){ qf += (i==j?1.f:2.f)*w[i]*w[j]*M[v]; v++; }
    }
    #pragma unroll
    for(int i=0;i<6;i++) m1 += w[i]*M[21+i];
    float N = 262144.f;
    float mu = m1/N;
    float var = qf/N - mu*mu; if(var<0.f) var=0.f;
    float s1 = g[t]*rsqrtf(var + EPSB);
    sc[t]=s1; sh[t]=be[t]-mu*s1;
  }
}

// ---------------- edge-conv 1 fused: rebuild y1 tile in LDS, GEMM h2=W2*y1, stats + per-point max ----------------
__global__ __launch_bounds__(256) void k_ec1g2(const float* __restrict__ xe0, const int* __restrict__ idx1,
                                               const float* __restrict__ w1, const float* __restrict__ w2T,
                                               const float* __restrict__ s1, const float* __restrict__ t1,
                                               float* __restrict__ h2m, float* __restrict__ psum,
                                               float* __restrict__ psq){
  __shared__ float As[64*64];
  __shared__ float Bs[64*132];
  __shared__ float feat[6][128];
  __shared__ float w1l[384];
  int t = threadIdx.x;
  int blk = blockIdx.x;
  int s0 = blk*128;
  int pbase = s0>>5;
  int bb = (s0>>17)<<12;
  #pragma unroll
  for(int i=0;i<16;i++) As[t + i*256] = w2T[t + i*256];
  for(int i=t; i<384; i+=256) w1l[i] = w1[i];
  if(t < 128){
    int s = s0 + t;
    int p = pbase + (t>>5);
    int id = bb + idx1[s];
    const float* nb = xe0 + (size_t)id*3;
    const float* xc = xe0 + (size_t)p*3;
    float x0 = xc[0], x1 = xc[1], x2 = xc[2];
    feat[0][t] = nb[0]-x0; feat[1][t] = nb[1]-x1; feat[2][t] = nb[2]-x2;
    feat[3][t] = x0; feat[4][t] = x1; feat[5][t] = x2;
  }
  __syncthreads();
  #pragma unroll
  for(int i=0;i<32;i++){
    int e = t + (i<<8);
    int k = e>>7, n = e&127;
    float h = w1l[k*6+0]*feat[0][n] + w1l[k*6+1]*feat[1][n] + w1l[k*6+2]*feat[2][n]
            + w1l[k*6+3]*feat[3][n] + w1l[k*6+4]*feat[4][n] + w1l[k*6+5]*feat[5][n];
    Bs[k*132 + n] = lrelu(fmaf(h, s1[k], t1[k]));
  }
  __syncthreads();
  int tx = t&15, ty = t>>4;
  float acc[4][8];
  #pragma unroll
  for(int i=0;i<4;i++){
    #pragma unroll
    for(int j=0;j<8;j++) acc[i][j]=0.f;
  }
  #pragma unroll 4
  for(int k=0;k<64;k++){
    float4 a  = *(const float4*)&As[k*64 + ty*4];
    float4 b0 = *(const float4*)&Bs[k*132 + tx*4];
    float4 b1 = *(const float4*)&Bs[k*132 + 64 + tx*4];
    float av[4] = {a.x,a.y,a.z,a.w};
    float bv[8] = {b0.x,b0.y,b0.z,b0.w,b1.x,b1.y,b1.z,b1.w};
    #pragma unroll
    for(int i=0;i<4;i++){
      #pragma unroll
      for(int j=0;j<8;j++) acc[i][j] = fmaf(av[i], bv[j], acc[i][j]);
    }
  }
  #pragma unroll
  for(int i=0;i<4;i++){
    int m = ty*4 + i;
    float sr = ((acc[i][0]+acc[i][1])+(acc[i][2]+acc[i][3])) + ((acc[i][4]+acc[i][5])+(acc[i][6]+acc[i][7]));
    float sq = ((acc[i][0]*acc[i][0]+acc[i][1]*acc[i][1])+(acc[i][2]*acc[i][2]+acc[i][3]*acc[i][3]))
             + ((acc[i][4]*acc[i][4]+acc[i][5]*acc[i][5])+(acc[i][6]*acc[i][6]+acc[i][7]*acc[i][7]));
    #pragma unroll
    for(int off=1; off<16; off<<=1){ sr += __shfl_xor(sr, off); sq += __shfl_xor(sq, off); }
    if(tx==0){ psum[(size_t)blk*64+m]=sr; psq[(size_t)blk*64+m]=sq; }
    float m0 = fmaxf(fmaxf(acc[i][0],acc[i][1]), fmaxf(acc[i][2],acc[i][3]));
    float m1 = fmaxf(fmaxf(acc[i][4],acc[i][5]), fmaxf(acc[i][6],acc[i][7]));
    #pragma unroll
    for(int off=1; off<8; off<<=1){ m0 = fmaxf(m0, __shfl_xor(m0, off)); m1 = fmaxf(m1, __shfl_xor(m1, off)); }
    if((tx&7)==0){
      int pl = pbase + (tx>>3);
      h2m[(size_t)pl*64 + m]     = m0;
      h2m[(size_t)(pl+2)*64 + m] = m1;
    }
  }
}

// ---------------- ec1 finalize ----------------
__global__ __launch_bounds__(256) void k_ec1fin(const float* __restrict__ h2m, const float* __restrict__ s2,
                                                const float* __restrict__ t2, float* __restrict__ xe1,
                                                float* __restrict__ xe1T, float* __restrict__ sqx){
  int gid = blockIdx.x*256 + threadIdx.x;  // < NP*64
  int p = gid>>6, l = gid&63;
  float v = lrelu(fmaf(h2m[(size_t)p*64+l], s2[l], t2[l]));
  xe1[(size_t)p*64+l] = v;
  int b=p>>12, pr=p&4095;
  xe1T[(size_t)(b*64+l)*4096 + pr] = v;
  float sq = v*v;
  #pragma unroll
  for(int off=32; off; off>>=1) sq += __shfl_xor(sq, off);
  if(l==0) sqx[p]=sq;
}

// ---------------- D = sq_n - 2 X X^T + sq_m ----------------
__global__ __launch_bounds__(256) void k_dgemm(const float* __restrict__ xT, const float* __restrict__ sqx,
                                               float* __restrict__ D){
  __shared__ float As[32*128], Bs2[32*128];
  int b = blockIdx.z;
  int m0 = blockIdx.y*128, n0 = blockIdx.x*128;
  int t = threadIdx.x;
  int tx = t&15, ty = t>>4;
  const float* xb = xT + (size_t)b*64*4096;
  float acc[8][8];
  #pragma unroll
  for(int i=0;i<8;i++){
    #pragma unroll
    for(int j=0;j<8;j++) acc[i][j]=0.f;
  }
  for(int kc=0;kc<2;kc++){
    __syncthreads();
    #pragma unroll
    for(int i=0;i<16;i++){
      int e = t + (i<<8);
      int k = e>>7, mm = e&127;
      As[k*128+mm]  = xb[(size_t)(kc*32+k)*4096 + m0+mm];
      Bs2[k*128+mm] = xb[(size_t)(kc*32+k)*4096 + n0+mm];
    }
    __syncthreads();
    #pragma unroll 4
    for(int k=0;k<32;k++){
      float av[8], bv[8];
      float4 A0 = *(float4*)&As[k*128 + ty*8];
      float4 A1 = *(float4*)&As[k*128 + ty*8+4];
      float4 B0 = *(float4*)&Bs2[k*128 + tx*8];
      float4 B1 = *(float4*)&Bs2[k*128 + tx*8+4];
      av[0]=A0.x; av[1]=A0.y; av[2]=A0.z; av[3]=A0.w; av[4]=A1.x; av[5]=A1.y; av[6]=A1.z; av[7]=A1.w;
      bv[0]=B0.x; bv[1]=B0.y; bv[2]=B0.z; bv[3]=B0.w; bv[4]=B1.x; bv[5]=B1.y; bv[6]=B1.z; bv[7]=B1.w;
      #pragma unroll
      for(int i=0;i<8;i++){
        #pragma unroll
        for(int j=0;j<8;j++) acc[i][j] = fmaf(av[i], bv[j], acc[i][j]);
      }
    }
  }
  const float* sb = sqx + (b<<12);
  float* Db = D + ((size_t)b<<24);
  #pragma unroll
  for(int i=0;i<8;i++){
    int r = m0 + ty*8 + i;
    float sqa = sb[r];
    float o[8];
    #pragma unroll
    for(int j=0;j<8;j++) o[j] = (sqa - 2.0f*acc[i][j]) + sb[n0+tx*8+j];
    *(float4*)&Db[(size_t)r*4096 + n0+tx*8]   = make_float4(o[0],o[1],o[2],o[3]);
    *(float4*)&Db[(size_t)r*4096 + n0+tx*8+4] = make_float4(o[4],o[5],o[6],o[7]);
  }
}

// ---------------- edge-conv 2 pass 1 (bf16 MFMA gather-GEMM) ----------------
__global__ __launch_bounds__(256) void k_ec2m1(const float* __restrict__ xe1, const int* __restrict__ idx2,
                                               const short* __restrict__ wb, float* __restrict__ h1,
                                               float* __restrict__ psum, float* __restrict__ psq){
  __shared__ short sA[8192], sB[8192];
  __shared__ float cts[4][64];
  __shared__ int nid[128];
  __shared__ float srs[2][128], srq[2][128];
  int t = threadIdx.x;
  int blk = blockIdx.x;
  int s0 = blk*128;
  int pbase = s0>>5;
  int bb = (s0>>17)<<12;
  if(t<128) nid[t] = (idx2[s0+t] + bb)<<6;
  cts[t>>6][t&63] = xe1[(size_t)(pbase + (t>>6))*64 + (t&63)];
  int lane = t&63, w = t>>6;
  int wm4 = (w>>1)*4, wn4 = (w&1)*4;
  f4v acc[4][4];
  #pragma unroll
  for(int i=0;i<4;i++){
    #pragma unroll
    for(int j=0;j<4;j++) acc[i][j] = (f4v)(0.f);
  }
  for(int st=0; st<2; ++st){
    __syncthreads();
    #pragma unroll
    for(int i=0;i<4;i++){
      int slot = t + i*256;
      *(s8v*)&sA[slot*8] = *(const s8v*)&wb[st*8192 + slot*8];
      int chunk = slot>>6, li = slot&63;
      int n = (chunk&7)*16 + (li&15);
      int c = ((chunk>>3)<<5) + ((li>>4)<<3);
      float v[8];
      if(st==0){
        const float* src = xe1 + nid[n] + c;
        float4 a0 = *(const float4*)src;
        float4 a1 = *(const float4*)(src+4);
        const float* cc = &cts[n>>5][c];
        float4 c0 = *(const float4*)cc;
        float4 c1 = *(const float4*)(cc+4);
        v[0]=a0.x-c0.x; v[1]=a0.y-c0.y; v[2]=a0.z-c0.z; v[3]=a0.w-c0.w;
        v[4]=a1.x-c1.x; v[5]=a1.y-c1.y; v[6]=a1.z-c1.z; v[7]=a1.w-c1.w;
      } else {
        const float* cc = &cts[n>>5][c];
        float4 c0 = *(const float4*)cc;
        float4 c1 = *(const float4*)(cc+4);
        v[0]=c0.x; v[1]=c0.y; v[2]=c0.z; v[3]=c0.w;
        v[4]=c1.x; v[5]=c1.y; v[6]=c1.z; v[7]=c1.w;
      }
      s8v r;
      #pragma unroll
      for(int j=0;j<8;j++) r[j] = f2bf(v[j]);
      *(s8v*)&sB[slot*8] = r;
    }
    __syncthreads();
    #pragma unroll
    for(int kh=0;kh<2;kh++){
      s8v av[4], bv[4];
      #pragma unroll
      for(int f=0;f<4;f++) av[f] = *(const s8v*)&sA[(kh*8 + wm4 + f)*512 + lane*8];
      #pragma unroll
      for(int f=0;f<4;f++) bv[f] = *(const s8v*)&sB[(kh*8 + wn4 + f)*512 + lane*8];
      #pragma unroll
      for(int fm=0;fm<4;fm++){
        #pragma unroll
        for(int fn=0;fn<4;fn++)
          acc[fm][fn] = __builtin_amdgcn_mfma_f32_16x16x32_bf16(av[fm], bv[fn], acc[fm][fn], 0, 0, 0);
      }
    }
  }
  int l15 = lane&15, l4 = (lane>>4)<<2;
  #pragma unroll
  for(int fm=0;fm<4;fm++){
    int mb_ = wm4*16 + fm*16 + l4;
    #pragma unroll
    for(int fn=0;fn<4;fn++){
      int n = wn4*16 + fn*16 + l15;
      *(float4*)&h1[(size_t)(s0+n)*128 + mb_] =
        make_float4(acc[fm][fn][0], acc[fm][fn][1], acc[fm][fn][2], acc[fm][fn][3]);
    }
    #pragma unroll
    for(int r=0;r<4;r++){
      float sr = (acc[fm][0][r]+acc[fm][1][r]) + (acc[fm][2][r]+acc[fm][3][r]);
      float sq = (acc[fm][0][r]*acc[fm][0][r]+acc[fm][1][r]*acc[fm][1][r])
               + (acc[fm][2][r]*acc[fm][2][r]+acc[fm][3][r]*acc[fm][3][r]);
      #pragma unroll
      for(int off=1; off<16; off<<=1){ sr += __shfl_xor(sr, off); sq += __shfl_xor(sq, off); }
      if(l15==0){ srs[w&1][mb_+r] = sr; srq[w&1][mb_+r] = sq; }
    }
  }
  __syncthreads();
  if(t<128){
    psum[(size_t)blk*128+t] = srs[0][t]+srs[1][t];
    psq[(size_t)blk*128+t]  = srq[0][t]+srq[1][t];
  }
}

// ---------------- edge-conv 2 pass 2 (bf16 MFMA, fused BN1+lrelu, stats + per-point max) ----------------
__global__ __launch_bounds__(256) void k_ec2m2(const float* __restrict__ h1, const short* __restrict__ wb,
                                               const float* __restrict__ s1, const float* __restrict__ t1,
                                               float* __restrict__ h2max, float* __restrict__ psum,
                                               float* __restrict__ psq){
  __shared__ short sA[8192], sB[8192];
  __shared__ float bnS[128], bnT[128];
  __shared__ float srs[2][128], srq[2][128];
  int t = threadIdx.x;
  int blk = blockIdx.x;
  int s0 = blk*128;
  int pbase = s0>>5;
  if(t<128){ bnS[t]=s1[t]; bnT[t]=t1[t]; }
  int lane = t&63, w = t>>6;
  int wm4 = (w>>1)*4, wn4 = (w&1)*4;
  f4v acc[4][4];
  #pragma unroll
  for(int i=0;i<4;i++){
    #pragma unroll
    for(int j=0;j<4;j++) acc[i][j] = (f4v)(0.f);
  }
  for(int st=0; st<2; ++st){
    __syncthreads();
    #pragma unroll
    for(int i=0;i<4;i++){
      int slot = t + i*256;
      *(s8v*)&sA[slot*8] = *(const s8v*)&wb[st*8192 + slot*8];
      int chunk = slot>>6, li = slot&63;
      int n = (chunk&7)*16 + (li&15);
      int c = st*64 + ((chunk>>3)<<5) + ((li>>4)<<3);
      const float* src = h1 + (size_t)(s0+n)*128 + c;
      float4 a0 = *(const float4*)src;
      float4 a1 = *(const float4*)(src+4);
      float v[8] = {a0.x,a0.y,a0.z,a0.w,a1.x,a1.y,a1.z,a1.w};
      s8v r;
      #pragma unroll
      for(int j=0;j<8;j++) r[j] = f2bf(lrelu(fmaf(v[j], bnS[c+j], bnT[c+j])));
      *(s8v*)&sB[slot*8] = r;
    }
    __syncthreads();
    #pragma unroll
    for(int kh=0;kh<2;kh++){
      s8v av[4], bv[4];
      #pragma unroll
      for(int f=0;f<4;f++) av[f] = *(const s8v*)&sA[(kh*8 + wm4 + f)*512 + lane*8];
      #pragma unroll
      for(int f=0;f<4;f++) bv[f] = *(const s8v*)&sB[(kh*8 + wn4 + f)*512 + lane*8];
      #pragma unroll
      for(int fm=0;fm<4;fm++){
        #pragma unroll
        for(int fn=0;fn<4;fn++)
          acc[fm][fn] = __builtin_amdgcn_mfma_f32_16x16x32_bf16(av[fm], bv[fn], acc[fm][fn], 0, 0, 0);
      }
    }
  }
  int l15 = lane&15, l4 = (lane>>4)<<2;
  int pp0 = wn4>>1;
  #pragma unroll
  for(int fm=0;fm<4;fm++){
    int mb_ = wm4*16 + fm*16 + l4;
    #pragma unroll
    for(int r=0;r<4;r++){
      float sr = (acc[fm][0][r]+acc[fm][1][r]) + (acc[fm][2][r]+acc[fm][3][r]);
      float sq = (acc[fm][0][r]*acc[fm][0][r]+acc[fm][1][r]*acc[fm][1][r])
               + (acc[fm][2][r]*acc[fm][2][r]+acc[fm][3][r]*acc[fm][3][r]);
      float m0 = fmaxf(acc[fm][0][r], acc[fm][1][r]);
      float m1 = fmaxf(acc[fm][2][r], acc[fm][3][r]);
      #pragma unroll
      for(int off=1; off<16; off<<=1){ sr += __shfl_xor(sr, off); sq += __shfl_xor(sq, off); }
      #pragma unroll
      for(int off=1; off<16; off<<=1){ m0 = fmaxf(m0, __shfl_xor(m0, off)); m1 = fmaxf(m1, __shfl_xor(m1, off)); }
      if(l15==0){
        srs[w&1][mb_+r] = sr; srq[w&1][mb_+r] = sq;
        h2max[(size_t)(pbase+pp0)*128   + mb_+r] = m0;
        h2max[(size_t)(pbase+pp0+1)*128 + mb_+r] = m1;
      }
    }
  }
  __syncthreads();
  if(t<128){
    psum[(size_t)blk*128+t] = srs[0][t]+srs[1][t];
    psq[(size_t)blk*128+t]  = srq[0][t]+srq[1][t];
  }
}

// ---------------- xe2 = lrelu(BN(h2max)) in-place ----------------
__global__ void k_xe2fin(float* __restrict__ xe2, const float* __restrict__ s2, const float* __restrict__ t2){
  int i = blockIdx.x*256 + threadIdx.x;   // < NP*128
  if(i >= NP*128) return;
  int o = i&127;
  xe2[i] = lrelu(fmaf(xe2[i], s2[o], t2[o]));
}

// ---------------- hcat ----------------
__global__ void k_hcat(const float* __restrict__ xe2, const float* __restrict__ kr, float* __restrict__ hcat){
  size_t i = (size_t)blockIdx.x*256 + threadIdx.x;
  int b = (int)(i>>20);
  int r = (int)(i & 1048575);
  int ch = r>>12;
  float v;
  if(ch < 128) v = xe2[(size_t)b*524288 + r];
  else         v = kr [(size_t)(b*128 + (ch-128))*4096 + (r&4095)];
  hcat[i] = v;
}

// ---------------- generic small transpose ----------------
__global__ void k_transpose(const float* __restrict__ w, float* __restrict__ wT, int O, int C){
  int i = blockIdx.x*256 + threadIdx.x;
  if(i >= O*C) return;
  int o = i / C, c = i % C;
  wT[(size_t)c*O + o] = w[i];
}

// ---------------- weight fp32 -> bf16 fragment-linear ----------------
__global__ void k_wprep(const float* __restrict__ w, short* __restrict__ wb, int M, int K){
  int tid = blockIdx.x*256 + threadIdx.x;
  int m = tid % M, kb8 = tid / M;
  int k0 = kb8*8;
  float4 v0 = *(const float4*)&w[(size_t)m*K + k0];
  float4 v1 = *(const float4*)&w[(size_t)m*K + k0 + 4];
  s8v r;
  r[0]=f2bf(v0.x); r[1]=f2bf(v0.y); r[2]=f2bf(v0.z); r[3]=f2bf(v0.w);
  r[4]=f2bf(v1.x); r[5]=f2bf(v1.y); r[6]=f2bf(v1.z); r[7]=f2bf(v1.w);
  int region = (m>>7)*(K>>6) + (k0>>6);
  int chunk = ((kb8>>2)&1)*8 + ((m>>4)&7);
  int lane = (kb8&3)*16 + (m&15);
  *(s8v*)&wb[(size_t)region*8192 + chunk*512 + lane*8] = r;
}

// ---------------- activations -> bf16 fragment-linear ----------------
__global__ void k_bprep(const float* __restrict__ in, const float* __restrict__ sc, const float* __restrict__ sh,
                        short* __restrict__ ob, int K){
  int tid = blockIdx.x*256 + threadIdx.x;
  int n = tid & 8191, kb8 = tid >> 13;
  int k0 = kb8*8;
  int b = n>>12, s = n&4095;
  const float* ib = in + ((size_t)b*K + k0)*4096 + s;
  float v[8];
  #pragma unroll
  for(int j=0;j<8;j++) v[j] = ib[(size_t)j*4096];
  if(sc){
    #pragma unroll
    for(int j=0;j<8;j++) v[j] = lrelu(fmaf(v[j], sc[k0+j], sh[k0+j]));
  }
  s8v r;
  #pragma unroll
  for(int j=0;j<8;j++) r[j] = f2bf(v[j]);
  int region = (n>>7)*(K>>6) + (k0>>6);
  int chunk = ((kb8>>2)&1)*8 + ((n>>4)&7);
  int lane = (kb8&3)*16 + (n&15);
  *(s8v*)&ob[(size_t)region*8192 + chunk*512 + lane*8] = r;
}

// ---------------- bf16 MFMA GEMM ----------------
__global__ __launch_bounds__(256) void k_gmm(const short* __restrict__ A, const short* __restrict__ B,
                                             float* __restrict__ out, int M, int K){
  __shared__ short sA[8192], sB[8192];
  int t = threadIdx.x;
  int lane = t&63;
  int w = t>>6;
  int wm4 = (w>>1)*4, wn4 = (w&1)*4;
  int mb = blockIdx.y, nb = blockIdx.x;
  int ksteps = K>>6;
  const short* AG = A + (size_t)mb*ksteps*8192;
  const short* BG = B + (size_t)nb*ksteps*8192;
  f4v acc[4][4];
  #pragma unroll
  for(int i=0;i<4;i++){
    #pragma unroll
    for(int j=0;j<4;j++) acc[i][j] = (f4v)(0.f);
  }
  for(int st=0; st<ksteps; ++st){
    __syncthreads();
    #pragma unroll
    for(int i=0;i<4;i++){
      int slot = t + i*256;
      *(s8v*)&sA[slot*8] = *(const s8v*)&AG[(size_t)st*8192 + slot*8];
      *(s8v*)&sB[slot*8] = *(const s8v*)&BG[(size_t)st*8192 + slot*8];
    }
    __syncthreads();
    #pragma unroll
    for(int kh=0;kh<2;kh++){
      s8v av[4], bv[4];
      #pragma unroll
      for(int f=0;f<4;f++) av[f] = *(const s8v*)&sA[(kh*8 + wm4 + f)*512 + lane*8];
      #pragma unroll
      for(int f=0;f<4;f++) bv[f] = *(const s8v*)&sB[(kh*8 + wn4 + f)*512 + lane*8];
      #pragma unroll
      for(int fm=0;fm<4;fm++){
        #pragma unroll
        for(int fn=0;fn<4;fn++)
          acc[fm][fn] = __builtin_amdgcn_mfma_f32_16x16x32_bf16(av[fm], bv[fn], acc[fm][fn], 0, 0, 0);
      }
    }
  }
  int l15 = lane&15, l4 = (lane>>4)*4;
  #pragma unroll
  for(int fm=0;fm<4;fm++){
    int mrow = mb*128 + wm4*16 + fm*16 + l4;
    #pragma unroll
    for(int fn=0;fn<4;fn++){
      int n = nb*128 + wn4*16 + fn*16 + l15;
      int b = n>>12, s = n&4095;
      float* ob = out + ((size_t)b*M + mrow)*4096 + s;
      #pragma unroll
      for(int r=0;r<4;r++) ob[(size_t)r*4096] = acc[fm][fn][r];
    }
  }
}

// ---------------- per-channel stats for cbr layers ----------------
__global__ void k_cstats(const float* __restrict__ buf, int C, const float* __restrict__ g,
                         const float* __restrict__ be, float* __restrict__ sc, float* __restrict__ sh){
  int o = blockIdx.x, t = threadIdx.x;
  float s=0.f, q=0.f;
  for(int i=t;i<8192;i+=256){
    int b=i>>12, ss_=i&4095;
    float v = buf[(size_t)(b*C+o)*4096 + ss_];
    s+=v; q+=v*v;
  }
  __shared__ float ls[256], lq[256];
  ls[t]=s; lq[t]=q; __syncthreads();
  for(int st=128; st; st>>=1){ if(t<st){ ls[t]+=ls[t+st]; lq[t]+=lq[t+st]; } __syncthreads(); }
  if(t==0){
    float mu = ls[0]/8192.f;
    float var = lq[0]/8192.f - mu*mu; if(var<0.f) var=0.f;
    float s1 = g[o]*rsqrtf(var + EPSB);
    sc[o]=s1; sh[o]=be[o]-mu*s1;
  }
}

// ---------------- final layer ----------------
__global__ __launch_bounds__(256) void k_final4(const float* __restrict__ c3, const float* __restrict__ w4T,
                                                const float* __restrict__ sc, const float* __restrict__ sh,
                                                float* __restrict__ pmax){
  int b = blockIdx.y, st = blockIdx.x;
  int t = threadIdx.x; int s = st*256 + t;
  float acc[9];
  #pragma unroll
  for(int j=0;j<9;j++) acc[j]=0.f;
  const float* ib = c3 + (size_t)b*256*4096;
  for(int c=0;c<256;c++){
    float x = lrelu(fmaf(ib[(size_t)c*4096+s], sc[c], sh[c]));
    #pragma unroll
    for(int j=0;j<9;j++) acc[j]=fmaf(x, w4T[c*9+j], acc[j]);
  }
  __shared__ float red[256];
  for(int j=0;j<9;j++){
    red[t]=acc[j]; __syncthreads();
    for(int stp=128; stp; stp>>=1){ if(t<stp) red[t]=fmaxf(red[t],red[t+stp]); __syncthreads(); }
    if(t==0) pmax[(b*16+st)*9 + j]=red[0];
    __syncthreads();
  }
}

__global__ void k_out(const float* __restrict__ pmax, float* __restrict__ out){
  int i = threadIdx.x;
  if(i<18){
    int b=i/9, o=i%9;
    float m=-3.4e38f;
    for(int k=0;k<16;k++) m=fmaxf(m, pmax[(b*16+k)*9+o]);
    out[i] = m + ((o==0||o==4||o==8)?1.f:0.f);
  }
}

// ---------------- launch ----------------
extern "C" void kernel_launch(void* const* d_in, const int* in_sizes, int n_in,
                              void* d_out, int out_size, void* d_ws, size_t ws_size,
                              hipStream_t stream){
  const float* x    = (const float*)d_in[0];
  const float* kc   = (const float*)d_in[1];
  const float* e1w1 = (const float*)d_in[2];
  const float* e1g1 = (const float*)d_in[3];
  const float* e1b1 = (const float*)d_in[4];
  const float* e1w2 = (const float*)d_in[5];
  const float* e1g2 = (const float*)d_in[6];
  const float* e1b2 = (const float*)d_in[7];
  const float* e2w1 = (const float*)d_in[8];
  const float* e2g1 = (const float*)d_in[9];
  const float* e2b1 = (const float*)d_in[10];
  const float* e2w2 = (const float*)d_in[11];
  const float* e2g2 = (const float*)d_in[12];
  const float* e2b2 = (const float*)d_in[13];
  const float* w1   = (const float*)d_in[14];
  const float* g1   = (const float*)d_in[15];
  const float* b1   = (const float*)d_in[16];
  const float* w2   = (const float*)d_in[17];
  const float* g2   = (const float*)d_in[18];
  const float* b2   = (const float*)d_in[19];
  const float* w3   = (const float*)d_in[20];
  const float* g3   = (const float*)d_in[21];
  const float* b3   = (const float*)d_in[22];
  const float* w4   = (const float*)d_in[23];

  if(ws_size < 156061696ull) return;
  char* ws = (char*)d_ws;
  float* pts   = (float*)(ws + 0);
  float* xe0   = (float*)(ws + 98304);
  float* sqp   = (float*)(ws + 196608);
  float* sqe   = (float*)(ws + 229376);
  float* sqx1  = (float*)(ws + 262144);
  float* xe1   = (float*)(ws + 294912);
  float* xe1T  = (float*)(ws + 2392064);
  float* xe2   = (float*)(ws + 4489216);
  float* kr    = (float*)(ws + 8683520);
  int*   idxP  = (int*)  (ws + 12877824);
  int*   idx1  = (int*)  (ws + 13926400);
  int*   idx2  = (int*)  (ws + 14974976);
  float* psum  = (float*)(ws + 16023552);
  float* psq   = (float*)(ws + 17072128);
  float* par   = (float*)(ws + 18120704);
  float* pmax  = (float*)(ws + 18153472);
  float* e1w2T = (float*)(ws + 18157568);
  float* wT4   = (float*)(ws + 21827584);
  float* hbuf  = (float*)(ws + 21843968);
  short* wbe1  = (short*)(ws + 0);       // reuses dead pts region
  short* wbe2  = (short*)(ws + 65536);
  short* actB  = (short*)(ws + 88952832);
  short* wb1   = (short*)(ws + 105730048);
  short* wb2   = (short*)(ws + 106254336);
  short* wb3   = (short*)(ws + 107302912);
  float* pmom  = psum;                   // 27*2048 floats, consumed before psum reused
  float* momv  = psq;                    // 27 floats

  float* e1s1 = par+0;    float* e1t1 = par+64;
  float* e1s2 = par+128;  float* e1t2 = par+192;
  float* e2s1 = par+256;  float* e2t1 = par+384;
  float* e2s2 = par+512;  float* e2t2 = par+640;
  float* c1s  = par+768;  float* c1t  = par+1792;
  float* c2s  = par+2816; float* c2t  = par+3328;
  float* c3s  = par+3840; float* c3t  = par+4096;

  float* hcat  = hbuf;
  float* c1out = hbuf + 2097152;
  float* c2out = hbuf + 10485760;
  float* c3out = hbuf + 14680064;

  hipLaunchKernelGGL(k_prep, dim3(32), dim3(256), 0, stream, x, pts, xe0, sqp, sqe);
  hipLaunchKernelGGL(k_knn3, dim3(2048), dim3(256), 0, stream, pts, sqp, idxP);
  hipLaunchKernelGGL(k_knn3, dim3(2048), dim3(256), 0, stream, xe0, sqe, idx1);
  hipLaunchKernelGGL(k_gauss, dim3(8192), dim3(128), 0, stream, pts, sqp, idxP, kc, kr);

  // edge-conv 1 (moment-based BN1 stats; h1 never stored)
  hipLaunchKernelGGL(k_transpose, dim3(16), dim3(256), 0, stream, e1w2, e1w2T, 64, 64);
  hipLaunchKernelGGL(k_ec1mom, dim3(512), dim3(256), 0, stream, xe0, idx1, pmom);
  hipLaunchKernelGGL(k_msum, dim3(27), dim3(256), 0, stream, pmom, momv);
  hipLaunchKernelGGL(k_ec1bn, dim3(1), dim3(64), 0, stream, momv, e1w1, e1g1, e1b1, e1s1, e1t1);
  hipLaunchKernelGGL(k_ec1g2, dim3(2048), dim3(256), 0, stream, xe0, idx1, e1w1, e1w2T, e1s1, e1t1, hbuf, psum, psq);
  hipLaunchKernelGGL(k_fin, dim3(64), dim3(256), 0, stream, psum, psq, 2048, 64, 262144.f, e1g2, e1b2, e1s2, e1t2);
  hipLaunchKernelGGL(k_ec1fin, dim3(2048), dim3(256), 0, stream, hbuf, e1s2, e1t2, xe1, xe1T, sqx1);

  // knn on 64-d features
  hipLaunchKernelGGL(k_dgemm, dim3(32,32,2), dim3(256), 0, stream, xe1T, sqx1, hbuf);
  hipLaunchKernelGGL(k_knn_sel, dim3(2048), dim3(256), 0, stream, hbuf, idx2);

  // edge-conv 2 (bf16 MFMA formulation, fused stats+max)
  hipLaunchKernelGGL(k_wprep, dim3(8), dim3(256), 0, stream, e2w1, wbe1, 128, 128);
  hipLaunchKernelGGL(k_wprep, dim3(8), dim3(256), 0, stream, e2w2, wbe2, 128, 128);
  hipLaunchKernelGGL(k_ec2m1, dim3(2048), dim3(256), 0, stream, xe1, idx2, wbe1, hbuf, psum, psq);
  hipLaunchKernelGGL(k_fin, dim3(128), dim3(256), 0, stream, psum, psq, 2048, 128, 262144.f, e2g1, e2b1, e2s1, e2t1);
  hipLaunchKernelGGL(k_ec2m2, dim3(2048), dim3(256), 0, stream, hbuf, wbe2, e2s1, e2t1, xe2, psum, psq);
  hipLaunchKernelGGL(k_fin, dim3(128), dim3(256), 0, stream, psum, psq, 2048, 128, 262144.f, e2g2, e2b2, e2s2, e2t2);
  hipLaunchKernelGGL(k_xe2fin, dim3(4096), dim3(256), 0, stream, xe2, e2s2, e2t2);

  // concat + bf16 MFMA cbr chain
  hipLaunchKernelGGL(k_hcat, dim3(8192), dim3(256), 0, stream, xe2, kr, hcat);
  hipLaunchKernelGGL(k_wprep, dim3(128), dim3(256), 0, stream, w1, wb1, 1024, 256);
  hipLaunchKernelGGL(k_wprep, dim3(256), dim3(256), 0, stream, w2, wb2, 512, 1024);
  hipLaunchKernelGGL(k_wprep, dim3(64),  dim3(256), 0, stream, w3, wb3, 256, 512);
  hipLaunchKernelGGL(k_transpose, dim3((9*256+255)/256), dim3(256), 0, stream, w4, wT4, 9, 256);

  hipLaunchKernelGGL(k_bprep, dim3(1024), dim3(256), 0, stream, hcat, (const float*)nullptr, (const float*)nullptr, actB, 256);
  hipLaunchKernelGGL(k_gmm, dim3(64,8), dim3(256), 0, stream, wb1, actB, c1out, 1024, 256);
  hipLaunchKernelGGL(k_cstats, dim3(1024), dim3(256), 0, stream, c1out, 1024, g1, b1, c1s, c1t);

  hipLaunchKernelGGL(k_bprep, dim3(4096), dim3(256), 0, stream, c1out, c1s, c1t, actB, 1024);
  hipLaunchKernelGGL(k_gmm, dim3(64,4), dim3(256), 0, stream, wb2, actB, c2out, 512, 1024);
  hipLaunchKernelGGL(k_cstats, dim3(512), dim3(256), 0, stream, c2out, 512, g2, b2, c2s, c2t);

  hipLaunchKernelGGL(k_bprep, dim3(2048), dim3(256), 0, stream, c2out, c2s, c2t, actB, 512);
  hipLaunchKernelGGL(k_gmm, dim3(64,2), dim3(256), 0, stream, wb3, actB, c3out, 256, 512);
  hipLaunchKernelGGL(k_cstats, dim3(256), dim3(256), 0, stream, c3out, 256, g3, b3, c3s, c3t);

  hipLaunchKernelGGL(k_final4, dim3(16,2), dim3(256), 0, stream, c3out, wT4, c3s, c3t, pmax);
  hipLaunchKernelGGL(k_out, dim3(1), dim3(32), 0, stream, pmax, (float*)d_out);
}

// Round 11
// 713.821 us; speedup vs baseline: 3.4775x; 1.0515x over previous
//
#include <hip/hip_runtime.h>
#include <math.h>

#define WN 4096
#define NP 8192
#define KK 32
#define EPSB 1e-5f

typedef __attribute__((ext_vector_type(8))) short s8v;
typedef __attribute__((ext_vector_type(4))) float f4v;

__device__ __forceinline__ float lrelu(float x){ return fmaxf(x, 0.01f*x); }
__device__ __forceinline__ float rlane(float v, int c){
  return __int_as_float(__builtin_amdgcn_readlane(__float_as_int(v), c));
}
__device__ __forceinline__ short f2bf(float f){
  unsigned u = __float_as_uint(f);
  u = (u + 0x7fffu + ((u>>16)&1u)) >> 16;
  return (short)u;
}

// ---------------- prep ----------------
__global__ void k_prep(const float* __restrict__ x, float* __restrict__ pts, float* __restrict__ xe0,
                       float* __restrict__ sqp, float* __restrict__ sqe,
                       float4* __restrict__ pts4, float4* __restrict__ xe04){
  int i = blockIdx.x*256 + threadIdx.x;
  if(i >= NP) return;
  int b = i>>12, p = i&4095;
  const float* xb = x + b*12288;
  float a0 = xb[p], a1 = xb[4096+p], a2 = xb[8192+p];
  pts[i*3+0]=a0; pts[i*3+1]=a1; pts[i*3+2]=a2;
  float sp = (a0*a0 + a1*a1) + a2*a2;
  sqp[i] = sp;
  pts4[i] = make_float4(a0,a1,a2,sp);
  float e0 = xb[p*3+0], e1 = xb[p*3+1], e2 = xb[p*3+2];
  xe0[i*3+0]=e0; xe0[i*3+1]=e1; xe0[i*3+2]=e2;
  float se = (e0*e0 + e1*e1) + e2*e2;
  sqe[i] = se;
  xe04[i] = make_float4(e0,e1,e2,se);
}

// ---------------- bitonic sort of 64 (d, idx) pairs across lanes, ascending ----------------
__device__ __forceinline__ void bitonic64(float& d, int& m, int l){
  #pragma unroll
  for(int k=2;k<=64;k<<=1){
    #pragma unroll
    for(int j=k>>1;j>0;j>>=1){
      float pd = __shfl_xor(d, j);
      int pm = __shfl_xor(m, j);
      bool pLess = (pd < d);
      bool dirUp = ((l & k) == 0);
      bool lower = ((l & j) == 0);
      bool take = dirUp ? (lower ? pLess : !pLess) : (lower ? !pLess : pLess);
      if(take){ d = pd; m = pm; }
    }
  }
}

// ---------------- streaming wave top-32 (sorted list in lanes 0..31, no refinement) ----------------
// Stale survivors (>= current 32nd) compute pos==32 and become structural no-ops.
__device__ __forceinline__ void topk_stream(float d, int m, int l, float& lv, int& li){
  unsigned long long mask = __ballot(d < rlane(lv, 31));
  while(mask){
    int s = __ffsll((unsigned long long)mask) - 1;
    float cd = __shfl(d, s);
    int cm = __shfl(m, s);
    unsigned long long less = __ballot(lv < cd);
    int pos = __popcll(less & 0xffffffffULL);
    float uv = __shfl_up(lv, 1);
    int ui = __shfl_up(li, 1);
    if(l < 32){
      if(l == pos){ lv = cd; li = cm; }
      else if(l > pos){ lv = uv; li = ui; }
    }
    mask &= mask - 1;
  }
}

__global__ __launch_bounds__(256) void k_knn3(const float4* __restrict__ pnt4, int* __restrict__ idx){
  int l = threadIdx.x&63;
  int q = blockIdx.x*4 + (threadIdx.x>>6);
  int b = q>>12, qr = q&4095;
  const float4* pb = pnt4 + ((size_t)b<<12);
  float4 qv = pb[qr];
  float q0=qv.x, q1=qv.y, q2=qv.z, sqq=qv.w;
  // batch 0 via bitonic sort -> initial sorted top-32 + tight threshold
  float dd; int mm = l;
  {
    float4 c = pb[l];
    float dot = q0*c.x + q1*c.y + q2*c.z;
    dd = (sqq - 2.0f*dot) + c.w;
  }
  bitonic64(dd, mm, l);
  float lv = (l<32) ? dd : 3.4e38f;
  int li = (l<32) ? mm : 0x7fffffff;
  #pragma unroll 4
  for(int j=1;j<64;j++){
    int m = l + (j<<6);
    float4 c = pb[m];
    float dot = q0*c.x + q1*c.y + q2*c.z;
    float d = (sqq - 2.0f*dot) + c.w;
    topk_stream(d, m, l, lv, li);
  }
  if(l < 32) idx[(size_t)q*KK + l] = li;
}

__global__ __launch_bounds__(256) void k_knn_sel(const float* __restrict__ D, int* __restrict__ idx){
  int l = threadIdx.x&63;
  int q = blockIdx.x*4 + (threadIdx.x>>6);
  int b = q>>12, qr = q&4095;
  const float* row = D + ((size_t)b<<24) + ((size_t)qr<<12);
  float dd = row[l]; int mm = l;
  bitonic64(dd, mm, l);
  float lv = (l<32) ? dd : 3.4e38f;
  int li = (l<32) ? mm : 0x7fffffff;
  #pragma unroll 4
  for(int j=1;j<64;j++){
    int m = l + (j<<6);
    float d = row[m];
    topk_stream(d, m, l, lv, li);
  }
  if(l < 32) idx[(size_t)q*KK + l] = li;
}

// ---------------- gaussian kernel conv ----------------
__global__ __launch_bounds__(128) void k_gauss(const float* __restrict__ pts, const float* __restrict__ sqp,
                                               const int* __restrict__ idxP, const float* __restrict__ cen,
                                               float* __restrict__ kout){
  __shared__ float nbx[KK], nby[KK], nbz[KK], nsq[KK];
  int p = blockIdx.x; int b = p>>12; int t = threadIdx.x;
  if(t < KK){
    int id = idxP[(size_t)p*KK + t] + (b<<12);
    nbx[t]=pts[id*3]; nby[t]=pts[id*3+1]; nbz[t]=pts[id*3+2];
    nsq[t]=sqp[id];
  }
  __syncthreads();
  float c0=cen[t*3], c1=cen[t*3+1], c2=cen[t*3+2];
  float sqc=(c0*c0+c1*c1)+c2*c2;
  float acc=0.f;
  #pragma unroll
  for(int k=0;k<KK;k++){
    float dot = nbx[k]*c0 + nby[k]*c1 + nbz[k]*c2;
    float d = (nsq[k] - 2.0f*dot) + sqc;
    acc += __expf(-0.5f*d);
  }
  kout[(size_t)((b<<7)+t)*4096 + (p&4095)] = acc;
}

// ---------------- finalize BN stats ----------------
__global__ void k_fin(const float* __restrict__ psum, const float* __restrict__ psq, int NW, int C, float Nn,
                      const float* __restrict__ g, const float* __restrict__ be,
                      float* __restrict__ sc, float* __restrict__ sh){
  int o = blockIdx.x, t = threadIdx.x;
  float s=0.f, q=0.f;
  for(int w=t; w<NW; w+=256){ s += psum[(size_t)w*C+o]; q += psq[(size_t)w*C+o]; }
  __shared__ float ls[256], lq[256];
  ls[t]=s; lq[t]=q; __syncthreads();
  for(int st=128; st; st>>=1){ if(t<st){ ls[t]+=ls[t+st]; lq[t]+=lq[t+st]; } __syncthreads(); }
  if(t==0){
    float mu = ls[0]/Nn;
    float var = lq[0]/Nn - mu*mu; if(var<0.f) var=0.f;
    float s1 = g[o]*rsqrtf(var + EPSB);
    sc[o]=s1; sh[o]=be[o]-mu*s1;
  }
}

// ---------------- edge-conv 1 BN1 stats via feature moments ----------------
__global__ __launch_bounds__(256) void k_ec1mom(const float* __restrict__ xe0, const int* __restrict__ idx1,
                                                float* __restrict__ pmom){
  int tid = blockIdx.x*256 + threadIdx.x;      // < 131072
  int l = threadIdx.x & 63;
  int wid = tid >> 6;                           // < 2048
  float a[27];
  #pragma unroll
  for(int v=0;v<27;v++) a[v]=0.f;
  #pragma unroll
  for(int u=0;u<2;u++){
    int s = tid*2 + u;                          // < 262144
    int p = s>>5;
    int bb = (p>>12)<<12;
    int id = bb + idx1[s];
    const float* nb = xe0 + (size_t)id*3;
    const float* xc = xe0 + (size_t)p*3;
    float f[6];
    f[0]=nb[0]-xc[0]; f[1]=nb[1]-xc[1]; f[2]=nb[2]-xc[2];
    f[3]=xc[0]; f[4]=xc[1]; f[5]=xc[2];
    int v=0;
    #pragma unroll
    for(int i=0;i<6;i++){
      #pragma unroll
      for(int j=i;j<6;j++){ a[v] = fmaf(f[i], f[j], a[v]); v++; }
    }
    #pragma unroll
    for(int i=0;i<6;i++) a[21+i] += f[i];
  }
  #pragma unroll
  for(int v=0;v<27;v++){
    float t = a[v];
    #pragma unroll
    for(int off=32; off; off>>=1) t += __shfl_xor(t, off);
    if(l==0) pmom[v*2048 + wid] = t;
  }
}

__global__ void k_msum(const float* __restrict__ pmom, float* __restrict__ mom){
  int v = blockIdx.x; int t = threadIdx.x;
  float s=0.f;
  for(int i=t;i<2048;i+=256) s += pmom[v*2048+i];
  __shared__ float ls[256];
  ls[t]=s; __syncthreads();
  for(int st=128; st; st>>=1){ if(t<st) ls[t]+=ls[t+st]; __syncthreads(); }
  if(t==0) mom[v]=ls[0];
}

__global__ void k_ec1bn(const float* __restrict__ mom, const float* __restrict__ w1,
                        const float* __restrict__ g, const float* __restrict__ be,
                        float* __restrict__ sc, float* __restrict__ sh){
  __shared__ float M[27];
  int t = threadIdx.x;
  if(t<27) M[t]=mom[t];
  __syncthreads();
  if(t<64){
    float w[6];
    #pragma unroll
    for(int c=0;c<6;c++) w[c]=w1[t*6+c];
    float qf=0.f, m1=0.f;
    int v=0;
    #pragma unroll
    for(int i=0;i<6;i++){
      #pragma unroll
      for(int j=i;j<6;j++){ qf += (i==j?1.f:2.f)*w[i]*w[j]*M[v]; v++; }
    }
    #pragma unroll
    for(int i=0;i<6;i++) m1 += w[i]*M[21+i];
    float N = 262144.f;
    float mu = m1/N;
    float var = qf/N - mu*mu; if(var<0.f) var=0.f;
    float s1 = g[t]*rsqrtf(var + EPSB);
    sc[t]=s1; sh[t]=be[t]-mu*s1;
  }
}

// ---------------- edge-conv 1 fused: rebuild y1 tile in LDS, GEMM h2=W2*y1, stats + per-point max ----------------
__global__ __launch_bounds__(256) void k_ec1g2(const float* __restrict__ xe0, const int* __restrict__ idx1,
                                               const float* __restrict__ w1, const float* __restrict__ w2T,
                                               const float* __restrict__ s1, const float* __restrict__ t1,
                                               float* __restrict__ h2m, float* __restrict__ psum,
                                               float* __restrict__ psq){
  __shared__ float As[64*64];
  __shared__ float Bs[64*132];
  __shared__ float feat[6][128];
  __shared__ float w1l[384];
  int t = threadIdx.x;
  int blk = blockIdx.x;
  int s0 = blk*128;
  int pbase = s0>>5;
  int bb = (s0>>17)<<12;
  #pragma unroll
  for(int i=0;i<16;i++) As[t + i*256] = w2T[t + i*256];
  for(int i=t; i<384; i+=256) w1l[i] = w1[i];
  if(t < 128){
    int s = s0 + t;
    int p = pbase + (t>>5);
    int id = bb + idx1[s];
    const float* nb = xe0 + (size_t)id*3;
    const float* xc = xe0 + (size_t)p*3;
    float x0 = xc[0], x1 = xc[1], x2 = xc[2];
    feat[0][t] = nb[0]-x0; feat[1][t] = nb[1]-x1; feat[2][t] = nb[2]-x2;
    feat[3][t] = x0; feat[4][t] = x1; feat[5][t] = x2;
  }
  __syncthreads();
  #pragma unroll
  for(int i=0;i<32;i++){
    int e = t + (i<<8);
    int k = e>>7, n = e&127;
    float h = w1l[k*6+0]*feat[0][n] + w1l[k*6+1]*feat[1][n] + w1l[k*6+2]*feat[2][n]
            + w1l[k*6+3]*feat[3][n] + w1l[k*6+4]*feat[4][n] + w1l[k*6+5]*feat[5][n];
    Bs[k*132 + n] = lrelu(fmaf(h, s1[k], t1[k]));
  }
  __syncthreads();
  int tx = t&15, ty = t>>4;
  float acc[4][8];
  #pragma unroll
  for(int i=0;i<4;i++){
    #pragma unroll
    for(int j=0;j<8;j++) acc[i][j]=0.f;
  }
  #pragma unroll 4
  for(int k=0;k<64;k++){
    float4 a  = *(const float4*)&As[k*64 + ty*4];
    float4 b0 = *(const float4*)&Bs[k*132 + tx*4];
    float4 b1 = *(const float4*)&Bs[k*132 + 64 + tx*4];
    float av[4] = {a.x,a.y,a.z,a.w};
    float bv[8] = {b0.x,b0.y,b0.z,b0.w,b1.x,b1.y,b1.z,b1.w};
    #pragma unroll
    for(int i=0;i<4;i++){
      #pragma unroll
      for(int j=0;j<8;j++) acc[i][j] = fmaf(av[i], bv[j], acc[i][j]);
    }
  }
  #pragma unroll
  for(int i=0;i<4;i++){
    int m = ty*4 + i;
    float sr = ((acc[i][0]+acc[i][1])+(acc[i][2]+acc[i][3])) + ((acc[i][4]+acc[i][5])+(acc[i][6]+acc[i][7]));
    float sq = ((acc[i][0]*acc[i][0]+acc[i][1]*acc[i][1])+(acc[i][2]*acc[i][2]+acc[i][3]*acc[i][3]))
             + ((acc[i][4]*acc[i][4]+acc[i][5]*acc[i][5])+(acc[i][6]*acc[i][6]+acc[i][7]*acc[i][7]));
    #pragma unroll
    for(int off=1; off<16; off<<=1){ sr += __shfl_xor(sr, off); sq += __shfl_xor(sq, off); }
    if(tx==0){ psum[(size_t)blk*64+m]=sr; psq[(size_t)blk*64+m]=sq; }
    float m0 = fmaxf(fmaxf(acc[i][0],acc[i][1]), fmaxf(acc[i][2],acc[i][3]));
    float m1 = fmaxf(fmaxf(acc[i][4],acc[i][5]), fmaxf(acc[i][6],acc[i][7]));
    #pragma unroll
    for(int off=1; off<8; off<<=1){ m0 = fmaxf(m0, __shfl_xor(m0, off)); m1 = fmaxf(m1, __shfl_xor(m1, off)); }
    if((tx&7)==0){
      int pl = pbase + (tx>>3);
      h2m[(size_t)pl*64 + m]     = m0;
      h2m[(size_t)(pl+2)*64 + m] = m1;
    }
  }
}

// ---------------- ec1 finalize ----------------
__global__ __launch_bounds__(256) void k_ec1fin(const float* __restrict__ h2m, const float* __restrict__ s2,
                                                const float* __restrict__ t2, float* __restrict__ xe1,
                                                float* __restrict__ xe1T, float* __restrict__ sqx){
  int gid = blockIdx.x*256 + threadIdx.x;  // < NP*64
  int p = gid>>6, l = gid&63;
  float v = lrelu(fmaf(h2m[(size_t)p*64+l], s2[l], t2[l]));
  xe1[(size_t)p*64+l] = v;
  int b=p>>12, pr=p&4095;
  xe1T[(size_t)(b*64+l)*4096 + pr] = v;
  float sq = v*v;
  #pragma unroll
  for(int off=32; off; off>>=1) sq += __shfl_xor(sq, off);
  if(l==0) sqx[p]=sq;
}

// ---------------- D = sq_n - 2 X X^T + sq_m ----------------
__global__ __launch_bounds__(256) void k_dgemm(const float* __restrict__ xT, const float* __restrict__ sqx,
                                               float* __restrict__ D){
  __shared__ float As[32*128], Bs2[32*128];
  int b = blockIdx.z;
  int m0 = blockIdx.y*128, n0 = blockIdx.x*128;
  int t = threadIdx.x;
  int tx = t&15, ty = t>>4;
  const float* xb = xT + (size_t)b*64*4096;
  float acc[8][8];
  #pragma unroll
  for(int i=0;i<8;i++){
    #pragma unroll
    for(int j=0;j<8;j++) acc[i][j]=0.f;
  }
  for(int kc=0;kc<2;kc++){
    __syncthreads();
    #pragma unroll
    for(int i=0;i<16;i++){
      int e = t + (i<<8);
      int k = e>>7, mm = e&127;
      As[k*128+mm]  = xb[(size_t)(kc*32+k)*4096 + m0+mm];
      Bs2[k*128+mm] = xb[(size_t)(kc*32+k)*4096 + n0+mm];
    }
    __syncthreads();
    #pragma unroll 4
    for(int k=0;k<32;k++){
      float av[8], bv[8];
      float4 A0 = *(float4*)&As[k*128 + ty*8];
      float4 A1 = *(float4*)&As[k*128 + ty*8+4];
      float4 B0 = *(float4*)&Bs2[k*128 + tx*8];
      float4 B1 = *(float4*)&Bs2[k*128 + tx*8+4];
      av[0]=A0.x; av[1]=A0.y; av[2]=A0.z; av[3]=A0.w; av[4]=A1.x; av[5]=A1.y; av[6]=A1.z; av[7]=A1.w;
      bv[0]=B0.x; bv[1]=B0.y; bv[2]=B0.z; bv[3]=B0.w; bv[4]=B1.x; bv[5]=B1.y; bv[6]=B1.z; bv[7]=B1.w;
      #pragma unroll
      for(int i=0;i<8;i++){
        #pragma unroll
        for(int j=0;j<8;j++) acc[i][j] = fmaf(av[i], bv[j], acc[i][j]);
      }
    }
  }
  const float* sb = sqx + (b<<12);
  float* Db = D + ((size_t)b<<24);
  #pragma unroll
  for(int i=0;i<8;i++){
    int r = m0 + ty*8 + i;
    float sqa = sb[r];
    float o[8];
    #pragma unroll
    for(int j=0;j<8;j++) o[j] = (sqa - 2.0f*acc[i][j]) + sb[n0+tx*8+j];
    *(float4*)&Db[(size_t)r*4096 + n0+tx*8]   = make_float4(o[0],o[1],o[2],o[3]);
    *(float4*)&Db[(size_t)r*4096 + n0+tx*8+4] = make_float4(o[4],o[5],o[6],o[7]);
  }
}

// ---------------- edge-conv 2 pass 1 (bf16 MFMA gather-GEMM) ----------------
__global__ __launch_bounds__(256) void k_ec2m1(const float* __restrict__ xe1, const int* __restrict__ idx2,
                                               const short* __restrict__ wb, float* __restrict__ h1,
                                               float* __restrict__ psum, float* __restrict__ psq){
  __shared__ short sA[8192], sB[8192];
  __shared__ float cts[4][64];
  __shared__ int nid[128];
  __shared__ float srs[2][128], srq[2][128];
  int t = threadIdx.x;
  int blk = blockIdx.x;
  int s0 = blk*128;
  int pbase = s0>>5;
  int bb = (s0>>17)<<12;
  if(t<128) nid[t] = (idx2[s0+t] + bb)<<6;
  cts[t>>6][t&63] = xe1[(size_t)(pbase + (t>>6))*64 + (t&63)];
  int lane = t&63, w = t>>6;
  int wm4 = (w>>1)*4, wn4 = (w&1)*4;
  f4v acc[4][4];
  #pragma unroll
  for(int i=0;i<4;i++){
    #pragma unroll
    for(int j=0;j<4;j++) acc[i][j] = (f4v)(0.f);
  }
  for(int st=0; st<2; ++st){
    __syncthreads();
    #pragma unroll
    for(int i=0;i<4;i++){
      int slot = t + i*256;
      *(s8v*)&sA[slot*8] = *(const s8v*)&wb[st*8192 + slot*8];
      int chunk = slot>>6, li = slot&63;
      int n = (chunk&7)*16 + (li&15);
      int c = ((chunk>>3)<<5) + ((li>>4)<<3);
      float v[8];
      if(st==0){
        const float* src = xe1 + nid[n] + c;
        float4 a0 = *(const float4*)src;
        float4 a1 = *(const float4*)(src+4);
        const float* cc = &cts[n>>5][c];
        float4 c0 = *(const float4*)cc;
        float4 c1 = *(const float4*)(cc+4);
        v[0]=a0.x-c0.x; v[1]=a0.y-c0.y; v[2]=a0.z-c0.z; v[3]=a0.w-c0.w;
        v[4]=a1.x-c1.x; v[5]=a1.y-c1.y; v[6]=a1.z-c1.z; v[7]=a1.w-c1.w;
      } else {
        const float* cc = &cts[n>>5][c];
        float4 c0 = *(const float4*)cc;
        float4 c1 = *(const float4*)(cc+4);
        v[0]=c0.x; v[1]=c0.y; v[2]=c0.z; v[3]=c0.w;
        v[4]=c1.x; v[5]=c1.y; v[6]=c1.z; v[7]=c1.w;
      }
      s8v r;
      #pragma unroll
      for(int j=0;j<8;j++) r[j] = f2bf(v[j]);
      *(s8v*)&sB[slot*8] = r;
    }
    __syncthreads();
    #pragma unroll
    for(int kh=0;kh<2;kh++){
      s8v av[4], bv[4];
      #pragma unroll
      for(int f=0;f<4;f++) av[f] = *(const s8v*)&sA[(kh*8 + wm4 + f)*512 + lane*8];
      #pragma unroll
      for(int f=0;f<4;f++) bv[f] = *(const s8v*)&sB[(kh*8 + wn4 + f)*512 + lane*8];
      #pragma unroll
      for(int fm=0;fm<4;fm++){
        #pragma unroll
        for(int fn=0;fn<4;fn++)
          acc[fm][fn] = __builtin_amdgcn_mfma_f32_16x16x32_bf16(av[fm], bv[fn], acc[fm][fn], 0, 0, 0);
      }
    }
  }
  int l15 = lane&15, l4 = (lane>>4)<<2;
  #pragma unroll
  for(int fm=0;fm<4;fm++){
    int mb_ = wm4*16 + fm*16 + l4;
    #pragma unroll
    for(int fn=0;fn<4;fn++){
      int n = wn4*16 + fn*16 + l15;
      *(float4*)&h1[(size_t)(s0+n)*128 + mb_] =
        make_float4(acc[fm][fn][0], acc[fm][fn][1], acc[fm][fn][2], acc[fm][fn][3]);
    }
    #pragma unroll
    for(int r=0;r<4;r++){
      float sr = (acc[fm][0][r]+acc[fm][1][r]) + (acc[fm][2][r]+acc[fm][3][r]);
      float sq = (acc[fm][0][r]*acc[fm][0][r]+acc[fm][1][r]*acc[fm][1][r])
               + (acc[fm][2][r]*acc[fm][2][r]+acc[fm][3][r]*acc[fm][3][r]);
      #pragma unroll
      for(int off=1; off<16; off<<=1){ sr += __shfl_xor(sr, off); sq += __shfl_xor(sq, off); }
      if(l15==0){ srs[w&1][mb_+r] = sr; srq[w&1][mb_+r] = sq; }
    }
  }
  __syncthreads();
  if(t<128){
    psum[(size_t)blk*128+t] = srs[0][t]+srs[1][t];
    psq[(size_t)blk*128+t]  = srq[0][t]+srq[1][t];
  }
}

// ---------------- edge-conv 2 pass 2 (bf16 MFMA, fused BN1+lrelu, stats + per-point max) ----------------
__global__ __launch_bounds__(256) void k_ec2m2(const float* __restrict__ h1, const short* __restrict__ wb,
                                               const float* __restrict__ s1, const float* __restrict__ t1,
                                               float* __restrict__ h2max, float* __restrict__ psum,
                                               float* __restrict__ psq){
  __shared__ short sA[8192], sB[8192];
  __shared__ float bnS[128], bnT[128];
  __shared__ float srs[2][128], srq[2][128];
  int t = threadIdx.x;
  int blk = blockIdx.x;
  int s0 = blk*128;
  int pbase = s0>>5;
  if(t<128){ bnS[t]=s1[t]; bnT[t]=t1[t]; }
  int lane = t&63, w = t>>6;
  int wm4 = (w>>1)*4, wn4 = (w&1)*4;
  f4v acc[4][4];
  #pragma unroll
  for(int i=0;i<4;i++){
    #pragma unroll
    for(int j=0;j<4;j++) acc[i][j] = (f4v)(0.f);
  }
  for(int st=0; st<2; ++st){
    __syncthreads();
    #pragma unroll
    for(int i=0;i<4;i++){
      int slot = t + i*256;
      *(s8v*)&sA[slot*8] = *(const s8v*)&wb[st*8192 + slot*8];
      int chunk = slot>>6, li = slot&63;
      int n = (chunk&7)*16 + (li&15);
      int c = st*64 + ((chunk>>3)<<5) + ((li>>4)<<3);
      const float* src = h1 + (size_t)(s0+n)*128 + c;
      float4 a0 = *(const float4*)src;
      float4 a1 = *(const float4*)(src+4);
      float v[8] = {a0.x,a0.y,a0.z,a0.w,a1.x,a1.y,a1.z,a1.w};
      s8v r;
      #pragma unroll
      for(int j=0;j<8;j++) r[j] = f2bf(lrelu(fmaf(v[j], bnS[c+j], bnT[c+j])));
      *(s8v*)&sB[slot*8] = r;
    }
    __syncthreads();
    #pragma unroll
    for(int kh=0;kh<2;kh++){
      s8v av[4], bv[4];
      #pragma unroll
      for(int f=0;f<4;f++) av[f] = *(const s8v*)&sA[(kh*8 + wm4 + f)*512 + lane*8];
      #pragma unroll
      for(int f=0;f<4;f++) bv[f] = *(const s8v*)&sB[(kh*8 + wn4 + f)*512 + lane*8];
      #pragma unroll
      for(int fm=0;fm<4;fm++){
        #pragma unroll
        for(int fn=0;fn<4;fn++)
          acc[fm][fn] = __builtin_amdgcn_mfma_f32_16x16x32_bf16(av[fm], bv[fn], acc[fm][fn], 0, 0, 0);
      }
    }
  }
  int l15 = lane&15, l4 = (lane>>4)<<2;
  int pp0 = wn4>>1;
  #pragma unroll
  for(int fm=0;fm<4;fm++){
    int mb_ = wm4*16 + fm*16 + l4;
    #pragma unroll
    for(int r=0;r<4;r++){
      float sr = (acc[fm][0][r]+acc[fm][1][r]) + (acc[fm][2][r]+acc[fm][3][r]);
      float sq = (acc[fm][0][r]*acc[fm][0][r]+acc[fm][1][r]*acc[fm][1][r])
               + (acc[fm][2][r]*acc[fm][2][r]+acc[fm][3][r]*acc[fm][3][r]);
      float m0 = fmaxf(acc[fm][0][r], acc[fm][1][r]);
      float m1 = fmaxf(acc[fm][2][r], acc[fm][3][r]);
      #pragma unroll
      for(int off=1; off<16; off<<=1){ sr += __shfl_xor(sr, off); sq += __shfl_xor(sq, off); }
      #pragma unroll
      for(int off=1; off<16; off<<=1){ m0 = fmaxf(m0, __shfl_xor(m0, off)); m1 = fmaxf(m1, __shfl_xor(m1, off)); }
      if(l15==0){
        srs[w&1][mb_+r] = sr; srq[w&1][mb_+r] = sq;
        h2max[(size_t)(pbase+pp0)*128   + mb_+r] = m0;
        h2max[(size_t)(pbase+pp0+1)*128 + mb_+r] = m1;
      }
    }
  }
  __syncthreads();
  if(t<128){
    psum[(size_t)blk*128+t] = srs[0][t]+srs[1][t];
    psq[(size_t)blk*128+t]  = srq[0][t]+srq[1][t];
  }
}

// ---------------- xe2 = lrelu(BN(h2max)) in-place ----------------
__global__ void k_xe2fin(float* __restrict__ xe2, const float* __restrict__ s2, const float* __restrict__ t2){
  int i = blockIdx.x*256 + threadIdx.x;   // < NP*128
  if(i >= NP*128) return;
  int o = i&127;
  xe2[i] = lrelu(fmaf(xe2[i], s2[o], t2[o]));
}

// ---------------- hcat ----------------
__global__ void k_hcat(const float* __restrict__ xe2, const float* __restrict__ kr, float* __restrict__ hcat){
  size_t i = (size_t)blockIdx.x*256 + threadIdx.x;
  int b = (int)(i>>20);
  int r = (int)(i & 1048575);
  int ch = r>>12;
  float v;
  if(ch < 128) v = xe2[(size_t)b*524288 + r];
  else         v = kr [(size_t)(b*128 + (ch-128))*4096 + (r&4095)];
  hcat[i] = v;
}

// ---------------- generic small transpose ----------------
__global__ void k_transpose(const float* __restrict__ w, float* __restrict__ wT, int O, int C){
  int i = blockIdx.x*256 + threadIdx.x;
  if(i >= O*C) return;
  int o = i / C, c = i % C;
  wT[(size_t)c*O + o] = w[i];
}

// ---------------- weight fp32 -> bf16 fragment-linear ----------------
__global__ void k_wprep(const float* __restrict__ w, short* __restrict__ wb, int M, int K){
  int tid = blockIdx.x*256 + threadIdx.x;
  int m = tid % M, kb8 = tid / M;
  int k0 = kb8*8;
  float4 v0 = *(const float4*)&w[(size_t)m*K + k0];
  float4 v1 = *(const float4*)&w[(size_t)m*K + k0 + 4];
  s8v r;
  r[0]=f2bf(v0.x); r[1]=f2bf(v0.y); r[2]=f2bf(v0.z); r[3]=f2bf(v0.w);
  r[4]=f2bf(v1.x); r[5]=f2bf(v1.y); r[6]=f2bf(v1.z); r[7]=f2bf(v1.w);
  int region = (m>>7)*(K>>6) + (k0>>6);
  int chunk = ((kb8>>2)&1)*8 + ((m>>4)&7);
  int lane = (kb8&3)*16 + (m&15);
  *(s8v*)&wb[(size_t)region*8192 + chunk*512 + lane*8] = r;
}

// ---------------- activations -> bf16 fragment-linear ----------------
__global__ void k_bprep(const float* __restrict__ in, const float* __restrict__ sc, const float* __restrict__ sh,
                        short* __restrict__ ob, int K){
  int tid = blockIdx.x*256 + threadIdx.x;
  int n = tid & 8191, kb8 = tid >> 13;
  int k0 = kb8*8;
  int b = n>>12, s = n&4095;
  const float* ib = in + ((size_t)b*K + k0)*4096 + s;
  float v[8];
  #pragma unroll
  for(int j=0;j<8;j++) v[j] = ib[(size_t)j*4096];
  if(sc){
    #pragma unroll
    for(int j=0;j<8;j++) v[j] = lrelu(fmaf(v[j], sc[k0+j], sh[k0+j]));
  }
  s8v r;
  #pragma unroll
  for(int j=0;j<8;j++) r[j] = f2bf(v[j]);
  int region = (n>>7)*(K>>6) + (k0>>6);
  int chunk = ((kb8>>2)&1)*8 + ((n>>4)&7);
  int lane = (kb8&3)*16 + (n&15);
  *(s8v*)&ob[(size_t)region*8192 + chunk*512 + lane*8] = r;
}

// ---------------- bf16 MFMA GEMM ----------------
__global__ __launch_bounds__(256) void k_gmm(const short* __restrict__ A, const short* __restrict__ B,
                                             float* __restrict__ out, int M, int K){
  __shared__ short sA[8192], sB[8192];
  int t = threadIdx.x;
  int lane = t&63;
  int w = t>>6;
  int wm4 = (w>>1)*4, wn4 = (w&1)*4;
  int mb = blockIdx.y, nb = blockIdx.x;
  int ksteps = K>>6;
  const short* AG = A + (size_t)mb*ksteps*8192;
  const short* BG = B + (size_t)nb*ksteps*8192;
  f4v acc[4][4];
  #pragma unroll
  for(int i=0;i<4;i++){
    #pragma unroll
    for(int j=0;j<4;j++) acc[i][j] = (f4v)(0.f);
  }
  for(int st=0; st<ksteps; ++st){
    __syncthreads();
    #pragma unroll
    for(int i=0;i<4;i++){
      int slot = t + i*256;
      *(s8v*)&sA[slot*8] = *(const s8v*)&AG[(size_t)st*8192 + slot*8];
      *(s8v*)&sB[slot*8] = *(const s8v*)&BG[(size_t)st*8192 + slot*8];
    }
    __syncthreads();
    #pragma unroll
    for(int kh=0;kh<2;kh++){
      s8v av[4], bv[4];
      #pragma unroll
      for(int f=0;f<4;f++) av[f] = *(const s8v*)&sA[(kh*8 + wm4 + f)*512 + lane*8];
      #pragma unroll
      for(int f=0;f<4;f++) bv[f] = *(const s8v*)&sB[(kh*8 + wn4 + f)*512 + lane*8];
      #pragma unroll
      for(int fm=0;fm<4;fm++){
        #pragma unroll
        for(int fn=0;fn<4;fn++)
          acc[fm][fn] = __builtin_amdgcn_mfma_f32_16x16x32_bf16(av[fm], bv[fn], acc[fm][fn], 0, 0, 0);
      }
    }
  }
  int l15 = lane&15, l4 = (lane>>4)*4;
  #pragma unroll
  for(int fm=0;fm<4;fm++){
    int mrow = mb*128 + wm4*16 + fm*16 + l4;
    #pragma unroll
    for(int fn=0;fn<4;fn++){
      int n = nb*128 + wn4*16 + fn*16 + l15;
      int b = n>>12, s = n&4095;
      float* ob = out + ((size_t)b*M + mrow)*4096 + s;
      #pragma unroll
      for(int r=0;r<4;r++) ob[(size_t)r*4096] = acc[fm][fn][r];
    }
  }
}

// ---------------- per-channel stats for cbr layers ----------------
__global__ void k_cstats(const float* __restrict__ buf, int C, const float* __restrict__ g,
                         const float* __restrict__ be, float* __restrict__ sc, float* __restrict__ sh){
  int o = blockIdx.x, t = threadIdx.x;
  float s=0.f, q=0.f;
  for(int i=t;i<8192;i+=256){
    int b=i>>12, ss_=i&4095;
    float v = buf[(size_t)(b*C+o)*4096 + ss_];
    s+=v; q+=v*v;
  }
  __shared__ float ls[256], lq[256];
  ls[t]=s; lq[t]=q; __syncthreads();
  for(int st=128; st; st>>=1){ if(t<st){ ls[t]+=ls[t+st]; lq[t]+=lq[t+st]; } __syncthreads(); }
  if(t==0){
    float mu = ls[0]/8192.f;
    float var = lq[0]/8192.f - mu*mu; if(var<0.f) var=0.f;
    float s1 = g[o]*rsqrtf(var + EPSB);
    sc[o]=s1; sh[o]=be[o]-mu*s1;
  }
}

// ---------------- final layer ----------------
__global__ __launch_bounds__(256) void k_final4(const float* __restrict__ c3, const float* __restrict__ w4T,
                                                const float* __restrict__ sc, const float* __restrict__ sh,
                                                float* __restrict__ pmax){
  int b = blockIdx.y, st = blockIdx.x;
  int t = threadIdx.x; int s = st*256 + t;
  float acc[9];
  #pragma unroll
  for(int j=0;j<9;j++) acc[j]=0.f;
  const float* ib = c3 + (size_t)b*256*4096;
  for(int c=0;c<256;c++){
    float x = lrelu(fmaf(ib[(size_t)c*4096+s], sc[c], sh[c]));
    #pragma unroll
    for(int j=0;j<9;j++) acc[j]=fmaf(x, w4T[c*9+j], acc[j]);
  }
  __shared__ float red[256];
  for(int j=0;j<9;j++){
    red[t]=acc[j]; __syncthreads();
    for(int stp=128; stp; stp>>=1){ if(t<stp) red[t]=fmaxf(red[t],red[t+stp]); __syncthreads(); }
    if(t==0) pmax[(b*16+st)*9 + j]=red[0];
    __syncthreads();
  }
}

__global__ void k_out(const float* __restrict__ pmax, float* __restrict__ out){
  int i = threadIdx.x;
  if(i<18){
    int b=i/9, o=i%9;
    float m=-3.4e38f;
    for(int k=0;k<16;k++) m=fmaxf(m, pmax[(b*16+k)*9+o]);
    out[i] = m + ((o==0||o==4||o==8)?1.f:0.f);
  }
}

// ---------------- launch ----------------
extern "C" void kernel_launch(void* const* d_in, const int* in_sizes, int n_in,
                              void* d_out, int out_size, void* d_ws, size_t ws_size,
                              hipStream_t stream){
  const float* x    = (const float*)d_in[0];
  const float* kc   = (const float*)d_in[1];
  const float* e1w1 = (const float*)d_in[2];
  const float* e1g1 = (const float*)d_in[3];
  const float* e1b1 = (const float*)d_in[4];
  const float* e1w2 = (const float*)d_in[5];
  const float* e1g2 = (const float*)d_in[6];
  const float* e1b2 = (const float*)d_in[7];
  const float* e2w1 = (const float*)d_in[8];
  const float* e2g1 = (const float*)d_in[9];
  const float* e2b1 = (const float*)d_in[10];
  const float* e2w2 = (const float*)d_in[11];
  const float* e2g2 = (const float*)d_in[12];
  const float* e2b2 = (const float*)d_in[13];
  const float* w1   = (const float*)d_in[14];
  const float* g1   = (const float*)d_in[15];
  const float* b1   = (const float*)d_in[16];
  const float* w2   = (const float*)d_in[17];
  const float* g2   = (const float*)d_in[18];
  const float* b2   = (const float*)d_in[19];
  const float* w3   = (const float*)d_in[20];
  const float* g3   = (const float*)d_in[21];
  const float* b3   = (const float*)d_in[22];
  const float* w4   = (const float*)d_in[23];

  if(ws_size < 156061696ull) return;
  char* ws = (char*)d_ws;
  float* pts   = (float*)(ws + 0);
  float* xe0   = (float*)(ws + 98304);
  float* sqp   = (float*)(ws + 196608);
  float* sqe   = (float*)(ws + 229376);
  float* sqx1  = (float*)(ws + 262144);
  float* xe1   = (float*)(ws + 294912);
  float* xe1T  = (float*)(ws + 2392064);
  float* xe2   = (float*)(ws + 4489216);
  float* kr    = (float*)(ws + 8683520);
  int*   idxP  = (int*)  (ws + 12877824);
  int*   idx1  = (int*)  (ws + 13926400);
  int*   idx2  = (int*)  (ws + 14974976);
  float* psum  = (float*)(ws + 16023552);
  float* psq   = (float*)(ws + 17072128);
  float* par   = (float*)(ws + 18120704);
  float* pmax  = (float*)(ws + 18153472);
  float* e1w2T = (float*)(ws + 18157568);
  float* wT4   = (float*)(ws + 21827584);
  float* hbuf  = (float*)(ws + 21843968);
  short* wbe1  = (short*)(ws + 0);       // reuses dead pts region
  short* wbe2  = (short*)(ws + 65536);
  // packed point buffers live in the not-yet-written xe2 region (first write is k_ec2m2)
  float4* pts4 = (float4*)(ws + 4489216);
  float4* xe04 = (float4*)(ws + 4489216 + 131072);
  short* actB  = (short*)(ws + 88952832);
  short* wb1   = (short*)(ws + 105730048);
  short* wb2   = (short*)(ws + 106254336);
  short* wb3   = (short*)(ws + 107302912);
  float* pmom  = psum;
  float* momv  = psq;

  float* e1s1 = par+0;    float* e1t1 = par+64;
  float* e1s2 = par+128;  float* e1t2 = par+192;
  float* e2s1 = par+256;  float* e2t1 = par+384;
  float* e2s2 = par+512;  float* e2t2 = par+640;
  float* c1s  = par+768;  float* c1t  = par+1792;
  float* c2s  = par+2816; float* c2t  = par+3328;
  float* c3s  = par+3840; float* c3t  = par+4096;

  float* hcat  = hbuf;
  float* c1out = hbuf + 2097152;
  float* c2out = hbuf + 10485760;
  float* c3out = hbuf + 14680064;

  hipLaunchKernelGGL(k_prep, dim3(32), dim3(256), 0, stream, x, pts, xe0, sqp, sqe, pts4, xe04);
  hipLaunchKernelGGL(k_knn3, dim3(2048), dim3(256), 0, stream, pts4, idxP);
  hipLaunchKernelGGL(k_knn3, dim3(2048), dim3(256), 0, stream, xe04, idx1);
  hipLaunchKernelGGL(k_gauss, dim3(8192), dim3(128), 0, stream, pts, sqp, idxP, kc, kr);

  // edge-conv 1 (moment-based BN1 stats; h1 never stored)
  hipLaunchKernelGGL(k_transpose, dim3(16), dim3(256), 0, stream, e1w2, e1w2T, 64, 64);
  hipLaunchKernelGGL(k_ec1mom, dim3(512), dim3(256), 0, stream, xe0, idx1, pmom);
  hipLaunchKernelGGL(k_msum, dim3(27), dim3(256), 0, stream, pmom, momv);
  hipLaunchKernelGGL(k_ec1bn, dim3(1), dim3(64), 0, stream, momv, e1w1, e1g1, e1b1, e1s1, e1t1);
  hipLaunchKernelGGL(k_ec1g2, dim3(2048), dim3(256), 0, stream, xe0, idx1, e1w1, e1w2T, e1s1, e1t1, hbuf, psum, psq);
  hipLaunchKernelGGL(k_fin, dim3(64), dim3(256), 0, stream, psum, psq, 2048, 64, 262144.f, e1g2, e1b2, e1s2, e1t2);
  hipLaunchKernelGGL(k_ec1fin, dim3(2048), dim3(256), 0, stream, hbuf, e1s2, e1t2, xe1, xe1T, sqx1);

  // knn on 64-d features
  hipLaunchKernelGGL(k_dgemm, dim3(32,32,2), dim3(256), 0, stream, xe1T, sqx1, hbuf);
  hipLaunchKernelGGL(k_knn_sel, dim3(2048), dim3(256), 0, stream, hbuf, idx2);

  // edge-conv 2 (bf16 MFMA formulation, fused stats+max)
  hipLaunchKernelGGL(k_wprep, dim3(8), dim3(256), 0, stream, e2w1, wbe1, 128, 128);
  hipLaunchKernelGGL(k_wprep, dim3(8), dim3(256), 0, stream, e2w2, wbe2, 128, 128);
  hipLaunchKernelGGL(k_ec2m1, dim3(2048), dim3(256), 0, stream, xe1, idx2, wbe1, hbuf, psum, psq);
  hipLaunchKernelGGL(k_fin, dim3(128), dim3(256), 0, stream, psum, psq, 2048, 128, 262144.f, e2g1, e2b1, e2s1, e2t1);
  hipLaunchKernelGGL(k_ec2m2, dim3(2048), dim3(256), 0, stream, hbuf, wbe2, e2s1, e2t1, xe2, psum, psq);
  hipLaunchKernelGGL(k_fin, dim3(128), dim3(256), 0, stream, psum, psq, 2048, 128, 262144.f, e2g2, e2b2, e2s2, e2t2);
  hipLaunchKernelGGL(k_xe2fin, dim3(4096), dim3(256), 0, stream, xe2, e2s2, e2t2);

  // concat + bf16 MFMA cbr chain
  hipLaunchKernelGGL(k_hcat, dim3(8192), dim3(256), 0, stream, xe2, kr, hcat);
  hipLaunchKernelGGL(k_wprep, dim3(128), dim3(256), 0, stream, w1, wb1, 1024, 256);
  hipLaunchKernelGGL(k_wprep, dim3(256), dim3(256), 0, stream, w2, wb2, 512, 1024);
  hipLaunchKernelGGL(k_wprep, dim3(64),  dim3(256), 0, stream, w3, wb3, 256, 512);
  hipLaunchKernelGGL(k_transpose, dim3((9*256+255)/256), dim3(256), 0, stream, w4, wT4, 9, 256);

  hipLaunchKernelGGL(k_bprep, dim3(1024), dim3(256), 0, stream, hcat, (const float*)nullptr, (const float*)nullptr, actB, 256);
  hipLaunchKernelGGL(k_gmm, dim3(64,8), dim3(256), 0, stream, wb1, actB, c1out, 1024, 256);
  hipLaunchKernelGGL(k_cstats, dim3(1024), dim3(256), 0, stream, c1out, 1024, g1, b1, c1s, c1t);

  hipLaunchKernelGGL(k_bprep, dim3(4096), dim3(256), 0, stream, c1out, c1s, c1t, actB, 1024);
  hipLaunchKernelGGL(k_gmm, dim3(64,4), dim3(256), 0, stream, wb2, actB, c2out, 512, 1024);
  hipLaunchKernelGGL(k_cstats, dim3(512), dim3(256), 0, stream, c2out, 512, g2, b2, c2s, c2t);

  hipLaunchKernelGGL(k_bprep, dim3(2048), dim3(256), 0, stream, c2out, c2s, c2t, actB, 512);
  hipLaunchKernelGGL(k_gmm, dim3(64,2), dim3(256), 0, stream, wb3, actB, c3out, 256, 512);
  hipLaunchKernelGGL(k_cstats, dim3(256), dim3(256), 0, stream, c3out, 256, g3, b3, c3s, c3t);

  hipLaunchKernelGGL(k_final4, dim3(16,2), dim3(256), 0, stream, c3out, wT4, c3s, c3t, pmax);
  hipLaunchKernelGGL(k_out, dim3(1), dim3(32), 0, stream, pmax, (float*)d_out);
}